// Round 2
// baseline (1992.590 us; speedup 1.0000x reference)
//
#include <hip/hip_runtime.h>
#include <hip/hip_bf16.h>

typedef __hip_bfloat16 bf16;
typedef __attribute__((ext_vector_type(8))) short short8;
typedef __attribute__((ext_vector_type(4))) float floatx4;

#define B_ 2
#define L_ 4096
#define D_ 1024
#define DI_ 2048
#define H_ 16
#define HD_ 128
#define N_ 128
#define CS_ 256
#define MC_ 256
#define NC_ 16
#define PROJ_ 8208

__device__ __forceinline__ float bf2f(short s) {
    return __uint_as_float(((unsigned)(unsigned short)s) << 16);
}

// ---------------------------------------------------------------------------
// Generic bf16 MFMA GEMM: C[M,N] = A[M,K] @ Bt[N,K]^T  (both row-major, K contig)
// 128x128 block tile, 4 waves (2x2), each wave 64x64 = 4x4 MFMA 16x16x32 tiles.
// ---------------------------------------------------------------------------
#define LDK 72

struct GemmP {
    const bf16* A; const bf16* Bt;
    float* C; bf16* CB; bf16* CB2; bf16* CB3;
    const float* add0; const float* add1; const bf16* add0b; const float* scr;
    long lda, ldb, ldc;
    int M, N, K, zinner;
    long a_zo, a_zi, b_zo, b_zi, c_zo, c_zi;
};

template<int EPI>
__global__ __launch_bounds__(256, 2) void gemm_bt(GemmP p)
{
    int z = blockIdx.z;
    int zo = z / p.zinner, zi = z % p.zinner;
    const bf16* A  = p.A  + (long)zo * p.a_zo + (long)zi * p.a_zi;
    const bf16* Bt = p.Bt + (long)zo * p.b_zo + (long)zi * p.b_zi;
    long coff = (long)zo * p.c_zo + (long)zi * p.c_zi;

    __shared__ __align__(16) bf16 As[128 * LDK];
    __shared__ __align__(16) bf16 Bs[128 * LDK];

    int m0 = blockIdx.y * 128, n0 = blockIdx.x * 128;
    int tid = threadIdx.x;
    int lane = tid & 63, wave = tid >> 6;
    int wm = (wave >> 1) * 64, wn = (wave & 1) * 64;
    int r16 = lane & 15, q8 = (lane >> 4) * 8;

    floatx4 zero4 = {0.f, 0.f, 0.f, 0.f};
    floatx4 acc[4][4];
#pragma unroll
    for (int i = 0; i < 4; i++)
#pragma unroll
        for (int j = 0; j < 4; j++) acc[i][j] = zero4;

    int srow = tid >> 1;
    int scol = (tid & 1) * 32;

    for (int k0 = 0; k0 < p.K; k0 += 64) {
        {
            const short8* sa = (const short8*)(A + (long)(m0 + srow) * p.lda + k0 + scol);
            short8* da = (short8*)&As[srow * LDK + scol];
            da[0] = sa[0]; da[1] = sa[1]; da[2] = sa[2]; da[3] = sa[3];
            int bn = n0 + srow;
            short8* db = (short8*)&Bs[srow * LDK + scol];
            if (bn < p.N) {
                const short8* sb = (const short8*)(Bt + (long)bn * p.ldb + k0 + scol);
                db[0] = sb[0]; db[1] = sb[1]; db[2] = sb[2]; db[3] = sb[3];
            } else {
                short8 zz = {0,0,0,0,0,0,0,0};
                db[0] = zz; db[1] = zz; db[2] = zz; db[3] = zz;
            }
        }
        __syncthreads();
#pragma unroll
        for (int ks = 0; ks < 64; ks += 32) {
            short8 af[4], bq[4];
#pragma unroll
            for (int i = 0; i < 4; i++)
                af[i] = *(const short8*)&As[(wm + i * 16 + r16) * LDK + ks + q8];
#pragma unroll
            for (int j = 0; j < 4; j++)
                bq[j] = *(const short8*)&Bs[(wn + j * 16 + r16) * LDK + ks + q8];
#pragma unroll
            for (int i = 0; i < 4; i++)
#pragma unroll
                for (int j = 0; j < 4; j++)
                    acc[i][j] = __builtin_amdgcn_mfma_f32_16x16x32_bf16(af[i], bq[j], acc[i][j], 0, 0, 0);
        }
        __syncthreads();
    }

    int rq = (lane >> 4) * 4;
#pragma unroll
    for (int i = 0; i < 4; i++) {
#pragma unroll
        for (int j = 0; j < 4; j++) {
#pragma unroll
            for (int r = 0; r < 4; r++) {
                int gm = m0 + wm + i * 16 + rq + r;
                int gn = n0 + wn + j * 16 + r16;
                if (gm >= p.M || gn >= p.N) continue;
                float a = acc[i][j][r];
                if (EPI == 0) {                       // plain fp32
                    p.C[coff + (long)gm * p.ldc + gn] = a;
                } else if (EPI == 1) {                // fp32 + bf16 dup
                    long ix = coff + (long)gm * p.ldc + gn;
                    p.C[ix] = a; p.CB[ix] = __float2bfloat16(a);
                } else if (EPI == 2) {                // proj 4-way split
                    if (gn < 2048)      p.CB [(long)gm * 2048 + gn]          = __float2bfloat16(a);
                    else if (gn < 4096) p.CB2[(long)gm * 2048 + (gn - 2048)] = __float2bfloat16(a);
                    else if (gn < 8192) p.CB3[(long)gm * 4096 + (gn - 4096)] = __float2bfloat16(a);
                    else                p.C  [(long)gm * 16   + (gn - 8192)] = a;
                } else if (EPI == 3) {                // Mmem causal decay mask -> bf16
                    float lg = p.scr[1];
                    float v = (gm > gn) ? a * __expf((float)(gm - 1 - gn) * lg) : 0.f;
                    p.CB[coff + (long)gm * p.ldc + gn] = __float2bfloat16(v);
                } else if (EPI == 4) {                // inter: acc*gp[m] + intra(bf16) -> bf16
                    long ix = coff + (long)gm * p.ldc + gn;
                    float t = a * p.scr[16 + gm] + __bfloat162float(p.add0b[ix]);
                    p.CB[ix] = __float2bfloat16(t);
                } else if (EPI == 5) {                // final: x + out + 0.5*acc
                    long ix = (long)gm * p.ldc + gn;
                    p.C[ix] = p.add0[ix] + p.add1[ix] + 0.5f * a;
                } else if (EPI == 6) {                // bf16 only
                    p.CB[coff + (long)gm * p.ldc + gn] = __float2bfloat16(a);
                }
            }
        }
    }
}

// ---------------------------------------------------------------------------
// Elementwise / helper kernels
// ---------------------------------------------------------------------------
__global__ void k_gamma(const float* decay, float* scr)
{
    int t = threadIdx.x;
    float g = 1.f / (1.f + expf(-decay[0]));
    float lg = logf(g);
    if (t == 0) { scr[0] = g; scr[1] = lg; scr[2] = expf(256.f * lg); }
    scr[16 + t]  = expf(lg * (float)t);          // gp
    scr[272 + t] = expf(lg * (float)(255 - t));  // gw
}

__global__ void k_f2b(const float* __restrict__ s, bf16* __restrict__ d, long n4)
{
    long i = (long)blockIdx.x * 256 + threadIdx.x;
    if (i >= n4) return;
    float4 v = ((const float4*)s)[i];
    bf16* o = d + i * 4;
    o[0] = __float2bfloat16(v.x); o[1] = __float2bfloat16(v.y);
    o[2] = __float2bfloat16(v.z); o[3] = __float2bfloat16(v.w);
}

__global__ __launch_bounds__(256) void k_rmsnorm(const float* __restrict__ x,
                                                 const float* __restrict__ w,
                                                 bf16* __restrict__ o)
{
    int row = blockIdx.x, t = threadIdx.x;
    float4 xv = ((const float4*)(x + (long)row * D_))[t];
    float s = xv.x*xv.x + xv.y*xv.y + xv.z*xv.z + xv.w*xv.w;
#pragma unroll
    for (int m = 32; m > 0; m >>= 1) s += __shfl_xor(s, m, 64);
    __shared__ float ps[4];
    if ((t & 63) == 0) ps[t >> 6] = s;
    __syncthreads();
    s = ps[0] + ps[1] + ps[2] + ps[3];
    float r = rsqrtf(s * (1.f / (float)D_) + 1e-6f);
    float4 wv = ((const float4*)w)[t];
    bf16* orow = o + (long)row * D_ + t * 4;
    orow[0] = __float2bfloat16(xv.x * r * wv.x);
    orow[1] = __float2bfloat16(xv.y * r * wv.y);
    orow[2] = __float2bfloat16(xv.z * r * wv.z);
    orow[3] = __float2bfloat16(xv.w * r * wv.w);
}

__global__ void k_ld(const float* __restrict__ dtr, const float* __restrict__ dt_bias,
                     const float* __restrict__ A_log, float* __restrict__ ld)
{
    long i = (long)blockIdx.x * 256 + threadIdx.x;
    if (i >= (long)B_ * L_ * H_) return;
    int h = (int)(i & 15);
    float d = dtr[i] + dt_bias[h];
    float sp = (d > 20.f) ? d : log1pf(__expf(d));
    ld[i] = -__expf(A_log[h]) * sp;
}

// val_b: [B*L, 2048] bf16
__global__ void k_conv(const bf16* __restrict__ val_b, const float* __restrict__ cw,
                       const float* __restrict__ cb, bf16* __restrict__ vo)
{
    long idx = (long)blockIdx.x * 256 + threadIdx.x;
    if (idx >= (long)B_ * L_ * DI_) return;
    long row = idx >> 11; int ch = (int)(idx & 2047);
    int l = (int)(row & (L_ - 1));
    float acc = cb[ch];
#pragma unroll
    for (int k = 0; k < 4; k++) {
        int ls = l - 3 + k;
        if (ls >= 0) acc += cw[ch * 4 + k] * __bfloat162float(val_b[(row - 3 + k) * 2048 + ch]);
    }
    float s = acc / (1.f + __expf(-acc));
    vo[idx] = __float2bfloat16(s);
}

__global__ void k_gate(const bf16* __restrict__ gate_b, const float* __restrict__ Y,
                       bf16* __restrict__ yg)
{
    long idx = (long)blockIdx.x * 256 + threadIdx.x;
    if (idx >= (long)B_ * L_ * DI_) return;
    long row = idx >> 11; int ch = (int)(idx & 2047);
    float g = __bfloat162float(gate_b[row * 2048 + ch]);
    float s = g / (1.f + __expf(-g));
    yg[idx] = __float2bfloat16(Y[idx] * s);
}

__global__ void k_shift(const bf16* __restrict__ ob, bf16* __restrict__ wk)
{
    long idx = (long)blockIdx.x * 256 + threadIdx.x;
    if (idx >= (long)B_ * L_ * D_) return;
    int l = (int)((idx >> 10) & (L_ - 1));
    wk[idx] = (l == 0) ? __float2bfloat16(0.f) : ob[idx - D_];
}

__global__ void k_transpose(const float* __restrict__ srcg, bf16* __restrict__ dstg)
{
    __shared__ float t[32][33];
    int b = blockIdx.z;
    const float* src = srcg + (long)b * L_ * D_;
    bf16* dst = dstg + (long)b * D_ * L_;
    int r0 = blockIdx.x * 32, c0 = blockIdx.y * 32;
    int tx = threadIdx.x & 31, ty = threadIdx.x >> 5;
    for (int i = 0; i < 32; i += 8)
        t[ty + i][tx] = src[(long)(r0 + ty + i) * D_ + c0 + tx];
    __syncthreads();
    for (int i = 0; i < 32; i += 8)
        dst[(long)(c0 + ty + i) * L_ + r0 + tx] = __float2bfloat16(t[tx][ty + i]);
}

__global__ void k_trans_wkg(const float* __restrict__ outg, const float* __restrict__ scr,
                            bf16* __restrict__ dstg)
{
    __shared__ float t[32][33];
    int b = blockIdx.z;
    const float* src = outg + (long)b * L_ * D_;
    bf16* dst = dstg + (long)b * D_ * L_;
    int r0 = blockIdx.x * 32, c0 = blockIdx.y * 32;
    int tx = threadIdx.x & 31, ty = threadIdx.x >> 5;
    for (int i = 0; i < 32; i += 8) {
        int rr = r0 + ty + i;
        float g = scr[272 + (rr & 255)];
        t[ty + i][tx] = (rr == 0) ? 0.f : src[(long)(rr - 1) * D_ + c0 + tx] * g;
    }
    __syncthreads();
    for (int i = 0; i < 32; i += 8)
        dst[(long)(c0 + ty + i) * L_ + r0 + tx] = __float2bfloat16(t[tx][ty + i]);
}

// ---------------------------------------------------------------------------
// SSD kernels. block = one (b, chunk, head). bc_b: [B*L, 4096] (B cols 0..2047, C cols 2048..4095)
// ---------------------------------------------------------------------------
__global__ __launch_bounds__(256) void k_ssd1(
    const bf16* __restrict__ bc_b, const bf16* __restrict__ vconv,
    const float* __restrict__ ld, const float* __restrict__ Dskip,
    float* __restrict__ cum_g, float* __restrict__ cumlast, float* __restrict__ Y)
{
    int bid = blockIdx.x;
    int h = bid & 15, c = (bid >> 4) & 15, b = bid >> 8;
    int tid = threadIdx.x;
    long rowbase = (long)b * L_ + c * CS_;

    __shared__ float cum_s[256];
    __shared__ float Ms[32][257];
    __shared__ __align__(16) bf16 Cs[32][128];

    float lv = ld[(rowbase + tid) * H_ + h];
    cum_s[tid] = lv;
    __syncthreads();
    for (int off = 1; off < 256; off <<= 1) {
        float add = (tid >= off) ? cum_s[tid - off] : 0.f;
        __syncthreads();
        cum_s[tid] += add;
        __syncthreads();
    }
    float cumv = cum_s[tid];
    cum_g[(rowbase + tid) * H_ + h] = cumv;
    if (tid == 255) cumlast[bid] = cumv;
    __syncthreads();

    const bf16* Bp = bc_b + rowbase * 4096 + h * N_;
    const bf16* Cp = bc_b + rowbase * 4096 + 2048 + h * N_;
    const bf16* vc = vconv + rowbase * DI_ + h * HD_;

    int tp = tid >> 3, sub = tid & 7;
    int dseg = sub * 16;
    float dsk[16];
#pragma unroll
    for (int i = 0; i < 16; i++) dsk[i] = Dskip[h * HD_ + dseg + i];

    for (int tt = 0; tt < 8; tt++) {
        {
            const short8* s = (const short8*)(Cp + (long)(tt * 32 + tp) * 4096 + dseg);
            short8* d = (short8*)&Cs[tp][dseg];
            d[0] = s[0]; d[1] = s[1];
        }
        __syncthreads();
        int tglob = tt * 32 + tp;
        float ct = cum_s[tglob];
        for (int mm = 0; mm < 32; mm++) {
            int m = sub + mm * 8;
            float val = 0.f;
            if (m <= tglob) {
                const bf16* brow = Bp + (long)m * 4096;
                float dot = 0.f;
#pragma unroll
                for (int n8 = 0; n8 < 128; n8 += 8) {
                    short8 bv = *(const short8*)(brow + n8);
                    short8 cv = *(const short8*)&Cs[tp][n8];
#pragma unroll
                    for (int q = 0; q < 8; q++)
                        dot += bf2f(cv[q]) * bf2f(bv[q]);
                }
                val = dot * __expf(ct - cum_s[m]);
            }
            Ms[tp][m] = val;
        }
        __syncthreads();
        {
            float acc[16];
#pragma unroll
            for (int i = 0; i < 16; i++) acc[i] = 0.f;
            for (int m = 0; m <= tglob; m++) {
                float s = Ms[tp][m];
                const bf16* vrow = vc + (long)m * DI_ + dseg;
                short8 v0 = *(const short8*)(vrow);
                short8 v1 = *(const short8*)(vrow + 8);
#pragma unroll
                for (int q = 0; q < 8; q++) {
                    acc[q]     += s * bf2f(v0[q]);
                    acc[8 + q] += s * bf2f(v1[q]);
                }
            }
            const bf16* vt = vc + (long)tglob * DI_ + dseg;
            short8 v0 = *(const short8*)(vt);
            short8 v1 = *(const short8*)(vt + 8);
            float* yrow = Y + (rowbase + tglob) * DI_ + h * HD_ + dseg;
#pragma unroll
            for (int q = 0; q < 8; q++) {
                yrow[q]     = acc[q]     + dsk[q]     * bf2f(v0[q]);
                yrow[8 + q] = acc[8 + q] + dsk[8 + q] * bf2f(v1[q]);
            }
        }
        __syncthreads();
    }
}

__global__ __launch_bounds__(256) void k_ssd_u(
    const bf16* __restrict__ bc_b, const bf16* __restrict__ vconv,
    const float* __restrict__ cum_g, const float* __restrict__ cumlast,
    float* __restrict__ U)
{
    int bid = blockIdx.x;
    int h = bid & 15, c = (bid >> 4) & 15, b = bid >> 8;
    int tid = threadIdx.x;
    long rowbase = (long)b * L_ + c * CS_;
    __shared__ float w_s[256];
    float cl = cumlast[bid];
    w_s[tid] = __expf(cl - cum_g[(rowbase + tid) * H_ + h]);
    __syncthreads();
    int d0 = (tid >> 4) * 8, n0 = (tid & 15) * 8;
    const bf16* vp = vconv + rowbase * DI_ + h * HD_ + d0;
    const bf16* bp = bc_b + rowbase * 4096 + h * N_ + n0;
    float acc[8][8] = {};
    for (int t = 0; t < 256; t++) {
        float w = w_s[t];
        short8 vv = *(const short8*)(vp + (long)t * DI_);
        short8 bv = *(const short8*)(bp + (long)t * 4096);
        float vf[8], bfv[8];
#pragma unroll
        for (int q = 0; q < 8; q++) { vf[q] = bf2f(vv[q]) * w; bfv[q] = bf2f(bv[q]); }
#pragma unroll
        for (int i = 0; i < 8; i++)
#pragma unroll
            for (int j = 0; j < 8; j++)
                acc[i][j] += vf[i] * bfv[j];
    }
    float* up = U + (((long)c * B_ + b) * H_ + h) * (HD_ * N_) + d0 * N_ + n0;
    for (int i = 0; i < 8; i++)
        for (int j = 0; j < 8; j++)
            up[i * N_ + j] = acc[i][j];
}

__global__ void k_ssd2(const float* __restrict__ U, const float* __restrict__ cumlast,
                       float* __restrict__ hst)
{
    long idx = (long)blockIdx.x * 256 + threadIdx.x;
    const long tot = (long)B_ * H_ * HD_ * N_;
    if (idx >= tot) return;
    int bh = (int)(idx >> 14);
    int b = bh >> 4, h = bh & 15;
    float hv = 0.f;
    for (int c = 0; c < NC_; c++) {
        hst[c * tot + idx] = hv;
        float ef = __expf(cumlast[b * 256 + c * 16 + h]);
        hv = ef * hv + U[c * tot + idx];
    }
}

__global__ __launch_bounds__(256) void k_ssd3(
    const bf16* __restrict__ bc_b, const float* __restrict__ hst,
    const float* __restrict__ cum_g, float* __restrict__ Y)
{
    int bid = blockIdx.x;
    int h = bid & 15, c = (bid >> 4) & 15, b = bid >> 8;
    int tid = threadIdx.x;
    long rowbase = (long)b * L_ + c * CS_;
    __shared__ __align__(16) bf16 hs[128][128];   // [n][d]
    __shared__ __align__(16) bf16 Cs[32][128];
    const float* hp = hst + (long)c * ((long)B_ * H_ * HD_ * N_) + ((long)b * H_ + h) * (HD_ * N_);
    for (int i = tid; i < 4096; i += 256) {
        float4 vv = ((const float4*)hp)[i];
        int gi = i * 4;
        int d = gi >> 7, n = gi & 127;
        hs[n][d]     = __float2bfloat16(vv.x);
        hs[n + 1][d] = __float2bfloat16(vv.y);
        hs[n + 2][d] = __float2bfloat16(vv.z);
        hs[n + 3][d] = __float2bfloat16(vv.w);
    }
    const bf16* Cp = bc_b + rowbase * 4096 + 2048 + h * N_;
    int tp = tid >> 3, sub = tid & 7, dseg = sub * 16;
    __syncthreads();
    for (int tt = 0; tt < 8; tt++) {
        {
            const short8* s = (const short8*)(Cp + (long)(tt * 32 + tp) * 4096 + dseg);
            short8* d = (short8*)&Cs[tp][dseg];
            d[0] = s[0]; d[1] = s[1];
        }
        __syncthreads();
        int tglob = tt * 32 + tp;
        float acc[16];
#pragma unroll
        for (int i = 0; i < 16; i++) acc[i] = 0.f;
        for (int n = 0; n < 128; n++) {
            float cf = bf2f(((const short*)Cs)[tp * 128 + n]);
            short8 h0 = *(const short8*)&hs[n][dseg];
            short8 h1 = *(const short8*)&hs[n][dseg + 8];
#pragma unroll
            for (int q = 0; q < 8; q++) {
                acc[q]     += cf * bf2f(h0[q]);
                acc[8 + q] += cf * bf2f(h1[q]);
            }
        }
        float ec = __expf(cum_g[(rowbase + tglob) * H_ + h]);
        float* yr = Y + (rowbase + tglob) * DI_ + h * HD_ + dseg;
#pragma unroll
        for (int i = 0; i < 16; i++) yr[i] += ec * acc[i];
        __syncthreads();
    }
}

// W recurrence, in place: UwW[c] := W entering chunk c
__global__ void k_m2(bf16* __restrict__ UwW, const float* __restrict__ scr)
{
    long idx = (long)blockIdx.x * 256 + threadIdx.x;
    const long tot = (long)B_ * D_ * D_;
    if (idx >= tot) return;
    float gMC = scr[2];
    float w = 0.f;
    for (int c = 0; c < NC_; c++) {
        float tmp = __bfloat162float(UwW[c * tot + idx]);
        UwW[c * tot + idx] = __float2bfloat16(w);
        w = gMC * w + tmp;
    }
}

// ---------------------------------------------------------------------------
// Host side
// ---------------------------------------------------------------------------
static inline int cdiv_i(long a, long b) { return (int)((a + b - 1) / b); }

static void run_gemm(hipStream_t st, int epi, const bf16* A, const bf16* Bt,
                     float* C, bf16* CB, bf16* CB2, bf16* CB3,
                     const float* add0, const float* add1, const bf16* add0b,
                     const float* scr, int M, int N, int K,
                     long lda, long ldb, long ldc, int nbatch, int zinner,
                     long a_zo, long a_zi, long b_zo, long b_zi, long c_zo, long c_zi)
{
    GemmP p;
    p.A = A; p.Bt = Bt; p.C = C; p.CB = CB; p.CB2 = CB2; p.CB3 = CB3;
    p.add0 = add0; p.add1 = add1; p.add0b = add0b; p.scr = scr;
    p.lda = lda; p.ldb = ldb; p.ldc = ldc;
    p.M = M; p.N = N; p.K = K; p.zinner = zinner;
    p.a_zo = a_zo; p.a_zi = a_zi; p.b_zo = b_zo; p.b_zi = b_zi; p.c_zo = c_zo; p.c_zi = c_zi;
    dim3 g(cdiv_i(N, 128), cdiv_i(M, 128), nbatch);
    dim3 b(256);
    switch (epi) {
        case 0: gemm_bt<0><<<g, b, 0, st>>>(p); break;
        case 1: gemm_bt<1><<<g, b, 0, st>>>(p); break;
        case 2: gemm_bt<2><<<g, b, 0, st>>>(p); break;
        case 3: gemm_bt<3><<<g, b, 0, st>>>(p); break;
        case 4: gemm_bt<4><<<g, b, 0, st>>>(p); break;
        case 5: gemm_bt<5><<<g, b, 0, st>>>(p); break;
        case 6: gemm_bt<6><<<g, b, 0, st>>>(p); break;
    }
}

extern "C" void kernel_launch(void* const* d_in, const int* in_sizes, int n_in,
                              void* d_out, int out_size, void* d_ws, size_t ws_size,
                              hipStream_t stream)
{
    const float* x       = (const float*)d_in[0];
    const float* norm_w  = (const float*)d_in[1];
    const float* w_in    = (const float*)d_in[2];
    const float* conv_w  = (const float*)d_in[3];
    const float* conv_b  = (const float*)d_in[4];
    const float* A_log   = (const float*)d_in[5];
    const float* dt_bias = (const float*)d_in[6];
    const float* D_skip  = (const float*)d_in[7];
    const float* w_out   = (const float*)d_in[8];
    const float* w_write = (const float*)d_in[9];
    const float* w_read  = (const float*)d_in[10];
    const float* decay   = (const float*)d_in[11];
    float* outp = (float*)d_out;

    // ---- static workspace layout with lifetime overlays (total ~244.9 MB) ----
    const size_t SZ_SCR   = 4096;
    const size_t SZ_DT    = (size_t)B_ * L_ * H_ * 4;      // 524288
    const size_t SZ_CUML  = 2048;
    const size_t SZ_WOUT  = (size_t)D_ * DI_ * 2;          // 4 MiB
    const size_t SZ_WSML  = (size_t)D_ * D_ * 2;           // 2 MiB
    const size_t SZ_VAL   = (size_t)B_ * L_ * 2048 * 2;    // 33.5 MB
    const size_t SZ_GATE  = SZ_VAL;
    const size_t SZ_BC    = (size_t)B_ * L_ * 4096 * 2;    // 67.1 MB
    const size_t SZ_Y     = (size_t)B_ * L_ * DI_ * 4;     // 67.1 MB
    const size_t SZ_E     = (size_t)B_ * L_ * D_ * 4;      // 33.5 MB

    size_t o = 0;
    auto take = [&](size_t sz) { size_t r = o; o += (sz + 255) & ~(size_t)255; return r; };
    const size_t O_SCR  = take(SZ_SCR);
    const size_t O_DT   = take(SZ_DT);
    const size_t O_LD   = take(SZ_DT);
    const size_t O_CUM  = take(SZ_DT);
    const size_t O_CL   = take(SZ_CUML);
    const size_t O_WO   = take(SZ_WOUT);
    const size_t O_WW   = take(SZ_WSML);
    const size_t O_WR   = take(SZ_WSML);
    const size_t O_VAL  = take(SZ_VAL);
    const size_t O_GATE = take(SZ_GATE);
    const size_t O_BC   = take(SZ_BC);
    const size_t O_Y    = take(SZ_Y);
    const size_t O_E    = take(SZ_E);
    const size_t NEED = o;
    if (ws_size < NEED) return;   // diagnostic: clean absmax-fail instead of fault

    char* ws = (char*)d_ws;
    float* scr     = (float*)(ws + O_SCR);
    float* dt_raw  = (float*)(ws + O_DT);
    float* ld_g    = (float*)(ws + O_LD);
    float* cum_g   = (float*)(ws + O_CUM);
    float* cumlast = (float*)(ws + O_CL);
    bf16*  w_out_b   = (bf16*)(ws + O_WO);
    bf16*  w_write_b = (bf16*)(ws + O_WW);
    bf16*  w_read_b  = (bf16*)(ws + O_WR);

    // region VAL: proj-val -> U_ssd -> yg_b -> Sm_b+intra_b
    bf16*  val_b   = (bf16*)(ws + O_VAL);
    float* U_ssd   = (float*)(ws + O_VAL);
    bf16*  yg_b    = (bf16*)(ws + O_VAL);
    bf16*  Sm_b    = (bf16*)(ws + O_VAL);
    bf16*  intra_b = (bf16*)(ws + O_VAL + (size_t)NC_ * B_ * MC_ * MC_ * 2);
    // region GATE: proj-gate -> out_b + wk_b/reads_b
    bf16*  gate_b  = (bf16*)(ws + O_GATE);
    bf16*  out_b   = (bf16*)(ws + O_GATE);
    bf16*  wk_b    = (bf16*)(ws + O_GATE + (size_t)B_ * L_ * D_ * 2);
    bf16*  reads_b = wk_b;
    // region BC: proj B,C cols -> UwW
    bf16*  bc_b    = (bf16*)(ws + O_BC);
    bf16*  UwW     = (bf16*)(ws + O_BC);
    // region Y: xn_b + w_in_b -> Ybuf -> vbuf + vT + wkgT
    bf16*  xn_b    = (bf16*)(ws + O_Y);
    bf16*  w_in_b  = (bf16*)(ws + O_Y + (size_t)B_ * L_ * D_ * 2);
    float* Ybuf    = (float*)(ws + O_Y);
    float* vbuf    = (float*)(ws + O_Y);
    bf16*  vT      = (bf16*)(ws + O_Y + (size_t)B_ * L_ * D_ * 4);
    bf16*  wkgT    = (bf16*)(ws + O_Y + (size_t)B_ * L_ * D_ * 4 + (size_t)B_ * L_ * D_ * 2);
    // region E: vconv_b -> hstates -> outf
    bf16*  vconv_b = (bf16*)(ws + O_E);
    float* hstates = (float*)(ws + O_E);
    float* outf    = (float*)(ws + O_E);

    const long BLD  = (long)B_ * L_ * D_;
    const long BLDI = (long)B_ * L_ * DI_;

    // 0. decay-derived constants
    k_gamma<<<1, 256, 0, stream>>>(decay, scr);
    // 1. weight conversions
    k_f2b<<<cdiv_i((long)PROJ_ * D_ / 4, 256), 256, 0, stream>>>(w_in, w_in_b, (long)PROJ_ * D_ / 4);
    k_f2b<<<cdiv_i((long)D_ * DI_ / 4, 256), 256, 0, stream>>>(w_out, w_out_b, (long)D_ * DI_ / 4);
    k_f2b<<<cdiv_i((long)D_ * D_ / 4, 256), 256, 0, stream>>>(w_write, w_write_b, (long)D_ * D_ / 4);
    k_f2b<<<cdiv_i((long)D_ * D_ / 4, 256), 256, 0, stream>>>(w_read, w_read_b, (long)D_ * D_ / 4);
    // 2. rmsnorm
    k_rmsnorm<<<B_ * L_, 256, 0, stream>>>(x, norm_w, xn_b);
    // 3. proj GEMM (4-way split epilogue)
    run_gemm(stream, 2, xn_b, w_in_b, dt_raw, val_b, gate_b, bc_b, nullptr, nullptr, nullptr, nullptr,
             B_ * L_, PROJ_, D_, D_, D_, 0, 1, 1, 0, 0, 0, 0, 0, 0);
    // 4. ld
    k_ld<<<cdiv_i((long)B_ * L_ * H_, 256), 256, 0, stream>>>(dt_raw, dt_bias, A_log, ld_g);
    // 5. conv + silu
    k_conv<<<cdiv_i(BLDI, 256), 256, 0, stream>>>(val_b, conv_w, conv_b, vconv_b);
    // 6. SSD
    k_ssd1<<<B_ * NC_ * H_, 256, 0, stream>>>(bc_b, vconv_b, ld_g, D_skip, cum_g, cumlast, Ybuf);
    k_ssd_u<<<B_ * NC_ * H_, 256, 0, stream>>>(bc_b, vconv_b, cum_g, cumlast, U_ssd);
    k_ssd2<<<cdiv_i((long)B_ * H_ * HD_ * N_, 256), 256, 0, stream>>>(U_ssd, cumlast, hstates);
    k_ssd3<<<B_ * NC_ * H_, 256, 0, stream>>>(bc_b, hstates, cum_g, Ybuf);
    // 7. gate, out projection
    k_gate<<<cdiv_i(BLDI, 256), 256, 0, stream>>>(gate_b, Ybuf, yg_b);
    run_gemm(stream, 1, yg_b, w_out_b, outf, out_b, nullptr, nullptr, nullptr, nullptr, nullptr, nullptr,
             B_ * L_, D_, DI_, DI_, DI_, D_, 1, 1, 0, 0, 0, 0, 0, 0);
    // 8. memory-scan inputs
    k_shift<<<cdiv_i(BLD, 256), 256, 0, stream>>>(out_b, wk_b);
    run_gemm(stream, 0, out_b, w_write_b, vbuf, nullptr, nullptr, nullptr, nullptr, nullptr, nullptr, nullptr,
             B_ * L_, D_, D_, D_, D_, D_, 1, 1, 0, 0, 0, 0, 0, 0);
    k_transpose<<<dim3(L_ / 32, D_ / 32, B_), 256, 0, stream>>>(vbuf, vT);
    k_trans_wkg<<<dim3(L_ / 32, D_ / 32, B_), 256, 0, stream>>>(outf, scr, wkgT);
    // 9. per-chunk outer products Uw[c][b] = (v*gw)^T wk
    run_gemm(stream, 6, vT, wkgT, nullptr, UwW, nullptr, nullptr, nullptr, nullptr, nullptr, nullptr,
             D_, D_, MC_, L_, L_, D_, B_ * NC_, NC_,
             (long)D_ * L_, MC_, (long)D_ * L_, MC_, (long)D_ * D_, (long)B_ * D_ * D_);
    // 10. W recurrence (in place)
    k_m2<<<cdiv_i((long)B_ * D_ * D_, 256), 256, 0, stream>>>(UwW, scr);
    // 11. S = rk wk^T with Mmem mask
    run_gemm(stream, 3, out_b, wk_b, nullptr, Sm_b, nullptr, nullptr, nullptr, nullptr, nullptr, scr,
             MC_, MC_, D_, D_, D_, MC_, B_ * NC_, NC_,
             (long)L_ * D_, (long)MC_ * D_, (long)L_ * D_, (long)MC_ * D_,
             (long)MC_ * MC_, (long)B_ * MC_ * MC_);
    // 12. intra = Sm @ v_c  (bf16 out)
    run_gemm(stream, 6, Sm_b, vT, nullptr, intra_b, nullptr, nullptr, nullptr, nullptr, nullptr, nullptr,
             MC_, D_, MC_, MC_, L_, D_, B_ * NC_, NC_,
             (long)MC_ * MC_, (long)B_ * MC_ * MC_, (long)D_ * L_, MC_,
             (long)L_ * D_, (long)MC_ * D_);
    // 13. reads = (rk @ W^T)*gp + intra   (bf16 out, overwrites wk region)
    run_gemm(stream, 4, out_b, UwW, nullptr, reads_b, nullptr, nullptr, nullptr, nullptr, intra_b, scr,
             MC_, D_, D_, D_, D_, D_, B_ * NC_, NC_,
             (long)L_ * D_, (long)MC_ * D_, (long)D_ * D_, (long)B_ * D_ * D_,
             (long)L_ * D_, (long)MC_ * D_);
    // 14. final: d_out = x + out + 0.5 * reads @ w_read^T
    run_gemm(stream, 5, reads_b, w_read_b, outp, nullptr, nullptr, nullptr, x, outf, nullptr, nullptr,
             B_ * L_, D_, D_, D_, D_, D_, 1, 1, 0, 0, 0, 0, 0, 0);
}

// Round 3
// 936.359 us; speedup vs baseline: 2.1280x; 2.1280x over previous
//
#include <hip/hip_runtime.h>
#include <hip/hip_bf16.h>

typedef __hip_bfloat16 bf16;
typedef __attribute__((ext_vector_type(8))) short short8;
typedef __attribute__((ext_vector_type(4))) float floatx4;

#define B_ 2
#define L_ 4096
#define D_ 1024
#define DI_ 2048
#define H_ 16
#define HD_ 128
#define N_ 128
#define CS_ 256
#define MC_ 256
#define NC_ 16
#define PROJ_ 8208

__device__ __forceinline__ float bf2f(short s) {
    return __uint_as_float(((unsigned)(unsigned short)s) << 16);
}

// ---------------------------------------------------------------------------
// Generic bf16 MFMA GEMM: C[M,N] = A[M,K] @ Bt[N,K]^T  (both row-major, K contig)
// ---------------------------------------------------------------------------
#define LDK 72

struct GemmP {
    const bf16* A; const bf16* Bt;
    float* C; bf16* CB; bf16* CB2; bf16* CB3;
    const float* add0; const float* add1; const bf16* add0b; const float* scr;
    long lda, ldb, ldc;
    int M, N, K, zinner;
    long a_zo, a_zi, b_zo, b_zi, c_zo, c_zi;
};

template<int EPI>
__global__ __launch_bounds__(256, 2) void gemm_bt(GemmP p)
{
    int z = blockIdx.z;
    int zo = z / p.zinner, zi = z % p.zinner;
    const bf16* A  = p.A  + (long)zo * p.a_zo + (long)zi * p.a_zi;
    const bf16* Bt = p.Bt + (long)zo * p.b_zo + (long)zi * p.b_zi;
    long coff = (long)zo * p.c_zo + (long)zi * p.c_zi;

    __shared__ __align__(16) bf16 As[128 * LDK];
    __shared__ __align__(16) bf16 Bs[128 * LDK];

    int m0 = blockIdx.y * 128, n0 = blockIdx.x * 128;
    int tid = threadIdx.x;
    int lane = tid & 63, wave = tid >> 6;
    int wm = (wave >> 1) * 64, wn = (wave & 1) * 64;
    int r16 = lane & 15, q8 = (lane >> 4) * 8;

    floatx4 zero4 = {0.f, 0.f, 0.f, 0.f};
    floatx4 acc[4][4];
#pragma unroll
    for (int i = 0; i < 4; i++)
#pragma unroll
        for (int j = 0; j < 4; j++) acc[i][j] = zero4;

    int srow = tid >> 1;
    int scol = (tid & 1) * 32;

    for (int k0 = 0; k0 < p.K; k0 += 64) {
        {
            const short8* sa = (const short8*)(A + (long)(m0 + srow) * p.lda + k0 + scol);
            short8* da = (short8*)&As[srow * LDK + scol];
            da[0] = sa[0]; da[1] = sa[1]; da[2] = sa[2]; da[3] = sa[3];
            int bn = n0 + srow;
            short8* db = (short8*)&Bs[srow * LDK + scol];
            if (bn < p.N) {
                const short8* sb = (const short8*)(Bt + (long)bn * p.ldb + k0 + scol);
                db[0] = sb[0]; db[1] = sb[1]; db[2] = sb[2]; db[3] = sb[3];
            } else {
                short8 zz = {0,0,0,0,0,0,0,0};
                db[0] = zz; db[1] = zz; db[2] = zz; db[3] = zz;
            }
        }
        __syncthreads();
#pragma unroll
        for (int ks = 0; ks < 64; ks += 32) {
            short8 af[4], bq[4];
#pragma unroll
            for (int i = 0; i < 4; i++)
                af[i] = *(const short8*)&As[(wm + i * 16 + r16) * LDK + ks + q8];
#pragma unroll
            for (int j = 0; j < 4; j++)
                bq[j] = *(const short8*)&Bs[(wn + j * 16 + r16) * LDK + ks + q8];
#pragma unroll
            for (int i = 0; i < 4; i++)
#pragma unroll
                for (int j = 0; j < 4; j++)
                    acc[i][j] = __builtin_amdgcn_mfma_f32_16x16x32_bf16(af[i], bq[j], acc[i][j], 0, 0, 0);
        }
        __syncthreads();
    }

    int rq = (lane >> 4) * 4;
#pragma unroll
    for (int i = 0; i < 4; i++) {
#pragma unroll
        for (int j = 0; j < 4; j++) {
#pragma unroll
            for (int r = 0; r < 4; r++) {
                int gm = m0 + wm + i * 16 + rq + r;
                int gn = n0 + wn + j * 16 + r16;
                if (gm >= p.M || gn >= p.N) continue;
                float a = acc[i][j][r];
                if (EPI == 0) {
                    p.C[coff + (long)gm * p.ldc + gn] = a;
                } else if (EPI == 1) {
                    long ix = coff + (long)gm * p.ldc + gn;
                    p.C[ix] = a; p.CB[ix] = __float2bfloat16(a);
                } else if (EPI == 2) {                // proj 4-way split
                    if (gn < 2048)      p.CB [(long)gm * 2048 + gn]          = __float2bfloat16(a);
                    else if (gn < 4096) p.CB2[(long)gm * 2048 + (gn - 2048)] = __float2bfloat16(a);
                    else if (gn < 8192) p.CB3[(long)gm * 4096 + (gn - 4096)] = __float2bfloat16(a);
                    else                p.C  [(long)gm * 16   + (gn - 8192)] = a;
                } else if (EPI == 3) {                // Mmem causal decay mask -> bf16
                    float lg = p.scr[1];
                    float v = (gm > gn) ? a * __expf((float)(gm - 1 - gn) * lg) : 0.f;
                    p.CB[coff + (long)gm * p.ldc + gn] = __float2bfloat16(v);
                } else if (EPI == 4) {                // inter: acc*gp[m] + intra(bf16) -> bf16
                    long ix = coff + (long)gm * p.ldc + gn;
                    float t = a * p.scr[16 + gm] + __bfloat162float(p.add0b[ix]);
                    p.CB[ix] = __float2bfloat16(t);
                } else if (EPI == 5) {                // final: x + out + 0.5*acc
                    long ix = (long)gm * p.ldc + gn;
                    p.C[ix] = p.add0[ix] + p.add1[ix] + 0.5f * a;
                } else if (EPI == 6) {                // bf16 only
                    p.CB[coff + (long)gm * p.ldc + gn] = __float2bfloat16(a);
                }
            }
        }
    }
}

// ---------------------------------------------------------------------------
// Elementwise / helper kernels
// ---------------------------------------------------------------------------
__global__ void k_gamma(const float* decay, float* scr)
{
    int t = threadIdx.x;
    float g = 1.f / (1.f + expf(-decay[0]));
    float lg = logf(g);
    if (t == 0) { scr[0] = g; scr[1] = lg; scr[2] = expf(256.f * lg); }
    scr[16 + t]  = expf(lg * (float)t);          // gp
    scr[272 + t] = expf(lg * (float)(255 - t));  // gw
}

__global__ void k_f2b(const float* __restrict__ s, bf16* __restrict__ d, long n4)
{
    long i = (long)blockIdx.x * 256 + threadIdx.x;
    if (i >= n4) return;
    float4 v = ((const float4*)s)[i];
    bf16* o = d + i * 4;
    o[0] = __float2bfloat16(v.x); o[1] = __float2bfloat16(v.y);
    o[2] = __float2bfloat16(v.z); o[3] = __float2bfloat16(v.w);
}

__global__ __launch_bounds__(256) void k_rmsnorm(const float* __restrict__ x,
                                                 const float* __restrict__ w,
                                                 bf16* __restrict__ o)
{
    int row = blockIdx.x, t = threadIdx.x;
    float4 xv = ((const float4*)(x + (long)row * D_))[t];
    float s = xv.x*xv.x + xv.y*xv.y + xv.z*xv.z + xv.w*xv.w;
#pragma unroll
    for (int m = 32; m > 0; m >>= 1) s += __shfl_xor(s, m, 64);
    __shared__ float ps[4];
    if ((t & 63) == 0) ps[t >> 6] = s;
    __syncthreads();
    s = ps[0] + ps[1] + ps[2] + ps[3];
    float r = rsqrtf(s * (1.f / (float)D_) + 1e-6f);
    float4 wv = ((const float4*)w)[t];
    bf16* orow = o + (long)row * D_ + t * 4;
    orow[0] = __float2bfloat16(xv.x * r * wv.x);
    orow[1] = __float2bfloat16(xv.y * r * wv.y);
    orow[2] = __float2bfloat16(xv.z * r * wv.z);
    orow[3] = __float2bfloat16(xv.w * r * wv.w);
}

__global__ void k_ld(const float* __restrict__ dtr, const float* __restrict__ dt_bias,
                     const float* __restrict__ A_log, float* __restrict__ ld)
{
    long i = (long)blockIdx.x * 256 + threadIdx.x;
    if (i >= (long)B_ * L_ * H_) return;
    int h = (int)(i & 15);
    float d = dtr[i] + dt_bias[h];
    float sp = (d > 20.f) ? d : log1pf(__expf(d));
    ld[i] = -__expf(A_log[h]) * sp;
}

__global__ __launch_bounds__(256) void k_cum(const float* __restrict__ ld,
                                             float* __restrict__ cum_g,
                                             float* __restrict__ cumlast)
{
    int bid = blockIdx.x;           // b*256 + c*16 + h
    int h = bid & 15, c = (bid >> 4) & 15, b = bid >> 8;
    long rowbase = (long)b * L_ + c * CS_;
    int tid = threadIdx.x;
    __shared__ float cum_s[256];
    cum_s[tid] = ld[(rowbase + tid) * H_ + h];
    __syncthreads();
    for (int off = 1; off < 256; off <<= 1) {
        float add = (tid >= off) ? cum_s[tid - off] : 0.f;
        __syncthreads();
        cum_s[tid] += add;
        __syncthreads();
    }
    cum_g[(rowbase + tid) * H_ + h] = cum_s[tid];
    if (tid == 255) cumlast[bid] = cum_s[255];
}

__global__ void k_conv(const bf16* __restrict__ val_b, const float* __restrict__ cw,
                       const float* __restrict__ cb, bf16* __restrict__ vo)
{
    long idx = (long)blockIdx.x * 256 + threadIdx.x;
    if (idx >= (long)B_ * L_ * DI_) return;
    long row = idx >> 11; int ch = (int)(idx & 2047);
    int l = (int)(row & (L_ - 1));
    float acc = cb[ch];
#pragma unroll
    for (int k = 0; k < 4; k++) {
        int ls = l - 3 + k;
        if (ls >= 0) acc += cw[ch * 4 + k] * __bfloat162float(val_b[(row - 3 + k) * 2048 + ch]);
    }
    float s = acc / (1.f + __expf(-acc));
    vo[idx] = __float2bfloat16(s);
}

// vconv [b*L][2048] -> vT [b*2048 + d][L] bf16, plus decay-weighted vTw
__global__ void k_vt(const bf16* __restrict__ vconv, const float* __restrict__ cum_g,
                     const float* __restrict__ cumlast, bf16* __restrict__ vT,
                     bf16* __restrict__ vTw)
{
    __shared__ bf16 tile[32][33];
    int b = blockIdx.z;
    int r0 = blockIdx.x * 32, c0 = blockIdx.y * 32;
    int tx = threadIdx.x & 31, ty = threadIdx.x >> 5;
    for (int i = 0; i < 32; i += 8)
        tile[ty + i][tx] = vconv[((long)b * L_ + r0 + ty + i) * 2048 + c0 + tx];
    __syncthreads();
    int l = r0 + tx;
    int h = c0 >> 7;
    float w = __expf(cumlast[b * 256 + (l >> 8) * 16 + h] - cum_g[((long)b * L_ + l) * 16 + h]);
    for (int i = 0; i < 32; i += 8) {
        int col = c0 + ty + i;
        long oidx = ((long)b * 2048 + col) * L_ + l;
        bf16 v = tile[tx][ty + i];
        vT[oidx] = v;
        vTw[oidx] = __float2bfloat16(__bfloat162float(v) * w);
    }
}

// bc_b B-part [b*L][4096 cols 0..2047] -> BT [b*2048 + col][L]
__global__ void k_bt(const bf16* __restrict__ bc, bf16* __restrict__ BT)
{
    __shared__ bf16 tile[32][33];
    int b = blockIdx.z;
    int r0 = blockIdx.x * 32, c0 = blockIdx.y * 32;
    int tx = threadIdx.x & 31, ty = threadIdx.x >> 5;
    for (int i = 0; i < 32; i += 8)
        tile[ty + i][tx] = bc[((long)b * L_ + r0 + ty + i) * 4096 + c0 + tx];
    __syncthreads();
    int l = r0 + tx;
    for (int i = 0; i < 32; i += 8) {
        int col = c0 + ty + i;
        BT[((long)b * 2048 + col) * L_ + l] = tile[tx][ty + i];
    }
}

// U[c][b][h][d][n] = sum_t (v*w)[t,d] B[t,n]  — MFMA, global fragments
__global__ __launch_bounds__(256, 2) void k_ssd_u2(
    const bf16* __restrict__ vTw, const bf16* __restrict__ BT, float* __restrict__ U)
{
    int bid = blockIdx.x;
    int h = bid & 15, c = (bid >> 4) & 15, b = bid >> 8;
    int lane = threadIdx.x & 63, wave = threadIdx.x >> 6;
    int r16 = lane & 15, q8 = (lane >> 4) * 8, rq = (lane >> 4) * 4;
    int d0 = (wave >> 1) * 64, n0 = (wave & 1) * 64;
    const bf16* vb = vTw + ((long)b * 2048 + h * 128) * L_ + c * 256;
    const bf16* bb = BT  + ((long)b * 2048 + h * 128) * L_ + c * 256;
    floatx4 zero4 = {0.f, 0.f, 0.f, 0.f};
    floatx4 acc[4][4];
#pragma unroll
    for (int i = 0; i < 4; i++)
#pragma unroll
        for (int j = 0; j < 4; j++) acc[i][j] = zero4;
#pragma unroll 2
    for (int ks = 0; ks < 8; ks++) {
        short8 af[4], bq[4];
#pragma unroll
        for (int i = 0; i < 4; i++)
            af[i] = *(const short8*)(vb + (long)(d0 + i * 16 + r16) * L_ + ks * 32 + q8);
#pragma unroll
        for (int j = 0; j < 4; j++)
            bq[j] = *(const short8*)(bb + (long)(n0 + j * 16 + r16) * L_ + ks * 32 + q8);
#pragma unroll
        for (int i = 0; i < 4; i++)
#pragma unroll
            for (int j = 0; j < 4; j++)
                acc[i][j] = __builtin_amdgcn_mfma_f32_16x16x32_bf16(af[i], bq[j], acc[i][j], 0, 0, 0);
    }
    float* up = U + (((long)c * B_ + b) * H_ + h) * 16384;
#pragma unroll
    for (int i = 0; i < 4; i++)
#pragma unroll
        for (int j = 0; j < 4; j++)
#pragma unroll
            for (int r = 0; r < 4; r++)
                up[(d0 + i * 16 + rq + r) * 128 + (n0 + j * 16 + r16)] = acc[i][j][r];
}

// h recurrence -> bf16 states entering each chunk
__global__ void k_ssd2(const float* __restrict__ U, const float* __restrict__ cumlast,
                       bf16* __restrict__ hst)
{
    long idx = (long)blockIdx.x * 256 + threadIdx.x;
    const long tot = (long)B_ * H_ * HD_ * N_;
    if (idx >= tot) return;
    int bh = (int)(idx >> 14);
    int b = bh >> 4, h = bh & 15;
    float hv = 0.f;
    for (int c = 0; c < NC_; c++) {
        hst[c * tot + idx] = __float2bfloat16(hv);
        float ef = __expf(cumlast[b * 256 + c * 16 + h]);
        hv = ef * hv + U[c * tot + idx];
    }
}

// Fused intra+inter SSD output, flash-style MFMA. Writes gated bf16 yg.
__global__ __launch_bounds__(256, 2) void k_ssd_y(
    const bf16* __restrict__ bc_b, const bf16* __restrict__ vT,
    const bf16* __restrict__ hst, const float* __restrict__ cum_g,
    const float* __restrict__ Dskip, const bf16* __restrict__ gate_b,
    bf16* __restrict__ yg)
{
    int bid = blockIdx.x;
    int h = bid & 15, c = (bid >> 4) & 15, b = bid >> 8;
    long rowbase = (long)b * L_ + c * CS_;
    int tid = threadIdx.x, lane = tid & 63, wave = tid >> 6;
    int r16 = lane & 15, q8 = (lane >> 4) * 8, rq = (lane >> 4) * 4;
    int wt = (wave >> 1) * 32, wmS = (wave & 1) * 32, wd = (wave & 1) * 64;

    __shared__ float cum_s[256];
    __shared__ __align__(16) bf16 Ss[64][72];

    cum_s[tid] = cum_g[(rowbase + tid) * H_ + h];
    __syncthreads();

    const bf16* Cb  = bc_b + rowbase * 4096 + 2048 + h * 128;
    const bf16* Bb  = bc_b + rowbase * 4096 + h * 128;
    const bf16* vTb = vT + ((long)b * 2048 + h * 128) * L_ + c * 256;
    const bf16* hp  = hst + (((long)c * B_ + b) * H_ + h) * 16384;

    floatx4 zero4 = {0.f, 0.f, 0.f, 0.f};

    for (int tt = 0; tt < 4; tt++) {
        int tbase = tt * 64;
        // cache C fragments for this t-tile (rows wt..wt+31 via i, k over 128)
        short8 caf[2][4];
#pragma unroll
        for (int i = 0; i < 2; i++)
#pragma unroll
            for (int ks = 0; ks < 4; ks++)
                caf[i][ks] = *(const short8*)(Cb + (long)(tbase + wt + i * 16 + r16) * 4096 + ks * 32 + q8);

        // ---- inter: yacc = C @ hprev^T, then scale rows by exp(cum[t]) ----
        floatx4 yacc[2][4];
#pragma unroll
        for (int i = 0; i < 2; i++)
#pragma unroll
            for (int j = 0; j < 4; j++) yacc[i][j] = zero4;
#pragma unroll
        for (int ks = 0; ks < 4; ks++)
#pragma unroll
            for (int j = 0; j < 4; j++) {
                short8 hq = *(const short8*)(hp + (long)(wd + j * 16 + r16) * 128 + ks * 32 + q8);
#pragma unroll
                for (int i = 0; i < 2; i++)
                    yacc[i][j] = __builtin_amdgcn_mfma_f32_16x16x32_bf16(caf[i][ks], hq, yacc[i][j], 0, 0, 0);
            }
        float texp[2][4];
#pragma unroll
        for (int i = 0; i < 2; i++)
#pragma unroll
            for (int r = 0; r < 4; r++)
                texp[i][r] = __expf(cum_s[tbase + wt + i * 16 + rq + r]);
#pragma unroll
        for (int i = 0; i < 2; i++)
#pragma unroll
            for (int j = 0; j < 4; j++)
#pragma unroll
                for (int r = 0; r < 4; r++) yacc[i][j][r] *= texp[i][r];

        // ---- intra m-loop ----
        for (int mt = 0; mt <= tt; mt++) {
            int mbase = mt * 64;
            floatx4 sacc[2][2];
#pragma unroll
            for (int i = 0; i < 2; i++)
#pragma unroll
                for (int j = 0; j < 2; j++) sacc[i][j] = zero4;
#pragma unroll
            for (int ks = 0; ks < 4; ks++) {
                short8 bq[2];
#pragma unroll
                for (int j = 0; j < 2; j++)
                    bq[j] = *(const short8*)(Bb + (long)(mbase + wmS + j * 16 + r16) * 4096 + ks * 32 + q8);
#pragma unroll
                for (int i = 0; i < 2; i++)
#pragma unroll
                    for (int j = 0; j < 2; j++)
                        sacc[i][j] = __builtin_amdgcn_mfma_f32_16x16x32_bf16(caf[i][ks], bq[j], sacc[i][j], 0, 0, 0);
            }
            __syncthreads();          // prev Y-phase reads of Ss done
#pragma unroll
            for (int i = 0; i < 2; i++)
#pragma unroll
                for (int r = 0; r < 4; r++) {
                    int trow = wt + i * 16 + rq + r;
                    float ct = cum_s[tbase + trow];
#pragma unroll
                    for (int j = 0; j < 2; j++) {
                        int mcol = mbase + wmS + j * 16 + r16;
                        float val = (mcol <= tbase + trow) ? sacc[i][j][r] * __expf(ct - cum_s[mcol]) : 0.f;
                        Ss[trow][wmS + j * 16 + r16] = __float2bfloat16(val);
                    }
                }
            __syncthreads();
#pragma unroll
            for (int ks = 0; ks < 2; ks++) {
                short8 saf[2];
#pragma unroll
                for (int i = 0; i < 2; i++)
                    saf[i] = *(const short8*)&Ss[wt + i * 16 + r16][ks * 32 + q8];
#pragma unroll
                for (int j = 0; j < 4; j++) {
                    short8 vq = *(const short8*)(vTb + (long)(wd + j * 16 + r16) * L_ + mbase + ks * 32 + q8);
#pragma unroll
                    for (int i = 0; i < 2; i++)
                        yacc[i][j] = __builtin_amdgcn_mfma_f32_16x16x32_bf16(saf[i], vq, yacc[i][j], 0, 0, 0);
                }
            }
        }
        // ---- epilogue: + Dskip*v, silu(gate) fuse, bf16 store ----
#pragma unroll
        for (int i = 0; i < 2; i++)
#pragma unroll
            for (int r = 0; r < 4; r++) {
                int t = tbase + wt + i * 16 + rq + r;
                long grow = (rowbase + t) * 2048 + h * 128;
#pragma unroll
                for (int j = 0; j < 4; j++) {
                    int d = wd + j * 16 + r16;
                    float vv = __bfloat162float(vTb[(long)d * L_ + t]);
                    float y = yacc[i][j][r] + Dskip[h * 128 + d] * vv;
                    float g = __bfloat162float(gate_b[grow + d]);
                    float sg = g / (1.f + __expf(-g));
                    yg[grow + d] = __float2bfloat16(y * sg);
                }
            }
    }
}

__global__ void k_shift(const bf16* __restrict__ ob, bf16* __restrict__ wk)
{
    long idx = (long)blockIdx.x * 256 + threadIdx.x;
    if (idx >= (long)B_ * L_ * D_) return;
    int l = (int)((idx >> 10) & (L_ - 1));
    wk[idx] = (l == 0) ? __float2bfloat16(0.f) : ob[idx - D_];
}

__global__ void k_transpose(const float* __restrict__ srcg, bf16* __restrict__ dstg)
{
    __shared__ float t[32][33];
    int b = blockIdx.z;
    const float* src = srcg + (long)b * L_ * D_;
    bf16* dst = dstg + (long)b * D_ * L_;
    int r0 = blockIdx.x * 32, c0 = blockIdx.y * 32;
    int tx = threadIdx.x & 31, ty = threadIdx.x >> 5;
    for (int i = 0; i < 32; i += 8)
        t[ty + i][tx] = src[(long)(r0 + ty + i) * D_ + c0 + tx];
    __syncthreads();
    for (int i = 0; i < 32; i += 8)
        dst[(long)(c0 + ty + i) * L_ + r0 + tx] = __float2bfloat16(t[tx][ty + i]);
}

__global__ void k_trans_wkg(const float* __restrict__ outg, const float* __restrict__ scr,
                            bf16* __restrict__ dstg)
{
    __shared__ float t[32][33];
    int b = blockIdx.z;
    const float* src = outg + (long)b * L_ * D_;
    bf16* dst = dstg + (long)b * D_ * L_;
    int r0 = blockIdx.x * 32, c0 = blockIdx.y * 32;
    int tx = threadIdx.x & 31, ty = threadIdx.x >> 5;
    for (int i = 0; i < 32; i += 8) {
        int rr = r0 + ty + i;
        float g = scr[272 + (rr & 255)];
        t[ty + i][tx] = (rr == 0) ? 0.f : src[(long)(rr - 1) * D_ + c0 + tx] * g;
    }
    __syncthreads();
    for (int i = 0; i < 32; i += 8)
        dst[(long)(c0 + ty + i) * L_ + r0 + tx] = __float2bfloat16(t[tx][ty + i]);
}

// W recurrence, in place
__global__ void k_m2(bf16* __restrict__ UwW, const float* __restrict__ scr)
{
    long idx = (long)blockIdx.x * 256 + threadIdx.x;
    const long tot = (long)B_ * D_ * D_;
    if (idx >= tot) return;
    float gMC = scr[2];
    float w = 0.f;
    for (int c = 0; c < NC_; c++) {
        float tmp = __bfloat162float(UwW[c * tot + idx]);
        UwW[c * tot + idx] = __float2bfloat16(w);
        w = gMC * w + tmp;
    }
}

// ---------------------------------------------------------------------------
// Host side
// ---------------------------------------------------------------------------
static inline int cdiv_i(long a, long b) { return (int)((a + b - 1) / b); }

static void run_gemm(hipStream_t st, int epi, const bf16* A, const bf16* Bt,
                     float* C, bf16* CB, bf16* CB2, bf16* CB3,
                     const float* add0, const float* add1, const bf16* add0b,
                     const float* scr, int M, int N, int K,
                     long lda, long ldb, long ldc, int nbatch, int zinner,
                     long a_zo, long a_zi, long b_zo, long b_zi, long c_zo, long c_zi)
{
    GemmP p;
    p.A = A; p.Bt = Bt; p.C = C; p.CB = CB; p.CB2 = CB2; p.CB3 = CB3;
    p.add0 = add0; p.add1 = add1; p.add0b = add0b; p.scr = scr;
    p.lda = lda; p.ldb = ldb; p.ldc = ldc;
    p.M = M; p.N = N; p.K = K; p.zinner = zinner;
    p.a_zo = a_zo; p.a_zi = a_zi; p.b_zo = b_zo; p.b_zi = b_zi; p.c_zo = c_zo; p.c_zi = c_zi;
    dim3 g(cdiv_i(N, 128), cdiv_i(M, 128), nbatch);
    dim3 b(256);
    switch (epi) {
        case 0: gemm_bt<0><<<g, b, 0, st>>>(p); break;
        case 1: gemm_bt<1><<<g, b, 0, st>>>(p); break;
        case 2: gemm_bt<2><<<g, b, 0, st>>>(p); break;
        case 3: gemm_bt<3><<<g, b, 0, st>>>(p); break;
        case 4: gemm_bt<4><<<g, b, 0, st>>>(p); break;
        case 5: gemm_bt<5><<<g, b, 0, st>>>(p); break;
        case 6: gemm_bt<6><<<g, b, 0, st>>>(p); break;
    }
}

extern "C" void kernel_launch(void* const* d_in, const int* in_sizes, int n_in,
                              void* d_out, int out_size, void* d_ws, size_t ws_size,
                              hipStream_t stream)
{
    const float* x       = (const float*)d_in[0];
    const float* norm_w  = (const float*)d_in[1];
    const float* w_in    = (const float*)d_in[2];
    const float* conv_w  = (const float*)d_in[3];
    const float* conv_b  = (const float*)d_in[4];
    const float* A_log   = (const float*)d_in[5];
    const float* dt_bias = (const float*)d_in[6];
    const float* D_skip  = (const float*)d_in[7];
    const float* w_out   = (const float*)d_in[8];
    const float* w_write = (const float*)d_in[9];
    const float* w_read  = (const float*)d_in[10];
    const float* decay   = (const float*)d_in[11];
    float* outp = (float*)d_out;

    // ---- workspace layout (lifetime overlays, ~244.9 MB) ----
    const size_t SZ_SCR  = 4096;
    const size_t SZ_DT   = (size_t)B_ * L_ * H_ * 4;
    const size_t SZ_CUML = 2048;
    const size_t SZ_WOUT = (size_t)D_ * DI_ * 2;
    const size_t SZ_WSML = (size_t)D_ * D_ * 2;
    const size_t SZ_R1   = (size_t)B_ * L_ * 2048 * 2;          // 33.5 MB
    const size_t SZ_R2   = SZ_R1;                               // 33.5 MB
    const size_t SZ_R3   = (size_t)B_ * L_ * 4096 * 2;          // 67.1 MB
    const size_t SZ_R4   = (size_t)B_ * L_ * D_ * 2 + (size_t)PROJ_ * D_ * 2; // 33.6 MB
    const size_t SZ_R5   = (size_t)B_ * L_ * 2048 * 4;          // 67.1 MB

    size_t o = 0;
    auto take = [&](size_t sz) { size_t r = o; o += (sz + 255) & ~(size_t)255; return r; };
    const size_t O_SCR = take(SZ_SCR);
    const size_t O_DT  = take(SZ_DT);
    const size_t O_LD  = take(SZ_DT);
    const size_t O_CUM = take(SZ_DT);
    const size_t O_CL  = take(SZ_CUML);
    const size_t O_WO  = take(SZ_WOUT);
    const size_t O_WW  = take(SZ_WSML);
    const size_t O_WR  = take(SZ_WSML);
    const size_t O_R1  = take(SZ_R1);
    const size_t O_R2  = take(SZ_R2);
    const size_t O_R3  = take(SZ_R3);
    const size_t O_R4  = take(SZ_R4);
    const size_t O_R5  = take(SZ_R5);
    const size_t NEED = o;
    if (ws_size < NEED) return;

    char* ws = (char*)d_ws;
    float* scr     = (float*)(ws + O_SCR);
    float* dt_raw  = (float*)(ws + O_DT);
    float* ld_g    = (float*)(ws + O_LD);
    float* cum_g   = (float*)(ws + O_CUM);
    float* cumlast = (float*)(ws + O_CL);
    bf16*  w_out_b   = (bf16*)(ws + O_WO);
    bf16*  w_write_b = (bf16*)(ws + O_WW);
    bf16*  w_read_b  = (bf16*)(ws + O_WR);

    // R1: val_b -> vTw_g -> (yg_b | hst_b) -> Sm_b + intra_b
    bf16*  val_b   = (bf16*)(ws + O_R1);
    bf16*  vTw_g   = (bf16*)(ws + O_R1);
    bf16*  yg_b    = (bf16*)(ws + O_R1);
    bf16*  hst_b   = (bf16*)(ws + O_R1 + (size_t)B_ * L_ * D_ * 2);   // 16.8 MB slot
    bf16*  Sm_b    = (bf16*)(ws + O_R1);
    bf16*  intra_b = (bf16*)(ws + O_R1 + (size_t)NC_ * B_ * MC_ * MC_ * 2);
    // R2: gate_b -> out_b + wk_b/reads_b
    bf16*  gate_b  = (bf16*)(ws + O_R2);
    bf16*  out_b   = (bf16*)(ws + O_R2);
    bf16*  wk_b    = (bf16*)(ws + O_R2 + (size_t)B_ * L_ * D_ * 2);
    bf16*  reads_b = wk_b;
    // R3: bc_b -> UwW
    bf16*  bc_b    = (bf16*)(ws + O_R3);
    bf16*  UwW     = (bf16*)(ws + O_R3);
    // R4: xn_b + w_in_b -> vconv_b -> U_ssd -> outf
    bf16*  xn_b    = (bf16*)(ws + O_R4);
    bf16*  w_in_b  = (bf16*)(ws + O_R4 + (size_t)B_ * L_ * D_ * 2);
    bf16*  vconv_b = (bf16*)(ws + O_R4);
    float* U_ssd   = (float*)(ws + O_R4);
    float* outf    = (float*)(ws + O_R4);
    // R5: vT_g + BT_g -> vbuf + vTm + wkgT
    bf16*  vT_g    = (bf16*)(ws + O_R5);
    bf16*  BT_g    = (bf16*)(ws + O_R5 + (size_t)B_ * L_ * 2048 * 2);
    float* vbuf    = (float*)(ws + O_R5);
    bf16*  vTm     = (bf16*)(ws + O_R5 + (size_t)B_ * L_ * D_ * 4);
    bf16*  wkgT    = (bf16*)(ws + O_R5 + (size_t)B_ * L_ * D_ * 4 + (size_t)B_ * L_ * D_ * 2);

    const long BLD  = (long)B_ * L_ * D_;
    const long BLDI = (long)B_ * L_ * DI_;

    k_gamma<<<1, 256, 0, stream>>>(decay, scr);
    k_f2b<<<cdiv_i((long)PROJ_ * D_ / 4, 256), 256, 0, stream>>>(w_in, w_in_b, (long)PROJ_ * D_ / 4);
    k_f2b<<<cdiv_i((long)D_ * DI_ / 4, 256), 256, 0, stream>>>(w_out, w_out_b, (long)D_ * DI_ / 4);
    k_f2b<<<cdiv_i((long)D_ * D_ / 4, 256), 256, 0, stream>>>(w_write, w_write_b, (long)D_ * D_ / 4);
    k_f2b<<<cdiv_i((long)D_ * D_ / 4, 256), 256, 0, stream>>>(w_read, w_read_b, (long)D_ * D_ / 4);
    k_rmsnorm<<<B_ * L_, 256, 0, stream>>>(x, norm_w, xn_b);
    // proj
    run_gemm(stream, 2, xn_b, w_in_b, dt_raw, val_b, gate_b, bc_b, nullptr, nullptr, nullptr, nullptr,
             B_ * L_, PROJ_, D_, D_, D_, 0, 1, 1, 0, 0, 0, 0, 0, 0);
    k_ld<<<cdiv_i((long)B_ * L_ * H_, 256), 256, 0, stream>>>(dt_raw, dt_bias, A_log, ld_g);
    k_cum<<<B_ * NC_ * H_, 256, 0, stream>>>(ld_g, cum_g, cumlast);
    k_conv<<<cdiv_i(BLDI, 256), 256, 0, stream>>>(val_b, conv_w, conv_b, vconv_b);
    // transposes for SSD MFMA
    k_vt<<<dim3(L_ / 32, DI_ / 32, B_), 256, 0, stream>>>(vconv_b, cum_g, cumlast, vT_g, vTw_g);
    k_bt<<<dim3(L_ / 32, DI_ / 32, B_), 256, 0, stream>>>(bc_b, BT_g);
    // SSD
    k_ssd_u2<<<B_ * NC_ * H_, 256, 0, stream>>>(vTw_g, BT_g, U_ssd);
    k_ssd2<<<cdiv_i((long)B_ * H_ * HD_ * N_, 256), 256, 0, stream>>>(U_ssd, cumlast, hst_b);
    k_ssd_y<<<B_ * NC_ * H_, 256, 0, stream>>>(bc_b, vT_g, hst_b, cum_g, D_skip, gate_b, yg_b);
    // out projection
    run_gemm(stream, 1, yg_b, w_out_b, outf, out_b, nullptr, nullptr, nullptr, nullptr, nullptr, nullptr,
             B_ * L_, D_, DI_, DI_, DI_, D_, 1, 1, 0, 0, 0, 0, 0, 0);
    // memory scan
    k_shift<<<cdiv_i(BLD, 256), 256, 0, stream>>>(out_b, wk_b);
    run_gemm(stream, 0, out_b, w_write_b, vbuf, nullptr, nullptr, nullptr, nullptr, nullptr, nullptr, nullptr,
             B_ * L_, D_, D_, D_, D_, D_, 1, 1, 0, 0, 0, 0, 0, 0);
    k_transpose<<<dim3(L_ / 32, D_ / 32, B_), 256, 0, stream>>>(vbuf, vTm);
    k_trans_wkg<<<dim3(L_ / 32, D_ / 32, B_), 256, 0, stream>>>(outf, scr, wkgT);
    run_gemm(stream, 6, vTm, wkgT, nullptr, UwW, nullptr, nullptr, nullptr, nullptr, nullptr, nullptr,
             D_, D_, MC_, L_, L_, D_, B_ * NC_, NC_,
             (long)D_ * L_, MC_, (long)D_ * L_, MC_, (long)D_ * D_, (long)B_ * D_ * D_);
    k_m2<<<cdiv_i((long)B_ * D_ * D_, 256), 256, 0, stream>>>(UwW, scr);
    run_gemm(stream, 3, out_b, wk_b, nullptr, Sm_b, nullptr, nullptr, nullptr, nullptr, nullptr, scr,
             MC_, MC_, D_, D_, D_, MC_, B_ * NC_, NC_,
             (long)L_ * D_, (long)MC_ * D_, (long)L_ * D_, (long)MC_ * D_,
             (long)MC_ * MC_, (long)B_ * MC_ * MC_);
    run_gemm(stream, 6, Sm_b, vTm, nullptr, intra_b, nullptr, nullptr, nullptr, nullptr, nullptr, nullptr,
             MC_, D_, MC_, MC_, L_, D_, B_ * NC_, NC_,
             (long)MC_ * MC_, (long)B_ * MC_ * MC_, (long)D_ * L_, MC_,
             (long)L_ * D_, (long)MC_ * D_);
    run_gemm(stream, 4, out_b, UwW, nullptr, reads_b, nullptr, nullptr, nullptr, nullptr, intra_b, scr,
             MC_, D_, D_, D_, D_, D_, B_ * NC_, NC_,
             (long)L_ * D_, (long)MC_ * D_, (long)D_ * D_, (long)B_ * D_ * D_,
             (long)L_ * D_, (long)MC_ * D_);
    run_gemm(stream, 5, reads_b, w_read_b, outp, nullptr, nullptr, nullptr, x, outf, nullptr, nullptr,
             B_ * L_, D_, D_, D_, D_, D_, 1, 1, 0, 0, 0, 0, 0, 0);
}

// Round 4
// 907.986 us; speedup vs baseline: 2.1945x; 1.0312x over previous
//
#include <hip/hip_runtime.h>
#include <hip/hip_bf16.h>

typedef __hip_bfloat16 bf16;
typedef __attribute__((ext_vector_type(8))) short short8;
typedef __attribute__((ext_vector_type(4))) float floatx4;

#define B_ 2
#define L_ 4096
#define D_ 1024
#define DI_ 2048
#define H_ 16
#define HD_ 128
#define N_ 128
#define CS_ 256
#define MC_ 256
#define NC_ 16
#define PROJ_ 8208

__device__ __forceinline__ float bf2f(short s) {
    return __uint_as_float(((unsigned)(unsigned short)s) << 16);
}

__device__ __forceinline__ void gl_lds16(const void* g, void* s) {
    __builtin_amdgcn_global_load_lds(
        (const __attribute__((address_space(1))) void*)g,
        (__attribute__((address_space(3))) void*)s, 16, 0, 0);
}

// ---------------------------------------------------------------------------
// Generic bf16 MFMA GEMM: C[M,N] = A[M,K] @ Bt[N,K]^T  (both row-major, K contig)
// 128x128 tile, 4 waves, global_load_lds(16B) staging, GROUP_M=8 L2 swizzle.
// ---------------------------------------------------------------------------
struct GemmP {
    const bf16* A; const bf16* Bt;
    float* C; bf16* CB; bf16* CB2; bf16* CB3;
    const float* add0; const float* add1; const bf16* add0b; const float* scr;
    long lda, ldb, ldc;
    int M, N, K, zinner;
    long a_zo, a_zi, b_zo, b_zi, c_zo, c_zi;
};

template<int EPI>
__global__ __launch_bounds__(256, 2) void gemm_bt(GemmP p)
{
    int z = blockIdx.z;
    int zo = z / p.zinner, zi = z % p.zinner;
    const bf16* A  = p.A  + (long)zo * p.a_zo + (long)zi * p.a_zi;
    const bf16* Bt = p.Bt + (long)zo * p.b_zo + (long)zi * p.b_zi;
    long coff = (long)zo * p.c_zo + (long)zi * p.c_zi;

    __shared__ __align__(16) bf16 As[128 * 64];
    __shared__ __align__(16) bf16 Bs[128 * 64];

    // L2 supertile swizzle (GROUP_M=8 along y)
    int nbx = gridDim.x, nby = gridDim.y;
    int pid = blockIdx.y * nbx + blockIdx.x;
    const int GRP = 8;
    int span = GRP * nbx;
    int grp = pid / span;
    int first = grp * GRP;
    int gsz = min(GRP, nby - first);
    int pin = pid - grp * span;
    int pid_m = first + pin % gsz;
    int pid_n = pin / gsz;
    int m0 = pid_m * 128, n0 = pid_n * 128;

    int tid = threadIdx.x;
    int lane = tid & 63, wave = tid >> 6;
    int wm = (wave >> 1) * 64, wn = (wave & 1) * 64;
    int r16 = lane & 15, q8 = (lane >> 4) * 8;

    floatx4 zero4 = {0.f, 0.f, 0.f, 0.f};
    floatx4 acc[4][4];
#pragma unroll
    for (int i = 0; i < 4; i++)
#pragma unroll
        for (int j = 0; j < 4; j++) acc[i][j] = zero4;

    // staging geometry: per wave 4 insts for A, 4 for B; each inst = 8 rows x 64 cols
    int lrow = lane >> 3;            // 0..7
    int lcol = (lane & 7) * 8;       // element col
    int wrow = wave * 32;

    for (int k0 = 0; k0 < p.K; k0 += 64) {
#pragma unroll
        for (int t = 0; t < 4; t++) {
            int row = wrow + t * 8 + lrow;
            gl_lds16(A + (long)(m0 + row) * p.lda + k0 + lcol, &As[(wrow + t * 8) * 64]);
            int bn = n0 + row; if (bn > p.N - 1) bn = p.N - 1;
            gl_lds16(Bt + (long)bn * p.ldb + k0 + lcol, &Bs[(wrow + t * 8) * 64]);
        }
        __syncthreads();
#pragma unroll
        for (int ks = 0; ks < 64; ks += 32) {
            short8 af[4], bq[4];
#pragma unroll
            for (int i = 0; i < 4; i++)
                af[i] = *(const short8*)&As[(wm + i * 16 + r16) * 64 + ks + q8];
#pragma unroll
            for (int j = 0; j < 4; j++)
                bq[j] = *(const short8*)&Bs[(wn + j * 16 + r16) * 64 + ks + q8];
#pragma unroll
            for (int i = 0; i < 4; i++)
#pragma unroll
                for (int j = 0; j < 4; j++)
                    acc[i][j] = __builtin_amdgcn_mfma_f32_16x16x32_bf16(af[i], bq[j], acc[i][j], 0, 0, 0);
        }
        __syncthreads();
    }

    int rq = (lane >> 4) * 4;
#pragma unroll
    for (int i = 0; i < 4; i++) {
#pragma unroll
        for (int j = 0; j < 4; j++) {
#pragma unroll
            for (int r = 0; r < 4; r++) {
                int gm = m0 + wm + i * 16 + rq + r;
                int gn = n0 + wn + j * 16 + r16;
                if (gm >= p.M || gn >= p.N) continue;
                float a = acc[i][j][r];
                if (EPI == 0) {
                    p.C[coff + (long)gm * p.ldc + gn] = a;
                } else if (EPI == 1) {
                    long ix = coff + (long)gm * p.ldc + gn;
                    p.C[ix] = a; p.CB[ix] = __float2bfloat16(a);
                } else if (EPI == 2) {                // proj 4-way split
                    if (gn < 2048)      p.CB [(long)gm * 2048 + gn]          = __float2bfloat16(a);
                    else if (gn < 4096) p.CB2[(long)gm * 2048 + (gn - 2048)] = __float2bfloat16(a);
                    else if (gn < 8192) p.CB3[(long)gm * 4096 + (gn - 4096)] = __float2bfloat16(a);
                    else                p.C  [(long)gm * 16   + (gn - 8192)] = a;
                } else if (EPI == 3) {                // Mmem causal decay mask -> bf16
                    float lg = p.scr[1];
                    float v = (gm > gn) ? a * __expf((float)(gm - 1 - gn) * lg) : 0.f;
                    p.CB[coff + (long)gm * p.ldc + gn] = __float2bfloat16(v);
                } else if (EPI == 4) {                // inter: acc*gp[m] + intra(bf16) -> bf16
                    long ix = coff + (long)gm * p.ldc + gn;
                    float t = a * p.scr[16 + gm] + __bfloat162float(p.add0b[ix]);
                    p.CB[ix] = __float2bfloat16(t);
                } else if (EPI == 5) {                // final: x + out + 0.5*acc
                    long ix = (long)gm * p.ldc + gn;
                    p.C[ix] = p.add0[ix] + p.add1[ix] + 0.5f * a;
                } else if (EPI == 6) {                // bf16 only
                    p.CB[coff + (long)gm * p.ldc + gn] = __float2bfloat16(a);
                }
            }
        }
    }
}

// ---------------------------------------------------------------------------
// Elementwise / helper kernels
// ---------------------------------------------------------------------------
__global__ void k_gamma(const float* decay, float* scr)
{
    int t = threadIdx.x;
    float g = 1.f / (1.f + expf(-decay[0]));
    float lg = logf(g);
    if (t == 0) { scr[0] = g; scr[1] = lg; scr[2] = expf(256.f * lg); }
    scr[16 + t]  = expf(lg * (float)t);          // gp
    scr[272 + t] = expf(lg * (float)(255 - t));  // gw
}

__global__ void k_f2b(const float* __restrict__ s, bf16* __restrict__ d, long n4)
{
    long i = (long)blockIdx.x * 256 + threadIdx.x;
    if (i >= n4) return;
    float4 v = ((const float4*)s)[i];
    bf16* o = d + i * 4;
    o[0] = __float2bfloat16(v.x); o[1] = __float2bfloat16(v.y);
    o[2] = __float2bfloat16(v.z); o[3] = __float2bfloat16(v.w);
}

__global__ __launch_bounds__(256) void k_rmsnorm(const float* __restrict__ x,
                                                 const float* __restrict__ w,
                                                 bf16* __restrict__ o)
{
    int row = blockIdx.x, t = threadIdx.x;
    float4 xv = ((const float4*)(x + (long)row * D_))[t];
    float s = xv.x*xv.x + xv.y*xv.y + xv.z*xv.z + xv.w*xv.w;
#pragma unroll
    for (int m = 32; m > 0; m >>= 1) s += __shfl_xor(s, m, 64);
    __shared__ float ps[4];
    if ((t & 63) == 0) ps[t >> 6] = s;
    __syncthreads();
    s = ps[0] + ps[1] + ps[2] + ps[3];
    float r = rsqrtf(s * (1.f / (float)D_) + 1e-6f);
    float4 wv = ((const float4*)w)[t];
    bf16* orow = o + (long)row * D_ + t * 4;
    orow[0] = __float2bfloat16(xv.x * r * wv.x);
    orow[1] = __float2bfloat16(xv.y * r * wv.y);
    orow[2] = __float2bfloat16(xv.z * r * wv.z);
    orow[3] = __float2bfloat16(xv.w * r * wv.w);
}

__global__ void k_ld(const float* __restrict__ dtr, const float* __restrict__ dt_bias,
                     const float* __restrict__ A_log, float* __restrict__ ld)
{
    long i = (long)blockIdx.x * 256 + threadIdx.x;
    if (i >= (long)B_ * L_ * H_) return;
    int h = (int)(i & 15);
    float d = dtr[i] + dt_bias[h];
    float sp = (d > 20.f) ? d : log1pf(__expf(d));
    ld[i] = -__expf(A_log[h]) * sp;
}

__global__ __launch_bounds__(256) void k_cum(const float* __restrict__ ld,
                                             float* __restrict__ cum_g,
                                             float* __restrict__ cumlast)
{
    int bid = blockIdx.x;           // b*256 + c*16 + h
    int h = bid & 15, c = (bid >> 4) & 15, b = bid >> 8;
    long rowbase = (long)b * L_ + c * CS_;
    int tid = threadIdx.x;
    __shared__ float cum_s[256];
    cum_s[tid] = ld[(rowbase + tid) * H_ + h];
    __syncthreads();
    for (int off = 1; off < 256; off <<= 1) {
        float add = (tid >= off) ? cum_s[tid - off] : 0.f;
        __syncthreads();
        cum_s[tid] += add;
        __syncthreads();
    }
    cum_g[(rowbase + tid) * H_ + h] = cum_s[tid];
    if (tid == 255) cumlast[bid] = cum_s[255];
}

__global__ void k_conv(const bf16* __restrict__ val_b, const float* __restrict__ cw,
                       const float* __restrict__ cb, bf16* __restrict__ vo)
{
    long idx = (long)blockIdx.x * 256 + threadIdx.x;
    if (idx >= (long)B_ * L_ * DI_) return;
    long row = idx >> 11; int ch = (int)(idx & 2047);
    int l = (int)(row & (L_ - 1));
    float acc = cb[ch];
#pragma unroll
    for (int k = 0; k < 4; k++) {
        int ls = l - 3 + k;
        if (ls >= 0) acc += cw[ch * 4 + k] * __bfloat162float(val_b[(row - 3 + k) * 2048 + ch]);
    }
    float s = acc / (1.f + __expf(-acc));
    vo[idx] = __float2bfloat16(s);
}

// vconv [b*L][2048] -> vT [b*2048 + d][L] bf16, plus decay-weighted vTw
__global__ void k_vt(const bf16* __restrict__ vconv, const float* __restrict__ cum_g,
                     const float* __restrict__ cumlast, bf16* __restrict__ vT,
                     bf16* __restrict__ vTw)
{
    __shared__ bf16 tile[32][33];
    int b = blockIdx.z;
    int r0 = blockIdx.x * 32, c0 = blockIdx.y * 32;
    int tx = threadIdx.x & 31, ty = threadIdx.x >> 5;
    for (int i = 0; i < 32; i += 8)
        tile[ty + i][tx] = vconv[((long)b * L_ + r0 + ty + i) * 2048 + c0 + tx];
    __syncthreads();
    int l = r0 + tx;
    int h = c0 >> 7;
    float w = __expf(cumlast[b * 256 + (l >> 8) * 16 + h] - cum_g[((long)b * L_ + l) * 16 + h]);
    for (int i = 0; i < 32; i += 8) {
        int col = c0 + ty + i;
        long oidx = ((long)b * 2048 + col) * L_ + l;
        bf16 v = tile[tx][ty + i];
        vT[oidx] = v;
        vTw[oidx] = __float2bfloat16(__bfloat162float(v) * w);
    }
}

// bc_b B-part [b*L][4096 cols 0..2047] -> BT [b*2048 + col][L]
__global__ void k_bt(const bf16* __restrict__ bc, bf16* __restrict__ BT)
{
    __shared__ bf16 tile[32][33];
    int b = blockIdx.z;
    int r0 = blockIdx.x * 32, c0 = blockIdx.y * 32;
    int tx = threadIdx.x & 31, ty = threadIdx.x >> 5;
    for (int i = 0; i < 32; i += 8)
        tile[ty + i][tx] = bc[((long)b * L_ + r0 + ty + i) * 4096 + c0 + tx];
    __syncthreads();
    int l = r0 + tx;
    for (int i = 0; i < 32; i += 8) {
        int col = c0 + ty + i;
        BT[((long)b * 2048 + col) * L_ + l] = tile[tx][ty + i];
    }
}

// U[c][b][h][d][n] = sum_t (v*w)[t,d] B[t,n]  — MFMA, global fragments
__global__ __launch_bounds__(256, 2) void k_ssd_u2(
    const bf16* __restrict__ vTw, const bf16* __restrict__ BT, float* __restrict__ U)
{
    int bid = blockIdx.x;
    int h = bid & 15, c = (bid >> 4) & 15, b = bid >> 8;
    int lane = threadIdx.x & 63, wave = threadIdx.x >> 6;
    int r16 = lane & 15, q8 = (lane >> 4) * 8, rq = (lane >> 4) * 4;
    int d0 = (wave >> 1) * 64, n0 = (wave & 1) * 64;
    const bf16* vb = vTw + ((long)b * 2048 + h * 128) * L_ + c * 256;
    const bf16* bb = BT  + ((long)b * 2048 + h * 128) * L_ + c * 256;
    floatx4 zero4 = {0.f, 0.f, 0.f, 0.f};
    floatx4 acc[4][4];
#pragma unroll
    for (int i = 0; i < 4; i++)
#pragma unroll
        for (int j = 0; j < 4; j++) acc[i][j] = zero4;
#pragma unroll 2
    for (int ks = 0; ks < 8; ks++) {
        short8 af[4], bq[4];
#pragma unroll
        for (int i = 0; i < 4; i++)
            af[i] = *(const short8*)(vb + (long)(d0 + i * 16 + r16) * L_ + ks * 32 + q8);
#pragma unroll
        for (int j = 0; j < 4; j++)
            bq[j] = *(const short8*)(bb + (long)(n0 + j * 16 + r16) * L_ + ks * 32 + q8);
#pragma unroll
        for (int i = 0; i < 4; i++)
#pragma unroll
            for (int j = 0; j < 4; j++)
                acc[i][j] = __builtin_amdgcn_mfma_f32_16x16x32_bf16(af[i], bq[j], acc[i][j], 0, 0, 0);
    }
    float* up = U + (((long)c * B_ + b) * H_ + h) * 16384;
#pragma unroll
    for (int i = 0; i < 4; i++)
#pragma unroll
        for (int j = 0; j < 4; j++)
#pragma unroll
            for (int r = 0; r < 4; r++)
                up[(d0 + i * 16 + rq + r) * 128 + (n0 + j * 16 + r16)] = acc[i][j][r];
}

// h recurrence -> bf16 states entering each chunk
__global__ void k_ssd2(const float* __restrict__ U, const float* __restrict__ cumlast,
                       bf16* __restrict__ hst)
{
    long idx = (long)blockIdx.x * 256 + threadIdx.x;
    const long tot = (long)B_ * H_ * HD_ * N_;
    if (idx >= tot) return;
    int bh = (int)(idx >> 14);
    int b = bh >> 4, h = bh & 15;
    float hv = 0.f;
    for (int c = 0; c < NC_; c++) {
        hst[c * tot + idx] = __float2bfloat16(hv);
        float ef = __expf(cumlast[b * 256 + c * 16 + h]);
        hv = ef * hv + U[c * tot + idx];
    }
}

// Fused intra+inter SSD output, flash-style MFMA. Writes gated bf16 yg.
__global__ __launch_bounds__(256, 2) void k_ssd_y(
    const bf16* __restrict__ bc_b, const bf16* __restrict__ vT,
    const bf16* __restrict__ hst, const float* __restrict__ cum_g,
    const float* __restrict__ Dskip, const bf16* __restrict__ gate_b,
    bf16* __restrict__ yg)
{
    int bid = blockIdx.x;
    int h = bid & 15, c = (bid >> 4) & 15, b = bid >> 8;
    long rowbase = (long)b * L_ + c * CS_;
    int tid = threadIdx.x, lane = tid & 63, wave = tid >> 6;
    int r16 = lane & 15, q8 = (lane >> 4) * 8, rq = (lane >> 4) * 4;
    int wt = (wave >> 1) * 32, wmS = (wave & 1) * 32, wd = (wave & 1) * 64;

    __shared__ float cum_s[256];
    __shared__ __align__(16) bf16 Ss[64][72];

    cum_s[tid] = cum_g[(rowbase + tid) * H_ + h];
    __syncthreads();

    const bf16* Cb  = bc_b + rowbase * 4096 + 2048 + h * 128;
    const bf16* Bb  = bc_b + rowbase * 4096 + h * 128;
    const bf16* vTb = vT + ((long)b * 2048 + h * 128) * L_ + c * 256;
    const bf16* hp  = hst + (((long)c * B_ + b) * H_ + h) * 16384;

    floatx4 zero4 = {0.f, 0.f, 0.f, 0.f};

    for (int tt = 0; tt < 4; tt++) {
        int tbase = tt * 64;
        short8 caf[2][4];
#pragma unroll
        for (int i = 0; i < 2; i++)
#pragma unroll
            for (int ks = 0; ks < 4; ks++)
                caf[i][ks] = *(const short8*)(Cb + (long)(tbase + wt + i * 16 + r16) * 4096 + ks * 32 + q8);

        // ---- inter: yacc = C @ hprev^T, scaled by exp(cum[t]) ----
        floatx4 yacc[2][4];
#pragma unroll
        for (int i = 0; i < 2; i++)
#pragma unroll
            for (int j = 0; j < 4; j++) yacc[i][j] = zero4;
#pragma unroll
        for (int ks = 0; ks < 4; ks++)
#pragma unroll
            for (int j = 0; j < 4; j++) {
                short8 hq = *(const short8*)(hp + (long)(wd + j * 16 + r16) * 128 + ks * 32 + q8);
#pragma unroll
                for (int i = 0; i < 2; i++)
                    yacc[i][j] = __builtin_amdgcn_mfma_f32_16x16x32_bf16(caf[i][ks], hq, yacc[i][j], 0, 0, 0);
            }
        float texp[2][4];
#pragma unroll
        for (int i = 0; i < 2; i++)
#pragma unroll
            for (int r = 0; r < 4; r++)
                texp[i][r] = __expf(cum_s[tbase + wt + i * 16 + rq + r]);
#pragma unroll
        for (int i = 0; i < 2; i++)
#pragma unroll
            for (int j = 0; j < 4; j++)
#pragma unroll
                for (int r = 0; r < 4; r++) yacc[i][j][r] *= texp[i][r];

        // ---- intra m-loop ----
        for (int mt = 0; mt <= tt; mt++) {
            int mbase = mt * 64;
            floatx4 sacc[2][2];
#pragma unroll
            for (int i = 0; i < 2; i++)
#pragma unroll
                for (int j = 0; j < 2; j++) sacc[i][j] = zero4;
#pragma unroll
            for (int ks = 0; ks < 4; ks++) {
                short8 bq[2];
#pragma unroll
                for (int j = 0; j < 2; j++)
                    bq[j] = *(const short8*)(Bb + (long)(mbase + wmS + j * 16 + r16) * 4096 + ks * 32 + q8);
#pragma unroll
                for (int i = 0; i < 2; i++)
#pragma unroll
                    for (int j = 0; j < 2; j++)
                        sacc[i][j] = __builtin_amdgcn_mfma_f32_16x16x32_bf16(caf[i][ks], bq[j], sacc[i][j], 0, 0, 0);
            }
            __syncthreads();
#pragma unroll
            for (int i = 0; i < 2; i++)
#pragma unroll
                for (int r = 0; r < 4; r++) {
                    int trow = wt + i * 16 + rq + r;
                    float ct = cum_s[tbase + trow];
#pragma unroll
                    for (int j = 0; j < 2; j++) {
                        int mcol = mbase + wmS + j * 16 + r16;
                        float val = (mcol <= tbase + trow) ? sacc[i][j][r] * __expf(ct - cum_s[mcol]) : 0.f;
                        Ss[trow][wmS + j * 16 + r16] = __float2bfloat16(val);
                    }
                }
            __syncthreads();
#pragma unroll
            for (int ks = 0; ks < 2; ks++) {
                short8 saf[2];
#pragma unroll
                for (int i = 0; i < 2; i++)
                    saf[i] = *(const short8*)&Ss[wt + i * 16 + r16][ks * 32 + q8];
#pragma unroll
                for (int j = 0; j < 4; j++) {
                    short8 vq = *(const short8*)(vTb + (long)(wd + j * 16 + r16) * L_ + mbase + ks * 32 + q8);
#pragma unroll
                    for (int i = 0; i < 2; i++)
                        yacc[i][j] = __builtin_amdgcn_mfma_f32_16x16x32_bf16(saf[i], vq, yacc[i][j], 0, 0, 0);
                }
            }
        }
        // ---- epilogue ----
#pragma unroll
        for (int i = 0; i < 2; i++)
#pragma unroll
            for (int r = 0; r < 4; r++) {
                int t = tbase + wt + i * 16 + rq + r;
                long grow = (rowbase + t) * 2048 + h * 128;
#pragma unroll
                for (int j = 0; j < 4; j++) {
                    int d = wd + j * 16 + r16;
                    float vv = __bfloat162float(vTb[(long)d * L_ + t]);
                    float y = yacc[i][j][r] + Dskip[h * 128 + d] * vv;
                    float g = __bfloat162float(gate_b[grow + d]);
                    float sg = g / (1.f + __expf(-g));
                    yg[grow + d] = __float2bfloat16(y * sg);
                }
            }
    }
}

__global__ void k_shift(const bf16* __restrict__ ob, bf16* __restrict__ wk)
{
    long idx = (long)blockIdx.x * 256 + threadIdx.x;
    if (idx >= (long)B_ * L_ * D_) return;
    int l = (int)((idx >> 10) & (L_ - 1));
    wk[idx] = (l == 0) ? __float2bfloat16(0.f) : ob[idx - D_];
}

__global__ void k_transpose(const float* __restrict__ srcg, bf16* __restrict__ dstg)
{
    __shared__ float t[32][33];
    int b = blockIdx.z;
    const float* src = srcg + (long)b * L_ * D_;
    bf16* dst = dstg + (long)b * D_ * L_;
    int r0 = blockIdx.x * 32, c0 = blockIdx.y * 32;
    int tx = threadIdx.x & 31, ty = threadIdx.x >> 5;
    for (int i = 0; i < 32; i += 8)
        t[ty + i][tx] = src[(long)(r0 + ty + i) * D_ + c0 + tx];
    __syncthreads();
    for (int i = 0; i < 32; i += 8)
        dst[(long)(c0 + ty + i) * L_ + r0 + tx] = __float2bfloat16(t[tx][ty + i]);
}

__global__ void k_trans_wkg(const float* __restrict__ outg, const float* __restrict__ scr,
                            bf16* __restrict__ dstg)
{
    __shared__ float t[32][33];
    int b = blockIdx.z;
    const float* src = outg + (long)b * L_ * D_;
    bf16* dst = dstg + (long)b * D_ * L_;
    int r0 = blockIdx.x * 32, c0 = blockIdx.y * 32;
    int tx = threadIdx.x & 31, ty = threadIdx.x >> 5;
    for (int i = 0; i < 32; i += 8) {
        int rr = r0 + ty + i;
        float g = scr[272 + (rr & 255)];
        t[ty + i][tx] = (rr == 0) ? 0.f : src[(long)(rr - 1) * D_ + c0 + tx] * g;
    }
    __syncthreads();
    for (int i = 0; i < 32; i += 8)
        dst[(long)(c0 + ty + i) * L_ + r0 + tx] = __float2bfloat16(t[tx][ty + i]);
}

// W recurrence, in place
__global__ void k_m2(bf16* __restrict__ UwW, const float* __restrict__ scr)
{
    long idx = (long)blockIdx.x * 256 + threadIdx.x;
    const long tot = (long)B_ * D_ * D_;
    if (idx >= tot) return;
    float gMC = scr[2];
    float w = 0.f;
    for (int c = 0; c < NC_; c++) {
        float tmp = __bfloat162float(UwW[c * tot + idx]);
        UwW[c * tot + idx] = __float2bfloat16(w);
        w = gMC * w + tmp;
    }
}

// ---------------------------------------------------------------------------
// Host side
// ---------------------------------------------------------------------------
static inline int cdiv_i(long a, long b) { return (int)((a + b - 1) / b); }

static void run_gemm(hipStream_t st, int epi, const bf16* A, const bf16* Bt,
                     float* C, bf16* CB, bf16* CB2, bf16* CB3,
                     const float* add0, const float* add1, const bf16* add0b,
                     const float* scr, int M, int N, int K,
                     long lda, long ldb, long ldc, int nbatch, int zinner,
                     long a_zo, long a_zi, long b_zo, long b_zi, long c_zo, long c_zi)
{
    GemmP p;
    p.A = A; p.Bt = Bt; p.C = C; p.CB = CB; p.CB2 = CB2; p.CB3 = CB3;
    p.add0 = add0; p.add1 = add1; p.add0b = add0b; p.scr = scr;
    p.lda = lda; p.ldb = ldb; p.ldc = ldc;
    p.M = M; p.N = N; p.K = K; p.zinner = zinner;
    p.a_zo = a_zo; p.a_zi = a_zi; p.b_zo = b_zo; p.b_zi = b_zi; p.c_zo = c_zo; p.c_zi = c_zi;
    dim3 g(cdiv_i(N, 128), cdiv_i(M, 128), nbatch);
    dim3 b(256);
    switch (epi) {
        case 0: gemm_bt<0><<<g, b, 0, st>>>(p); break;
        case 1: gemm_bt<1><<<g, b, 0, st>>>(p); break;
        case 2: gemm_bt<2><<<g, b, 0, st>>>(p); break;
        case 3: gemm_bt<3><<<g, b, 0, st>>>(p); break;
        case 4: gemm_bt<4><<<g, b, 0, st>>>(p); break;
        case 5: gemm_bt<5><<<g, b, 0, st>>>(p); break;
        case 6: gemm_bt<6><<<g, b, 0, st>>>(p); break;
    }
}

extern "C" void kernel_launch(void* const* d_in, const int* in_sizes, int n_in,
                              void* d_out, int out_size, void* d_ws, size_t ws_size,
                              hipStream_t stream)
{
    const float* x       = (const float*)d_in[0];
    const float* norm_w  = (const float*)d_in[1];
    const float* w_in    = (const float*)d_in[2];
    const float* conv_w  = (const float*)d_in[3];
    const float* conv_b  = (const float*)d_in[4];
    const float* A_log   = (const float*)d_in[5];
    const float* dt_bias = (const float*)d_in[6];
    const float* D_skip  = (const float*)d_in[7];
    const float* w_out   = (const float*)d_in[8];
    const float* w_write = (const float*)d_in[9];
    const float* w_read  = (const float*)d_in[10];
    const float* decay   = (const float*)d_in[11];
    float* outp = (float*)d_out;

    // ---- workspace layout (lifetime overlays, ~244.9 MB) ----
    const size_t SZ_SCR  = 4096;
    const size_t SZ_DT   = (size_t)B_ * L_ * H_ * 4;
    const size_t SZ_CUML = 2048;
    const size_t SZ_WOUT = (size_t)D_ * DI_ * 2;
    const size_t SZ_WSML = (size_t)D_ * D_ * 2;
    const size_t SZ_R1   = (size_t)B_ * L_ * 2048 * 2;
    const size_t SZ_R2   = SZ_R1;
    const size_t SZ_R3   = (size_t)B_ * L_ * 4096 * 2;
    const size_t SZ_R4   = (size_t)B_ * L_ * D_ * 2 + (size_t)PROJ_ * D_ * 2;
    const size_t SZ_R5   = (size_t)B_ * L_ * 2048 * 4;

    size_t o = 0;
    auto take = [&](size_t sz) { size_t r = o; o += (sz + 255) & ~(size_t)255; return r; };
    const size_t O_SCR = take(SZ_SCR);
    const size_t O_DT  = take(SZ_DT);
    const size_t O_LD  = take(SZ_DT);
    const size_t O_CUM = take(SZ_DT);
    const size_t O_CL  = take(SZ_CUML);
    const size_t O_WO  = take(SZ_WOUT);
    const size_t O_WW  = take(SZ_WSML);
    const size_t O_WR  = take(SZ_WSML);
    const size_t O_R1  = take(SZ_R1);
    const size_t O_R2  = take(SZ_R2);
    const size_t O_R3  = take(SZ_R3);
    const size_t O_R4  = take(SZ_R4);
    const size_t O_R5  = take(SZ_R5);
    const size_t NEED = o;
    if (ws_size < NEED) return;

    char* ws = (char*)d_ws;
    float* scr     = (float*)(ws + O_SCR);
    float* dt_raw  = (float*)(ws + O_DT);
    float* ld_g    = (float*)(ws + O_LD);
    float* cum_g   = (float*)(ws + O_CUM);
    float* cumlast = (float*)(ws + O_CL);
    bf16*  w_out_b   = (bf16*)(ws + O_WO);
    bf16*  w_write_b = (bf16*)(ws + O_WW);
    bf16*  w_read_b  = (bf16*)(ws + O_WR);

    bf16*  val_b   = (bf16*)(ws + O_R1);
    bf16*  vTw_g   = (bf16*)(ws + O_R1);
    bf16*  yg_b    = (bf16*)(ws + O_R1);
    bf16*  hst_b   = (bf16*)(ws + O_R1 + (size_t)B_ * L_ * D_ * 2);
    bf16*  Sm_b    = (bf16*)(ws + O_R1);
    bf16*  intra_b = (bf16*)(ws + O_R1 + (size_t)NC_ * B_ * MC_ * MC_ * 2);
    bf16*  gate_b  = (bf16*)(ws + O_R2);
    bf16*  out_b   = (bf16*)(ws + O_R2);
    bf16*  wk_b    = (bf16*)(ws + O_R2 + (size_t)B_ * L_ * D_ * 2);
    bf16*  reads_b = wk_b;
    bf16*  bc_b    = (bf16*)(ws + O_R3);
    bf16*  UwW     = (bf16*)(ws + O_R3);
    bf16*  xn_b    = (bf16*)(ws + O_R4);
    bf16*  w_in_b  = (bf16*)(ws + O_R4 + (size_t)B_ * L_ * D_ * 2);
    bf16*  vconv_b = (bf16*)(ws + O_R4);
    float* U_ssd   = (float*)(ws + O_R4);
    float* outf    = (float*)(ws + O_R4);
    bf16*  vT_g    = (bf16*)(ws + O_R5);
    bf16*  BT_g    = (bf16*)(ws + O_R5 + (size_t)B_ * L_ * 2048 * 2);
    float* vbuf    = (float*)(ws + O_R5);
    bf16*  vTm     = (bf16*)(ws + O_R5 + (size_t)B_ * L_ * D_ * 4);
    bf16*  wkgT    = (bf16*)(ws + O_R5 + (size_t)B_ * L_ * D_ * 4 + (size_t)B_ * L_ * D_ * 2);

    const long BLD  = (long)B_ * L_ * D_;
    const long BLDI = (long)B_ * L_ * DI_;

    k_gamma<<<1, 256, 0, stream>>>(decay, scr);
    k_f2b<<<cdiv_i((long)PROJ_ * D_ / 4, 256), 256, 0, stream>>>(w_in, w_in_b, (long)PROJ_ * D_ / 4);
    k_f2b<<<cdiv_i((long)D_ * DI_ / 4, 256), 256, 0, stream>>>(w_out, w_out_b, (long)D_ * DI_ / 4);
    k_f2b<<<cdiv_i((long)D_ * D_ / 4, 256), 256, 0, stream>>>(w_write, w_write_b, (long)D_ * D_ / 4);
    k_f2b<<<cdiv_i((long)D_ * D_ / 4, 256), 256, 0, stream>>>(w_read, w_read_b, (long)D_ * D_ / 4);
    k_rmsnorm<<<B_ * L_, 256, 0, stream>>>(x, norm_w, xn_b);
    // proj
    run_gemm(stream, 2, xn_b, w_in_b, dt_raw, val_b, gate_b, bc_b, nullptr, nullptr, nullptr, nullptr,
             B_ * L_, PROJ_, D_, D_, D_, 0, 1, 1, 0, 0, 0, 0, 0, 0);
    k_ld<<<cdiv_i((long)B_ * L_ * H_, 256), 256, 0, stream>>>(dt_raw, dt_bias, A_log, ld_g);
    k_cum<<<B_ * NC_ * H_, 256, 0, stream>>>(ld_g, cum_g, cumlast);
    k_conv<<<cdiv_i(BLDI, 256), 256, 0, stream>>>(val_b, conv_w, conv_b, vconv_b);
    // transposes for SSD MFMA
    k_vt<<<dim3(L_ / 32, DI_ / 32, B_), 256, 0, stream>>>(vconv_b, cum_g, cumlast, vT_g, vTw_g);
    k_bt<<<dim3(L_ / 32, DI_ / 32, B_), 256, 0, stream>>>(bc_b, BT_g);
    // SSD
    k_ssd_u2<<<B_ * NC_ * H_, 256, 0, stream>>>(vTw_g, BT_g, U_ssd);
    k_ssd2<<<cdiv_i((long)B_ * H_ * HD_ * N_, 256), 256, 0, stream>>>(U_ssd, cumlast, hst_b);
    k_ssd_y<<<B_ * NC_ * H_, 256, 0, stream>>>(bc_b, vT_g, hst_b, cum_g, D_skip, gate_b, yg_b);
    // out projection
    run_gemm(stream, 1, yg_b, w_out_b, outf, out_b, nullptr, nullptr, nullptr, nullptr, nullptr, nullptr,
             B_ * L_, D_, DI_, DI_, DI_, D_, 1, 1, 0, 0, 0, 0, 0, 0);
    // memory scan
    k_shift<<<cdiv_i(BLD, 256), 256, 0, stream>>>(out_b, wk_b);
    run_gemm(stream, 0, out_b, w_write_b, vbuf, nullptr, nullptr, nullptr, nullptr, nullptr, nullptr, nullptr,
             B_ * L_, D_, D_, D_, D_, D_, 1, 1, 0, 0, 0, 0, 0, 0);
    k_transpose<<<dim3(L_ / 32, D_ / 32, B_), 256, 0, stream>>>(vbuf, vTm);
    k_trans_wkg<<<dim3(L_ / 32, D_ / 32, B_), 256, 0, stream>>>(outf, scr, wkgT);
    run_gemm(stream, 6, vTm, wkgT, nullptr, UwW, nullptr, nullptr, nullptr, nullptr, nullptr, nullptr,
             D_, D_, MC_, L_, L_, D_, B_ * NC_, NC_,
             (long)D_ * L_, MC_, (long)D_ * L_, MC_, (long)D_ * D_, (long)B_ * D_ * D_);
    k_m2<<<cdiv_i((long)B_ * D_ * D_, 256), 256, 0, stream>>>(UwW, scr);
    run_gemm(stream, 3, out_b, wk_b, nullptr, Sm_b, nullptr, nullptr, nullptr, nullptr, nullptr, scr,
             MC_, MC_, D_, D_, D_, MC_, B_ * NC_, NC_,
             (long)L_ * D_, (long)MC_ * D_, (long)L_ * D_, (long)MC_ * D_,
             (long)MC_ * MC_, (long)B_ * MC_ * MC_);
    run_gemm(stream, 6, Sm_b, vTm, nullptr, intra_b, nullptr, nullptr, nullptr, nullptr, nullptr, nullptr,
             MC_, D_, MC_, MC_, L_, D_, B_ * NC_, NC_,
             (long)MC_ * MC_, (long)B_ * MC_ * MC_, (long)D_ * L_, MC_,
             (long)L_ * D_, (long)MC_ * D_);
    run_gemm(stream, 4, out_b, UwW, nullptr, reads_b, nullptr, nullptr, nullptr, nullptr, intra_b, scr,
             MC_, D_, D_, D_, D_, D_, B_ * NC_, NC_,
             (long)L_ * D_, (long)MC_ * D_, (long)D_ * D_, (long)B_ * D_ * D_,
             (long)L_ * D_, (long)MC_ * D_);
    run_gemm(stream, 5, reads_b, w_read_b, outp, nullptr, nullptr, nullptr, x, outf, nullptr, nullptr,
             B_ * L_, D_, D_, D_, D_, D_, 1, 1, 0, 0, 0, 0, 0, 0);
}

// Round 5
// 824.276 us; speedup vs baseline: 2.4174x; 1.1016x over previous
//
#include <hip/hip_runtime.h>
#include <hip/hip_bf16.h>

typedef __hip_bfloat16 bf16;
typedef __attribute__((ext_vector_type(8))) short short8;
typedef __attribute__((ext_vector_type(4))) float floatx4;

#define B_ 2
#define L_ 4096
#define D_ 1024
#define DI_ 2048
#define H_ 16
#define HD_ 128
#define N_ 128
#define CS_ 256
#define MC_ 256
#define NC_ 16
#define PROJ_ 8208

__device__ __forceinline__ float bf2f(short s) {
    return __uint_as_float(((unsigned)(unsigned short)s) << 16);
}

__device__ __forceinline__ void gl_lds16(const void* g, void* s) {
    __builtin_amdgcn_global_load_lds(
        (const __attribute__((address_space(1))) void*)g,
        (__attribute__((address_space(3))) void*)s, 16, 0, 0);
}

// ---------------------------------------------------------------------------
// Generic bf16 MFMA GEMM: C[M,N] = A[M,K] @ Bt[N,K]^T  (both row-major, K contig)
// 128x128 tile, 4 waves, global_load_lds(16B) staging, XCD-aware supertile
// remap (xcd = flat%8 owns a contiguous n-column run), XOR LDS bank swizzle.
// ---------------------------------------------------------------------------
struct GemmP {
    const bf16* A; const bf16* Bt;
    float* C; bf16* CB; bf16* CB2; bf16* CB3;
    const float* add0; const float* add1; const bf16* add0b; const float* scr;
    long lda, ldb, ldc;
    int M, N, K, zinner;
    long a_zo, a_zi, b_zo, b_zi, c_zo, c_zi;
};

template<int EPI>
__global__ __launch_bounds__(256, 2) void gemm_bt(GemmP p)
{
    // ---- XCD-aware tile remap (exact bijection grid -> tiles) ----
    int NT = gridDim.x, MT = gridDim.y;
    long T = (long)NT * MT * gridDim.z;
    long flat = ((long)blockIdx.z * MT + blockIdx.y) * NT + blockIdx.x;
    int xcd = (int)(flat & 7);
    long q = flat >> 3;
    long Tq = T >> 3; int Tr = (int)(T & 7);
    long tile = (long)xcd * Tq + (long)(xcd < Tr ? xcd : Tr) + q;
    long per_z = (long)NT * MT;
    int z = (int)(tile / per_z);
    int t2 = (int)(tile - (long)z * per_z);
    // enumeration: n_outer slow -> m_outer -> (n_in, m_in) with m fastest
    int FG = NT >> 3;
    int g, width, within;
    if (t2 < FG * MT * 8) { g = t2 / (MT * 8); width = 8; within = t2 - g * MT * 8; }
    else                  { g = FG; width = NT - FG * 8; within = t2 - FG * MT * 8; }
    int m_outer = within / (8 * width);
    int hb = MT - m_outer * 8; if (hb > 8) hb = 8;
    int inner = within - m_outer * 8 * width;
    int n_in = inner / hb, m_in = inner - n_in * hb;
    int m0 = (m_outer * 8 + m_in) * 128;
    int n0 = (g * 8 + n_in) * 128;

    int zo = z / p.zinner, zi = z % p.zinner;
    const bf16* A  = p.A  + (long)zo * p.a_zo + (long)zi * p.a_zi;
    const bf16* Bt = p.Bt + (long)zo * p.b_zo + (long)zi * p.b_zi;
    long coff = (long)zo * p.c_zo + (long)zi * p.c_zi;

    __shared__ __align__(16) bf16 As[128 * 64];
    __shared__ __align__(16) bf16 Bs[128 * 64];

    int tid = threadIdx.x;
    int lane = tid & 63, wave = tid >> 6;
    int wm = (wave >> 1) * 64, wn = (wave & 1) * 64;
    int r16 = lane & 15, q8 = (lane >> 4) * 8;

    floatx4 zero4 = {0.f, 0.f, 0.f, 0.f};
    floatx4 acc[4][4];
#pragma unroll
    for (int i = 0; i < 4; i++)
#pragma unroll
        for (int j = 0; j < 4; j++) acc[i][j] = zero4;

    // staging: per wave 4 insts for A, 4 for B; each inst = 8 rows x 64 cols.
    // XOR swizzle: lane (row lrow, phys block pcol) loads logical block pcol^lrow.
    int lrow = lane >> 3;
    int lc = ((lane & 7) ^ lrow) * 8;     // swizzled logical column (elements)
    int wrow = wave * 32;
    int rx = lane & 7;                    // read-side xor key

    for (int k0 = 0; k0 < p.K; k0 += 64) {
#pragma unroll
        for (int t = 0; t < 4; t++) {
            int row = wrow + t * 8 + lrow;
            gl_lds16(A + (long)(m0 + row) * p.lda + k0 + lc, &As[(wrow + t * 8) * 64]);
            int bn = n0 + row; if (bn > p.N - 1) bn = p.N - 1;
            gl_lds16(Bt + (long)bn * p.ldb + k0 + lc, &Bs[(wrow + t * 8) * 64]);
        }
        __syncthreads();
#pragma unroll
        for (int ks = 0; ks < 64; ks += 32) {
            int lb = (ks >> 3) + (lane >> 4);      // logical 8-elem block index
            int po = ((lb ^ rx) << 3);             // swizzled phys offset
            short8 af[4], bq[4];
#pragma unroll
            for (int i = 0; i < 4; i++)
                af[i] = *(const short8*)&As[(wm + i * 16 + r16) * 64 + po];
#pragma unroll
            for (int j = 0; j < 4; j++)
                bq[j] = *(const short8*)&Bs[(wn + j * 16 + r16) * 64 + po];
#pragma unroll
            for (int i = 0; i < 4; i++)
#pragma unroll
                for (int j = 0; j < 4; j++)
                    acc[i][j] = __builtin_amdgcn_mfma_f32_16x16x32_bf16(af[i], bq[j], acc[i][j], 0, 0, 0);
        }
        __syncthreads();
    }

    int rq = (lane >> 4) * 4;
#pragma unroll
    for (int i = 0; i < 4; i++) {
#pragma unroll
        for (int j = 0; j < 4; j++) {
#pragma unroll
            for (int r = 0; r < 4; r++) {
                int gm = m0 + wm + i * 16 + rq + r;
                int gn = n0 + wn + j * 16 + r16;
                if (gm >= p.M || gn >= p.N) continue;
                float a = acc[i][j][r];
                if (EPI == 0) {
                    p.C[coff + (long)gm * p.ldc + gn] = a;
                } else if (EPI == 1) {
                    long ix = coff + (long)gm * p.ldc + gn;
                    p.C[ix] = a; p.CB[ix] = __float2bfloat16(a);
                } else if (EPI == 2) {                // proj 4-way split
                    if (gn < 2048)      p.CB [(long)gm * 2048 + gn]          = __float2bfloat16(a);
                    else if (gn < 4096) p.CB2[(long)gm * 2048 + (gn - 2048)] = __float2bfloat16(a);
                    else if (gn < 8192) p.CB3[(long)gm * 4096 + (gn - 4096)] = __float2bfloat16(a);
                    else                p.C  [(long)gm * 16   + (gn - 8192)] = a;
                } else if (EPI == 3) {                // Mmem causal decay mask -> bf16
                    float lg = p.scr[1];
                    float v = (gm > gn) ? a * __expf((float)(gm - 1 - gn) * lg) : 0.f;
                    p.CB[coff + (long)gm * p.ldc + gn] = __float2bfloat16(v);
                } else if (EPI == 4) {                // inter: acc*gp[m] + intra(bf16) -> bf16
                    long ix = coff + (long)gm * p.ldc + gn;
                    float t = a * p.scr[16 + gm] + __bfloat162float(p.add0b[ix]);
                    p.CB[ix] = __float2bfloat16(t);
                } else if (EPI == 5) {                // final: x + out + 0.5*acc
                    long ix = (long)gm * p.ldc + gn;
                    p.C[ix] = p.add0[ix] + p.add1[ix] + 0.5f * a;
                } else if (EPI == 6) {                // bf16 only
                    p.CB[coff + (long)gm * p.ldc + gn] = __float2bfloat16(a);
                }
            }
        }
    }
}

// ---------------------------------------------------------------------------
// Elementwise / helper kernels
// ---------------------------------------------------------------------------
__global__ void k_gamma(const float* decay, float* scr)
{
    int t = threadIdx.x;
    float g = 1.f / (1.f + expf(-decay[0]));
    float lg = logf(g);
    if (t == 0) { scr[0] = g; scr[1] = lg; scr[2] = expf(256.f * lg); }
    scr[16 + t]  = expf(lg * (float)t);          // gp
    scr[272 + t] = expf(lg * (float)(255 - t));  // gw
}

__global__ void k_f2b(const float* __restrict__ s, bf16* __restrict__ d, long n4)
{
    long i = (long)blockIdx.x * 256 + threadIdx.x;
    if (i >= n4) return;
    float4 v = ((const float4*)s)[i];
    bf16* o = d + i * 4;
    o[0] = __float2bfloat16(v.x); o[1] = __float2bfloat16(v.y);
    o[2] = __float2bfloat16(v.z); o[3] = __float2bfloat16(v.w);
}

__global__ __launch_bounds__(256) void k_rmsnorm(const float* __restrict__ x,
                                                 const float* __restrict__ w,
                                                 bf16* __restrict__ o)
{
    int row = blockIdx.x, t = threadIdx.x;
    float4 xv = ((const float4*)(x + (long)row * D_))[t];
    float s = xv.x*xv.x + xv.y*xv.y + xv.z*xv.z + xv.w*xv.w;
#pragma unroll
    for (int m = 32; m > 0; m >>= 1) s += __shfl_xor(s, m, 64);
    __shared__ float ps[4];
    if ((t & 63) == 0) ps[t >> 6] = s;
    __syncthreads();
    s = ps[0] + ps[1] + ps[2] + ps[3];
    float r = rsqrtf(s * (1.f / (float)D_) + 1e-6f);
    float4 wv = ((const float4*)w)[t];
    bf16* orow = o + (long)row * D_ + t * 4;
    orow[0] = __float2bfloat16(xv.x * r * wv.x);
    orow[1] = __float2bfloat16(xv.y * r * wv.y);
    orow[2] = __float2bfloat16(xv.z * r * wv.z);
    orow[3] = __float2bfloat16(xv.w * r * wv.w);
}

__global__ void k_ld(const float* __restrict__ dtr, const float* __restrict__ dt_bias,
                     const float* __restrict__ A_log, float* __restrict__ ld)
{
    long i = (long)blockIdx.x * 256 + threadIdx.x;
    if (i >= (long)B_ * L_ * H_) return;
    int h = (int)(i & 15);
    float d = dtr[i] + dt_bias[h];
    float sp = (d > 20.f) ? d : log1pf(__expf(d));
    ld[i] = -__expf(A_log[h]) * sp;
}

__global__ __launch_bounds__(256) void k_cum(const float* __restrict__ ld,
                                             float* __restrict__ cum_g,
                                             float* __restrict__ cumlast)
{
    int bid = blockIdx.x;           // b*256 + c*16 + h
    int h = bid & 15, c = (bid >> 4) & 15, b = bid >> 8;
    long rowbase = (long)b * L_ + c * CS_;
    int tid = threadIdx.x;
    __shared__ float cum_s[256];
    cum_s[tid] = ld[(rowbase + tid) * H_ + h];
    __syncthreads();
    for (int off = 1; off < 256; off <<= 1) {
        float add = (tid >= off) ? cum_s[tid - off] : 0.f;
        __syncthreads();
        cum_s[tid] += add;
        __syncthreads();
    }
    cum_g[(rowbase + tid) * H_ + h] = cum_s[tid];
    if (tid == 255) cumlast[bid] = cum_s[255];
}

__global__ void k_conv(const bf16* __restrict__ val_b, const float* __restrict__ cw,
                       const float* __restrict__ cb, bf16* __restrict__ vo)
{
    long idx = (long)blockIdx.x * 256 + threadIdx.x;
    if (idx >= (long)B_ * L_ * DI_) return;
    long row = idx >> 11; int ch = (int)(idx & 2047);
    int l = (int)(row & (L_ - 1));
    float acc = cb[ch];
#pragma unroll
    for (int k = 0; k < 4; k++) {
        int ls = l - 3 + k;
        if (ls >= 0) acc += cw[ch * 4 + k] * __bfloat162float(val_b[(row - 3 + k) * 2048 + ch]);
    }
    float s = acc / (1.f + __expf(-acc));
    vo[idx] = __float2bfloat16(s);
}

// vconv [b*L][2048] -> vT [b*2048 + d][L] bf16, plus decay-weighted vTw
__global__ void k_vt(const bf16* __restrict__ vconv, const float* __restrict__ cum_g,
                     const float* __restrict__ cumlast, bf16* __restrict__ vT,
                     bf16* __restrict__ vTw)
{
    __shared__ bf16 tile[32][33];
    int b = blockIdx.z;
    int r0 = blockIdx.x * 32, c0 = blockIdx.y * 32;
    int tx = threadIdx.x & 31, ty = threadIdx.x >> 5;
    for (int i = 0; i < 32; i += 8)
        tile[ty + i][tx] = vconv[((long)b * L_ + r0 + ty + i) * 2048 + c0 + tx];
    __syncthreads();
    int l = r0 + tx;
    int h = c0 >> 7;
    float w = __expf(cumlast[b * 256 + (l >> 8) * 16 + h] - cum_g[((long)b * L_ + l) * 16 + h]);
    for (int i = 0; i < 32; i += 8) {
        int col = c0 + ty + i;
        long oidx = ((long)b * 2048 + col) * L_ + l;
        bf16 v = tile[tx][ty + i];
        vT[oidx] = v;
        vTw[oidx] = __float2bfloat16(__bfloat162float(v) * w);
    }
}

// bc_b B-part [b*L][4096 cols 0..2047] -> BT [b*2048 + col][L]
__global__ void k_bt(const bf16* __restrict__ bc, bf16* __restrict__ BT)
{
    __shared__ bf16 tile[32][33];
    int b = blockIdx.z;
    int r0 = blockIdx.x * 32, c0 = blockIdx.y * 32;
    int tx = threadIdx.x & 31, ty = threadIdx.x >> 5;
    for (int i = 0; i < 32; i += 8)
        tile[ty + i][tx] = bc[((long)b * L_ + r0 + ty + i) * 4096 + c0 + tx];
    __syncthreads();
    int l = r0 + tx;
    for (int i = 0; i < 32; i += 8) {
        int col = c0 + ty + i;
        BT[((long)b * 2048 + col) * L_ + l] = tile[tx][ty + i];
    }
}

// U[c][b][h][d][n] = sum_t (v*w)[t,d] B[t,n]  — MFMA, global fragments
__global__ __launch_bounds__(256, 2) void k_ssd_u2(
    const bf16* __restrict__ vTw, const bf16* __restrict__ BT, float* __restrict__ U)
{
    int bid = blockIdx.x;
    int h = bid & 15, c = (bid >> 4) & 15, b = bid >> 8;
    int lane = threadIdx.x & 63, wave = threadIdx.x >> 6;
    int r16 = lane & 15, q8 = (lane >> 4) * 8, rq = (lane >> 4) * 4;
    int d0 = (wave >> 1) * 64, n0 = (wave & 1) * 64;
    const bf16* vb = vTw + ((long)b * 2048 + h * 128) * L_ + c * 256;
    const bf16* bb = BT  + ((long)b * 2048 + h * 128) * L_ + c * 256;
    floatx4 zero4 = {0.f, 0.f, 0.f, 0.f};
    floatx4 acc[4][4];
#pragma unroll
    for (int i = 0; i < 4; i++)
#pragma unroll
        for (int j = 0; j < 4; j++) acc[i][j] = zero4;
#pragma unroll 2
    for (int ks = 0; ks < 8; ks++) {
        short8 af[4], bq[4];
#pragma unroll
        for (int i = 0; i < 4; i++)
            af[i] = *(const short8*)(vb + (long)(d0 + i * 16 + r16) * L_ + ks * 32 + q8);
#pragma unroll
        for (int j = 0; j < 4; j++)
            bq[j] = *(const short8*)(bb + (long)(n0 + j * 16 + r16) * L_ + ks * 32 + q8);
#pragma unroll
        for (int i = 0; i < 4; i++)
#pragma unroll
            for (int j = 0; j < 4; j++)
                acc[i][j] = __builtin_amdgcn_mfma_f32_16x16x32_bf16(af[i], bq[j], acc[i][j], 0, 0, 0);
    }
    float* up = U + (((long)c * B_ + b) * H_ + h) * 16384;
#pragma unroll
    for (int i = 0; i < 4; i++)
#pragma unroll
        for (int j = 0; j < 4; j++)
#pragma unroll
            for (int r = 0; r < 4; r++)
                up[(d0 + i * 16 + rq + r) * 128 + (n0 + j * 16 + r16)] = acc[i][j][r];
}

// h recurrence -> bf16 states entering each chunk
__global__ void k_ssd2(const float* __restrict__ U, const float* __restrict__ cumlast,
                       bf16* __restrict__ hst)
{
    long idx = (long)blockIdx.x * 256 + threadIdx.x;
    const long tot = (long)B_ * H_ * HD_ * N_;
    if (idx >= tot) return;
    int bh = (int)(idx >> 14);
    int b = bh >> 4, h = bh & 15;
    float hv = 0.f;
    for (int c = 0; c < NC_; c++) {
        hst[c * tot + idx] = __float2bfloat16(hv);
        float ef = __expf(cumlast[b * 256 + c * 16 + h]);
        hv = ef * hv + U[c * tot + idx];
    }
}

// Fused intra+inter SSD output, flash-style MFMA. Writes gated bf16 yg.
__global__ __launch_bounds__(256, 2) void k_ssd_y(
    const bf16* __restrict__ bc_b, const bf16* __restrict__ vT,
    const bf16* __restrict__ hst, const float* __restrict__ cum_g,
    const float* __restrict__ Dskip, const bf16* __restrict__ gate_b,
    bf16* __restrict__ yg)
{
    int bid = blockIdx.x;
    int h = bid & 15, c = (bid >> 4) & 15, b = bid >> 8;
    long rowbase = (long)b * L_ + c * CS_;
    int tid = threadIdx.x, lane = tid & 63, wave = tid >> 6;
    int r16 = lane & 15, q8 = (lane >> 4) * 8, rq = (lane >> 4) * 4;
    int wt = (wave >> 1) * 32, wmS = (wave & 1) * 32, wd = (wave & 1) * 64;

    __shared__ float cum_s[256];
    __shared__ __align__(16) bf16 Ss[64][72];

    cum_s[tid] = cum_g[(rowbase + tid) * H_ + h];
    __syncthreads();

    const bf16* Cb  = bc_b + rowbase * 4096 + 2048 + h * 128;
    const bf16* Bb  = bc_b + rowbase * 4096 + h * 128;
    const bf16* vTb = vT + ((long)b * 2048 + h * 128) * L_ + c * 256;
    const bf16* hp  = hst + (((long)c * B_ + b) * H_ + h) * 16384;

    floatx4 zero4 = {0.f, 0.f, 0.f, 0.f};

    for (int tt = 0; tt < 4; tt++) {
        int tbase = tt * 64;
        short8 caf[2][4];
#pragma unroll
        for (int i = 0; i < 2; i++)
#pragma unroll
            for (int ks = 0; ks < 4; ks++)
                caf[i][ks] = *(const short8*)(Cb + (long)(tbase + wt + i * 16 + r16) * 4096 + ks * 32 + q8);

        // ---- inter: yacc = C @ hprev^T, scaled by exp(cum[t]) ----
        floatx4 yacc[2][4];
#pragma unroll
        for (int i = 0; i < 2; i++)
#pragma unroll
            for (int j = 0; j < 4; j++) yacc[i][j] = zero4;
#pragma unroll
        for (int ks = 0; ks < 4; ks++)
#pragma unroll
            for (int j = 0; j < 4; j++) {
                short8 hq = *(const short8*)(hp + (long)(wd + j * 16 + r16) * 128 + ks * 32 + q8);
#pragma unroll
                for (int i = 0; i < 2; i++)
                    yacc[i][j] = __builtin_amdgcn_mfma_f32_16x16x32_bf16(caf[i][ks], hq, yacc[i][j], 0, 0, 0);
            }
        float texp[2][4];
#pragma unroll
        for (int i = 0; i < 2; i++)
#pragma unroll
            for (int r = 0; r < 4; r++)
                texp[i][r] = __expf(cum_s[tbase + wt + i * 16 + rq + r]);
#pragma unroll
        for (int i = 0; i < 2; i++)
#pragma unroll
            for (int j = 0; j < 4; j++)
#pragma unroll
                for (int r = 0; r < 4; r++) yacc[i][j][r] *= texp[i][r];

        // ---- intra m-loop ----
        for (int mt = 0; mt <= tt; mt++) {
            int mbase = mt * 64;
            floatx4 sacc[2][2];
#pragma unroll
            for (int i = 0; i < 2; i++)
#pragma unroll
                for (int j = 0; j < 2; j++) sacc[i][j] = zero4;
#pragma unroll
            for (int ks = 0; ks < 4; ks++) {
                short8 bq[2];
#pragma unroll
                for (int j = 0; j < 2; j++)
                    bq[j] = *(const short8*)(Bb + (long)(mbase + wmS + j * 16 + r16) * 4096 + ks * 32 + q8);
#pragma unroll
                for (int i = 0; i < 2; i++)
#pragma unroll
                    for (int j = 0; j < 2; j++)
                        sacc[i][j] = __builtin_amdgcn_mfma_f32_16x16x32_bf16(caf[i][ks], bq[j], sacc[i][j], 0, 0, 0);
            }
            __syncthreads();
#pragma unroll
            for (int i = 0; i < 2; i++)
#pragma unroll
                for (int r = 0; r < 4; r++) {
                    int trow = wt + i * 16 + rq + r;
                    float ct = cum_s[tbase + trow];
#pragma unroll
                    for (int j = 0; j < 2; j++) {
                        int mcol = mbase + wmS + j * 16 + r16;
                        float val = (mcol <= tbase + trow) ? sacc[i][j][r] * __expf(ct - cum_s[mcol]) : 0.f;
                        Ss[trow][wmS + j * 16 + r16] = __float2bfloat16(val);
                    }
                }
            __syncthreads();
#pragma unroll
            for (int ks = 0; ks < 2; ks++) {
                short8 saf[2];
#pragma unroll
                for (int i = 0; i < 2; i++)
                    saf[i] = *(const short8*)&Ss[wt + i * 16 + r16][ks * 32 + q8];
#pragma unroll
                for (int j = 0; j < 4; j++) {
                    short8 vq = *(const short8*)(vTb + (long)(wd + j * 16 + r16) * L_ + mbase + ks * 32 + q8);
#pragma unroll
                    for (int i = 0; i < 2; i++)
                        yacc[i][j] = __builtin_amdgcn_mfma_f32_16x16x32_bf16(saf[i], vq, yacc[i][j], 0, 0, 0);
                }
            }
        }
        // ---- epilogue ----
#pragma unroll
        for (int i = 0; i < 2; i++)
#pragma unroll
            for (int r = 0; r < 4; r++) {
                int t = tbase + wt + i * 16 + rq + r;
                long grow = (rowbase + t) * 2048 + h * 128;
#pragma unroll
                for (int j = 0; j < 4; j++) {
                    int d = wd + j * 16 + r16;
                    float vv = __bfloat162float(vTb[(long)d * L_ + t]);
                    float y = yacc[i][j][r] + Dskip[h * 128 + d] * vv;
                    float g = __bfloat162float(gate_b[grow + d]);
                    float sg = g / (1.f + __expf(-g));
                    yg[grow + d] = __float2bfloat16(y * sg);
                }
            }
    }
}

__global__ void k_shift(const bf16* __restrict__ ob, bf16* __restrict__ wk)
{
    long idx = (long)blockIdx.x * 256 + threadIdx.x;
    if (idx >= (long)B_ * L_ * D_) return;
    int l = (int)((idx >> 10) & (L_ - 1));
    wk[idx] = (l == 0) ? __float2bfloat16(0.f) : ob[idx - D_];
}

__global__ void k_transpose(const float* __restrict__ srcg, bf16* __restrict__ dstg)
{
    __shared__ float t[32][33];
    int b = blockIdx.z;
    const float* src = srcg + (long)b * L_ * D_;
    bf16* dst = dstg + (long)b * D_ * L_;
    int r0 = blockIdx.x * 32, c0 = blockIdx.y * 32;
    int tx = threadIdx.x & 31, ty = threadIdx.x >> 5;
    for (int i = 0; i < 32; i += 8)
        t[ty + i][tx] = src[(long)(r0 + ty + i) * D_ + c0 + tx];
    __syncthreads();
    for (int i = 0; i < 32; i += 8)
        dst[(long)(c0 + ty + i) * L_ + r0 + tx] = __float2bfloat16(t[tx][ty + i]);
}

__global__ void k_trans_wkg(const float* __restrict__ outg, const float* __restrict__ scr,
                            bf16* __restrict__ dstg)
{
    __shared__ float t[32][33];
    int b = blockIdx.z;
    const float* src = outg + (long)b * L_ * D_;
    bf16* dst = dstg + (long)b * D_ * L_;
    int r0 = blockIdx.x * 32, c0 = blockIdx.y * 32;
    int tx = threadIdx.x & 31, ty = threadIdx.x >> 5;
    for (int i = 0; i < 32; i += 8) {
        int rr = r0 + ty + i;
        float g = scr[272 + (rr & 255)];
        t[ty + i][tx] = (rr == 0) ? 0.f : src[(long)(rr - 1) * D_ + c0 + tx] * g;
    }
    __syncthreads();
    for (int i = 0; i < 32; i += 8)
        dst[(long)(c0 + ty + i) * L_ + r0 + tx] = __float2bfloat16(t[tx][ty + i]);
}

// W recurrence, in place
__global__ void k_m2(bf16* __restrict__ UwW, const float* __restrict__ scr)
{
    long idx = (long)blockIdx.x * 256 + threadIdx.x;
    const long tot = (long)B_ * D_ * D_;
    if (idx >= tot) return;
    float gMC = scr[2];
    float w = 0.f;
    for (int c = 0; c < NC_; c++) {
        float tmp = __bfloat162float(UwW[c * tot + idx]);
        UwW[c * tot + idx] = __float2bfloat16(w);
        w = gMC * w + tmp;
    }
}

// ---------------------------------------------------------------------------
// Host side
// ---------------------------------------------------------------------------
static inline int cdiv_i(long a, long b) { return (int)((a + b - 1) / b); }

static void run_gemm(hipStream_t st, int epi, const bf16* A, const bf16* Bt,
                     float* C, bf16* CB, bf16* CB2, bf16* CB3,
                     const float* add0, const float* add1, const bf16* add0b,
                     const float* scr, int M, int N, int K,
                     long lda, long ldb, long ldc, int nbatch, int zinner,
                     long a_zo, long a_zi, long b_zo, long b_zi, long c_zo, long c_zi)
{
    GemmP p;
    p.A = A; p.Bt = Bt; p.C = C; p.CB = CB; p.CB2 = CB2; p.CB3 = CB3;
    p.add0 = add0; p.add1 = add1; p.add0b = add0b; p.scr = scr;
    p.lda = lda; p.ldb = ldb; p.ldc = ldc;
    p.M = M; p.N = N; p.K = K; p.zinner = zinner;
    p.a_zo = a_zo; p.a_zi = a_zi; p.b_zo = b_zo; p.b_zi = b_zi; p.c_zo = c_zo; p.c_zi = c_zi;
    dim3 g(cdiv_i(N, 128), cdiv_i(M, 128), nbatch);
    dim3 b(256);
    switch (epi) {
        case 0: gemm_bt<0><<<g, b, 0, st>>>(p); break;
        case 1: gemm_bt<1><<<g, b, 0, st>>>(p); break;
        case 2: gemm_bt<2><<<g, b, 0, st>>>(p); break;
        case 3: gemm_bt<3><<<g, b, 0, st>>>(p); break;
        case 4: gemm_bt<4><<<g, b, 0, st>>>(p); break;
        case 5: gemm_bt<5><<<g, b, 0, st>>>(p); break;
        case 6: gemm_bt<6><<<g, b, 0, st>>>(p); break;
    }
}

extern "C" void kernel_launch(void* const* d_in, const int* in_sizes, int n_in,
                              void* d_out, int out_size, void* d_ws, size_t ws_size,
                              hipStream_t stream)
{
    const float* x       = (const float*)d_in[0];
    const float* norm_w  = (const float*)d_in[1];
    const float* w_in    = (const float*)d_in[2];
    const float* conv_w  = (const float*)d_in[3];
    const float* conv_b  = (const float*)d_in[4];
    const float* A_log   = (const float*)d_in[5];
    const float* dt_bias = (const float*)d_in[6];
    const float* D_skip  = (const float*)d_in[7];
    const float* w_out   = (const float*)d_in[8];
    const float* w_write = (const float*)d_in[9];
    const float* w_read  = (const float*)d_in[10];
    const float* decay   = (const float*)d_in[11];
    float* outp = (float*)d_out;

    // ---- workspace layout (lifetime overlays, ~244.9 MB) ----
    const size_t SZ_SCR  = 4096;
    const size_t SZ_DT   = (size_t)B_ * L_ * H_ * 4;
    const size_t SZ_CUML = 2048;
    const size_t SZ_WOUT = (size_t)D_ * DI_ * 2;
    const size_t SZ_WSML = (size_t)D_ * D_ * 2;
    const size_t SZ_R1   = (size_t)B_ * L_ * 2048 * 2;
    const size_t SZ_R2   = SZ_R1;
    const size_t SZ_R3   = (size_t)B_ * L_ * 4096 * 2;
    const size_t SZ_R4   = (size_t)B_ * L_ * D_ * 2 + (size_t)PROJ_ * D_ * 2;
    const size_t SZ_R5   = (size_t)B_ * L_ * 2048 * 4;

    size_t o = 0;
    auto take = [&](size_t sz) { size_t r = o; o += (sz + 255) & ~(size_t)255; return r; };
    const size_t O_SCR = take(SZ_SCR);
    const size_t O_DT  = take(SZ_DT);
    const size_t O_LD  = take(SZ_DT);
    const size_t O_CUM = take(SZ_DT);
    const size_t O_CL  = take(SZ_CUML);
    const size_t O_WO  = take(SZ_WOUT);
    const size_t O_WW  = take(SZ_WSML);
    const size_t O_WR  = take(SZ_WSML);
    const size_t O_R1  = take(SZ_R1);
    const size_t O_R2  = take(SZ_R2);
    const size_t O_R3  = take(SZ_R3);
    const size_t O_R4  = take(SZ_R4);
    const size_t O_R5  = take(SZ_R5);
    const size_t NEED = o;
    if (ws_size < NEED) return;

    char* ws = (char*)d_ws;
    float* scr     = (float*)(ws + O_SCR);
    float* dt_raw  = (float*)(ws + O_DT);
    float* ld_g    = (float*)(ws + O_LD);
    float* cum_g   = (float*)(ws + O_CUM);
    float* cumlast = (float*)(ws + O_CL);
    bf16*  w_out_b   = (bf16*)(ws + O_WO);
    bf16*  w_write_b = (bf16*)(ws + O_WW);
    bf16*  w_read_b  = (bf16*)(ws + O_WR);

    bf16*  val_b   = (bf16*)(ws + O_R1);
    bf16*  vTw_g   = (bf16*)(ws + O_R1);
    bf16*  yg_b    = (bf16*)(ws + O_R1);
    bf16*  hst_b   = (bf16*)(ws + O_R1 + (size_t)B_ * L_ * D_ * 2);
    bf16*  Sm_b    = (bf16*)(ws + O_R1);
    bf16*  intra_b = (bf16*)(ws + O_R1 + (size_t)NC_ * B_ * MC_ * MC_ * 2);
    bf16*  gate_b  = (bf16*)(ws + O_R2);
    bf16*  out_b   = (bf16*)(ws + O_R2);
    bf16*  wk_b    = (bf16*)(ws + O_R2 + (size_t)B_ * L_ * D_ * 2);
    bf16*  reads_b = wk_b;
    bf16*  bc_b    = (bf16*)(ws + O_R3);
    bf16*  UwW     = (bf16*)(ws + O_R3);
    bf16*  xn_b    = (bf16*)(ws + O_R4);
    bf16*  w_in_b  = (bf16*)(ws + O_R4 + (size_t)B_ * L_ * D_ * 2);
    bf16*  vconv_b = (bf16*)(ws + O_R4);
    float* U_ssd   = (float*)(ws + O_R4);
    float* outf    = (float*)(ws + O_R4);
    bf16*  vT_g    = (bf16*)(ws + O_R5);
    bf16*  BT_g    = (bf16*)(ws + O_R5 + (size_t)B_ * L_ * 2048 * 2);
    float* vbuf    = (float*)(ws + O_R5);
    bf16*  vTm     = (bf16*)(ws + O_R5 + (size_t)B_ * L_ * D_ * 4);
    bf16*  wkgT    = (bf16*)(ws + O_R5 + (size_t)B_ * L_ * D_ * 4 + (size_t)B_ * L_ * D_ * 2);

    const long BLD  = (long)B_ * L_ * D_;
    const long BLDI = (long)B_ * L_ * DI_;

    k_gamma<<<1, 256, 0, stream>>>(decay, scr);
    k_f2b<<<cdiv_i((long)PROJ_ * D_ / 4, 256), 256, 0, stream>>>(w_in, w_in_b, (long)PROJ_ * D_ / 4);
    k_f2b<<<cdiv_i((long)D_ * DI_ / 4, 256), 256, 0, stream>>>(w_out, w_out_b, (long)D_ * DI_ / 4);
    k_f2b<<<cdiv_i((long)D_ * D_ / 4, 256), 256, 0, stream>>>(w_write, w_write_b, (long)D_ * D_ / 4);
    k_f2b<<<cdiv_i((long)D_ * D_ / 4, 256), 256, 0, stream>>>(w_read, w_read_b, (long)D_ * D_ / 4);
    k_rmsnorm<<<B_ * L_, 256, 0, stream>>>(x, norm_w, xn_b);
    // proj
    run_gemm(stream, 2, xn_b, w_in_b, dt_raw, val_b, gate_b, bc_b, nullptr, nullptr, nullptr, nullptr,
             B_ * L_, PROJ_, D_, D_, D_, 0, 1, 1, 0, 0, 0, 0, 0, 0);
    k_ld<<<cdiv_i((long)B_ * L_ * H_, 256), 256, 0, stream>>>(dt_raw, dt_bias, A_log, ld_g);
    k_cum<<<B_ * NC_ * H_, 256, 0, stream>>>(ld_g, cum_g, cumlast);
    k_conv<<<cdiv_i(BLDI, 256), 256, 0, stream>>>(val_b, conv_w, conv_b, vconv_b);
    // transposes for SSD MFMA
    k_vt<<<dim3(L_ / 32, DI_ / 32, B_), 256, 0, stream>>>(vconv_b, cum_g, cumlast, vT_g, vTw_g);
    k_bt<<<dim3(L_ / 32, DI_ / 32, B_), 256, 0, stream>>>(bc_b, BT_g);
    // SSD
    k_ssd_u2<<<B_ * NC_ * H_, 256, 0, stream>>>(vTw_g, BT_g, U_ssd);
    k_ssd2<<<cdiv_i((long)B_ * H_ * HD_ * N_, 256), 256, 0, stream>>>(U_ssd, cumlast, hst_b);
    k_ssd_y<<<B_ * NC_ * H_, 256, 0, stream>>>(bc_b, vT_g, hst_b, cum_g, D_skip, gate_b, yg_b);
    // out projection
    run_gemm(stream, 1, yg_b, w_out_b, outf, out_b, nullptr, nullptr, nullptr, nullptr, nullptr, nullptr,
             B_ * L_, D_, DI_, DI_, DI_, D_, 1, 1, 0, 0, 0, 0, 0, 0);
    // memory scan
    k_shift<<<cdiv_i(BLD, 256), 256, 0, stream>>>(out_b, wk_b);
    run_gemm(stream, 0, out_b, w_write_b, vbuf, nullptr, nullptr, nullptr, nullptr, nullptr, nullptr, nullptr,
             B_ * L_, D_, D_, D_, D_, D_, 1, 1, 0, 0, 0, 0, 0, 0);
    k_transpose<<<dim3(L_ / 32, D_ / 32, B_), 256, 0, stream>>>(vbuf, vTm);
    k_trans_wkg<<<dim3(L_ / 32, D_ / 32, B_), 256, 0, stream>>>(outf, scr, wkgT);
    run_gemm(stream, 6, vTm, wkgT, nullptr, UwW, nullptr, nullptr, nullptr, nullptr, nullptr, nullptr,
             D_, D_, MC_, L_, L_, D_, B_ * NC_, NC_,
             (long)D_ * L_, MC_, (long)D_ * L_, MC_, (long)D_ * D_, (long)B_ * D_ * D_);
    k_m2<<<cdiv_i((long)B_ * D_ * D_, 256), 256, 0, stream>>>(UwW, scr);
    run_gemm(stream, 3, out_b, wk_b, nullptr, Sm_b, nullptr, nullptr, nullptr, nullptr, nullptr, scr,
             MC_, MC_, D_, D_, D_, MC_, B_ * NC_, NC_,
             (long)L_ * D_, (long)MC_ * D_, (long)L_ * D_, (long)MC_ * D_,
             (long)MC_ * MC_, (long)B_ * MC_ * MC_);
    run_gemm(stream, 6, Sm_b, vTm, nullptr, intra_b, nullptr, nullptr, nullptr, nullptr, nullptr, nullptr,
             MC_, D_, MC_, MC_, L_, D_, B_ * NC_, NC_,
             (long)MC_ * MC_, (long)B_ * MC_ * MC_, (long)D_ * L_, MC_,
             (long)L_ * D_, (long)MC_ * D_);
    run_gemm(stream, 4, out_b, UwW, nullptr, reads_b, nullptr, nullptr, nullptr, nullptr, intra_b, scr,
             MC_, D_, D_, D_, D_, D_, B_ * NC_, NC_,
             (long)L_ * D_, (long)MC_ * D_, (long)D_ * D_, (long)B_ * D_ * D_,
             (long)L_ * D_, (long)MC_ * D_);
    run_gemm(stream, 5, reads_b, w_read_b, outp, nullptr, nullptr, nullptr, x, outf, nullptr, nullptr,
             B_ * L_, D_, D_, D_, D_, D_, 1, 1, 0, 0, 0, 0, 0, 0);
}

// Round 6
// 813.546 us; speedup vs baseline: 2.4493x; 1.0132x over previous
//
#include <hip/hip_runtime.h>
#include <hip/hip_bf16.h>

typedef __hip_bfloat16 bf16;
typedef __attribute__((ext_vector_type(8))) short short8;
typedef __attribute__((ext_vector_type(4))) float floatx4;

#define B_ 2
#define L_ 4096
#define D_ 1024
#define DI_ 2048
#define H_ 16
#define HD_ 128
#define N_ 128
#define CS_ 256
#define MC_ 256
#define NC_ 16
#define PROJ_ 8208

__device__ __forceinline__ float bf2f(short s) {
    return __uint_as_float(((unsigned)(unsigned short)s) << 16);
}

__device__ __forceinline__ void gl_lds16(const void* g, void* s) {
    __builtin_amdgcn_global_load_lds(
        (const __attribute__((address_space(1))) void*)g,
        (__attribute__((address_space(3))) void*)s, 16, 0, 0);
}

// ---------------------------------------------------------------------------
// Generic bf16 MFMA GEMM: C[M,N] = A[M,K] @ Bt[N,K]^T  (both row-major, K contig)
// 128x128 tile, 4 waves, global_load_lds(16B) staging, XCD-aware supertile
// remap, XOR LDS bank swizzle.
// ---------------------------------------------------------------------------
struct GemmP {
    const bf16* A; const bf16* Bt;
    float* C; bf16* CB; bf16* CB2; bf16* CB3;
    const float* add0; const float* add1; const bf16* add0b; const float* scr;
    long lda, ldb, ldc;
    int M, N, K, zinner;
    long a_zo, a_zi, b_zo, b_zi, c_zo, c_zi;
};

template<int EPI>
__global__ __launch_bounds__(256, 2) void gemm_bt(GemmP p)
{
    // ---- XCD-aware tile remap (exact bijection grid -> tiles) ----
    int NT = gridDim.x, MT = gridDim.y;
    long T = (long)NT * MT * gridDim.z;
    long flat = ((long)blockIdx.z * MT + blockIdx.y) * NT + blockIdx.x;
    int xcd = (int)(flat & 7);
    long q = flat >> 3;
    long Tq = T >> 3; int Tr = (int)(T & 7);
    long tile = (long)xcd * Tq + (long)(xcd < Tr ? xcd : Tr) + q;
    long per_z = (long)NT * MT;
    int z = (int)(tile / per_z);
    int t2 = (int)(tile - (long)z * per_z);
    int FG = NT >> 3;
    int g, width, within;
    if (t2 < FG * MT * 8) { g = t2 / (MT * 8); width = 8; within = t2 - g * MT * 8; }
    else                  { g = FG; width = NT - FG * 8; within = t2 - FG * MT * 8; }
    int m_outer = within / (8 * width);
    int hb = MT - m_outer * 8; if (hb > 8) hb = 8;
    int inner = within - m_outer * 8 * width;
    int n_in = inner / hb, m_in = inner - n_in * hb;
    int m0 = (m_outer * 8 + m_in) * 128;
    int n0 = (g * 8 + n_in) * 128;

    int zo = z / p.zinner, zi = z % p.zinner;
    const bf16* A  = p.A  + (long)zo * p.a_zo + (long)zi * p.a_zi;
    const bf16* Bt = p.Bt + (long)zo * p.b_zo + (long)zi * p.b_zi;
    long coff = (long)zo * p.c_zo + (long)zi * p.c_zi;

    __shared__ __align__(16) bf16 As[128 * 64];
    __shared__ __align__(16) bf16 Bs[128 * 64];

    int tid = threadIdx.x;
    int lane = tid & 63, wave = tid >> 6;
    int wm = (wave >> 1) * 64, wn = (wave & 1) * 64;
    int r16 = lane & 15, q8 = (lane >> 4) * 8;

    floatx4 zero4 = {0.f, 0.f, 0.f, 0.f};
    floatx4 acc[4][4];
#pragma unroll
    for (int i = 0; i < 4; i++)
#pragma unroll
        for (int j = 0; j < 4; j++) acc[i][j] = zero4;

    int lrow = lane >> 3;
    int lc = ((lane & 7) ^ lrow) * 8;     // XOR-swizzled column
    int wrow = wave * 32;
    int rx = lane & 7;

    for (int k0 = 0; k0 < p.K; k0 += 64) {
#pragma unroll
        for (int t = 0; t < 4; t++) {
            int row = wrow + t * 8 + lrow;
            gl_lds16(A + (long)(m0 + row) * p.lda + k0 + lc, &As[(wrow + t * 8) * 64]);
            int bn = n0 + row; if (bn > p.N - 1) bn = p.N - 1;
            gl_lds16(Bt + (long)bn * p.ldb + k0 + lc, &Bs[(wrow + t * 8) * 64]);
        }
        __syncthreads();
#pragma unroll
        for (int ks = 0; ks < 64; ks += 32) {
            int lb = (ks >> 3) + (lane >> 4);
            int po = ((lb ^ rx) << 3);
            short8 af[4], bq[4];
#pragma unroll
            for (int i = 0; i < 4; i++)
                af[i] = *(const short8*)&As[(wm + i * 16 + r16) * 64 + po];
#pragma unroll
            for (int j = 0; j < 4; j++)
                bq[j] = *(const short8*)&Bs[(wn + j * 16 + r16) * 64 + po];
#pragma unroll
            for (int i = 0; i < 4; i++)
#pragma unroll
                for (int j = 0; j < 4; j++)
                    acc[i][j] = __builtin_amdgcn_mfma_f32_16x16x32_bf16(af[i], bq[j], acc[i][j], 0, 0, 0);
        }
        __syncthreads();
    }

    int rq = (lane >> 4) * 4;
#pragma unroll
    for (int i = 0; i < 4; i++) {
#pragma unroll
        for (int j = 0; j < 4; j++) {
#pragma unroll
            for (int r = 0; r < 4; r++) {
                int gm = m0 + wm + i * 16 + rq + r;
                int gn = n0 + wn + j * 16 + r16;
                if (gm >= p.M || gn >= p.N) continue;
                float a = acc[i][j][r];
                if (EPI == 0) {
                    p.C[coff + (long)gm * p.ldc + gn] = a;
                } else if (EPI == 2) {                // proj 4-way split
                    if (gn < 2048)      p.CB [(long)gm * 2048 + gn]          = __float2bfloat16(a);
                    else if (gn < 4096) p.CB2[(long)gm * 2048 + (gn - 2048)] = __float2bfloat16(a);
                    else if (gn < 8192) p.CB3[(long)gm * 4096 + (gn - 4096)] = __float2bfloat16(a);
                    else                p.C  [(long)gm * 16   + (gn - 8192)] = a;
                } else if (EPI == 3) {                // Mmem causal decay mask -> bf16
                    float lg = p.scr[1];
                    float v = (gm > gn) ? a * __expf((float)(gm - 1 - gn) * lg) : 0.f;
                    p.CB[coff + (long)gm * p.ldc + gn] = __float2bfloat16(v);
                } else if (EPI == 4) {                // inter: acc*gp[m] + intra(bf16) -> bf16
                    long ix = coff + (long)gm * p.ldc + gn;
                    float t = a * p.scr[16 + gm] + __bfloat162float(p.add0b[ix]);
                    p.CB[ix] = __float2bfloat16(t);
                } else if (EPI == 6) {                // bf16 only
                    p.CB[coff + (long)gm * p.ldc + gn] = __float2bfloat16(a);
                } else if (EPI == 7) {                // final: x(f32) + out(bf16) + 0.5*acc
                    long ix = (long)gm * p.ldc + gn;
                    p.C[ix] = p.add0[ix] + __bfloat162float(p.add0b[ix]) + 0.5f * a;
                }
            }
        }
    }
}

// ---------------------------------------------------------------------------
// Elementwise / helper kernels
// ---------------------------------------------------------------------------
__global__ void k_gamma(const float* decay, float* scr)
{
    int t = threadIdx.x;
    float g = 1.f / (1.f + expf(-decay[0]));
    float lg = logf(g);
    if (t == 0) { scr[0] = g; scr[1] = lg; scr[2] = expf(256.f * lg); }
    scr[16 + t]  = expf(lg * (float)t);          // gp
    scr[272 + t] = expf(lg * (float)(255 - t));  // gw
}

// one launch converting all four weight matrices fp32 -> bf16
__global__ void k_f2ball(const float* __restrict__ s0, bf16* __restrict__ d0, long n0,
                         const float* __restrict__ s1, bf16* __restrict__ d1, long n1,
                         const float* __restrict__ s2, bf16* __restrict__ d2, long n2,
                         const float* __restrict__ s3, bf16* __restrict__ d3, long n3)
{
    long i = (long)blockIdx.x * 256 + threadIdx.x;
    const float* s; bf16* d; long rel = i;
    if (rel < n0) { s = s0; d = d0; }
    else { rel -= n0;
        if (rel < n1) { s = s1; d = d1; }
        else { rel -= n1;
            if (rel < n2) { s = s2; d = d2; }
            else { rel -= n2; if (rel >= n3) return; s = s3; d = d3; }
        }
    }
    float4 v = ((const float4*)s)[rel];
    bf16* o = d + rel * 4;
    o[0] = __float2bfloat16(v.x); o[1] = __float2bfloat16(v.y);
    o[2] = __float2bfloat16(v.z); o[3] = __float2bfloat16(v.w);
}

__global__ __launch_bounds__(256) void k_rmsnorm(const float* __restrict__ x,
                                                 const float* __restrict__ w,
                                                 bf16* __restrict__ o)
{
    int row = blockIdx.x, t = threadIdx.x;
    float4 xv = ((const float4*)(x + (long)row * D_))[t];
    float s = xv.x*xv.x + xv.y*xv.y + xv.z*xv.z + xv.w*xv.w;
#pragma unroll
    for (int m = 32; m > 0; m >>= 1) s += __shfl_xor(s, m, 64);
    __shared__ float ps[4];
    if ((t & 63) == 0) ps[t >> 6] = s;
    __syncthreads();
    s = ps[0] + ps[1] + ps[2] + ps[3];
    float r = rsqrtf(s * (1.f / (float)D_) + 1e-6f);
    float4 wv = ((const float4*)w)[t];
    bf16* orow = o + (long)row * D_ + t * 4;
    orow[0] = __float2bfloat16(xv.x * r * wv.x);
    orow[1] = __float2bfloat16(xv.y * r * wv.y);
    orow[2] = __float2bfloat16(xv.z * r * wv.z);
    orow[3] = __float2bfloat16(xv.w * r * wv.w);
}

// fused softplus/ld + per-chunk inclusive cumsum
__global__ __launch_bounds__(256) void k_cum(const float* __restrict__ dtr,
                                             const float* __restrict__ dt_bias,
                                             const float* __restrict__ A_log,
                                             float* __restrict__ cum_g,
                                             float* __restrict__ cumlast)
{
    int bid = blockIdx.x;           // b*256 + c*16 + h
    int h = bid & 15, c = (bid >> 4) & 15, b = bid >> 8;
    long rowbase = (long)b * L_ + c * CS_;
    int tid = threadIdx.x;
    __shared__ float cum_s[256];
    float d = dtr[(rowbase + tid) * H_ + h] + dt_bias[h];
    float sp = (d > 20.f) ? d : log1pf(__expf(d));
    cum_s[tid] = -__expf(A_log[h]) * sp;
    __syncthreads();
    for (int off = 1; off < 256; off <<= 1) {
        float add = (tid >= off) ? cum_s[tid - off] : 0.f;
        __syncthreads();
        cum_s[tid] += add;
        __syncthreads();
    }
    cum_g[(rowbase + tid) * H_ + h] = cum_s[tid];
    if (tid == 255) cumlast[bid] = cum_s[255];
}

// fused causal-conv + silu + transpose: val_b [b*L][2048] -> vT [b*2048+d][L]
__global__ void k_vtc(const bf16* __restrict__ val_b, const float* __restrict__ cw,
                      const float* __restrict__ cb, bf16* __restrict__ vT)
{
    __shared__ bf16 tile[35][33];
    int b = blockIdx.z;
    int r0 = blockIdx.x * 32, c0 = blockIdx.y * 32;
    int tid = threadIdx.x;
    for (int idx = tid; idx < 35 * 32; idx += 256) {
        int row = idx >> 5, ch = idx & 31;   // l = r0 - 3 + row
        int gl = r0 - 3 + row;
        bf16 v = __float2bfloat16(0.f);
        if (gl >= 0 && gl < L_) v = val_b[((long)b * L_ + gl) * 2048 + c0 + ch];
        tile[row][ch] = v;
    }
    __syncthreads();
    int tx = tid & 31, ty = tid >> 5;
    int l = r0 + tx;
    for (int i = 0; i < 32; i += 8) {
        int ch = c0 + ty + i;
        float4 cwv = ((const float4*)cw)[ch];
        float acc = cb[ch]
                  + cwv.x * __bfloat162float(tile[tx][ty + i])
                  + cwv.y * __bfloat162float(tile[tx + 1][ty + i])
                  + cwv.z * __bfloat162float(tile[tx + 2][ty + i])
                  + cwv.w * __bfloat162float(tile[tx + 3][ty + i]);
        float s = acc / (1.f + __expf(-acc));
        vT[((long)b * 2048 + ch) * L_ + l] = __float2bfloat16(s);
    }
}

// bc_b B-part [b*L][4096 cols 0..2047] -> BT [b*2048 + col][L]
__global__ void k_bt(const bf16* __restrict__ bc, bf16* __restrict__ BT)
{
    __shared__ bf16 tile[32][33];
    int b = blockIdx.z;
    int r0 = blockIdx.x * 32, c0 = blockIdx.y * 32;
    int tx = threadIdx.x & 31, ty = threadIdx.x >> 5;
    for (int i = 0; i < 32; i += 8)
        tile[ty + i][tx] = bc[((long)b * L_ + r0 + ty + i) * 4096 + c0 + tx];
    __syncthreads();
    int l = r0 + tx;
    for (int i = 0; i < 32; i += 8) {
        int col = c0 + ty + i;
        BT[((long)b * 2048 + col) * L_ + l] = tile[tx][ty + i];
    }
}

// U[c][b][h][d][n] = sum_t (v[t,d]*w_t) B[t,n] — MFMA; v scaled in-register
__global__ __launch_bounds__(256, 2) void k_ssd_u2(
    const bf16* __restrict__ vT, const bf16* __restrict__ BT,
    const float* __restrict__ cum_g, const float* __restrict__ cumlast,
    float* __restrict__ U)
{
    int bid = blockIdx.x;
    int h = bid & 15, c = (bid >> 4) & 15, b = bid >> 8;
    long rowbase = (long)b * L_ + c * CS_;
    int tid = threadIdx.x;
    __shared__ float w_s[256];
    w_s[tid] = __expf(cumlast[bid] - cum_g[(rowbase + tid) * H_ + h]);
    __syncthreads();
    int lane = tid & 63, wave = tid >> 6;
    int r16 = lane & 15, q8 = (lane >> 4) * 8, rq = (lane >> 4) * 4;
    int d0 = (wave >> 1) * 64, n0 = (wave & 1) * 64;
    const bf16* vb = vT + ((long)b * 2048 + h * 128) * L_ + c * 256;
    const bf16* bb = BT + ((long)b * 2048 + h * 128) * L_ + c * 256;
    floatx4 zero4 = {0.f, 0.f, 0.f, 0.f};
    floatx4 acc[4][4];
#pragma unroll
    for (int i = 0; i < 4; i++)
#pragma unroll
        for (int j = 0; j < 4; j++) acc[i][j] = zero4;
#pragma unroll 2
    for (int ks = 0; ks < 8; ks++) {
        float wv[8];
#pragma unroll
        for (int j = 0; j < 8; j++) wv[j] = w_s[ks * 32 + q8 + j];
        short8 af[4], bq[4];
#pragma unroll
        for (int i = 0; i < 4; i++) {
            short8 raw = *(const short8*)(vb + (long)(d0 + i * 16 + r16) * L_ + ks * 32 + q8);
#pragma unroll
            for (int j = 0; j < 8; j++) {
                float f = bf2f(raw[j]) * wv[j];
                raw[j] = (short)(__float_as_uint(f) >> 16);   // truncate to bf16
            }
            af[i] = raw;
        }
#pragma unroll
        for (int j = 0; j < 4; j++)
            bq[j] = *(const short8*)(bb + (long)(n0 + j * 16 + r16) * L_ + ks * 32 + q8);
#pragma unroll
        for (int i = 0; i < 4; i++)
#pragma unroll
            for (int j = 0; j < 4; j++)
                acc[i][j] = __builtin_amdgcn_mfma_f32_16x16x32_bf16(af[i], bq[j], acc[i][j], 0, 0, 0);
    }
    float* up = U + (((long)c * B_ + b) * H_ + h) * 16384;
#pragma unroll
    for (int i = 0; i < 4; i++)
#pragma unroll
        for (int j = 0; j < 4; j++)
#pragma unroll
            for (int r = 0; r < 4; r++)
                up[(d0 + i * 16 + rq + r) * 128 + (n0 + j * 16 + r16)] = acc[i][j][r];
}

// h recurrence -> bf16 states entering each chunk
__global__ void k_ssd2(const float* __restrict__ U, const float* __restrict__ cumlast,
                       bf16* __restrict__ hst)
{
    long idx = (long)blockIdx.x * 256 + threadIdx.x;
    const long tot = (long)B_ * H_ * HD_ * N_;
    if (idx >= tot) return;
    int bh = (int)(idx >> 14);
    int b = bh >> 4, h = bh & 15;
    float hv = 0.f;
    for (int c = 0; c < NC_; c++) {
        hst[c * tot + idx] = __float2bfloat16(hv);
        float ef = __expf(cumlast[b * 256 + c * 16 + h]);
        hv = ef * hv + U[c * tot + idx];
    }
}

// Fused intra+inter SSD output, flash-style MFMA. Writes gated bf16 yg.
__global__ __launch_bounds__(256, 2) void k_ssd_y(
    const bf16* __restrict__ bc_b, const bf16* __restrict__ vT,
    const bf16* __restrict__ hst, const float* __restrict__ cum_g,
    const float* __restrict__ Dskip, const bf16* __restrict__ gate_b,
    bf16* __restrict__ yg)
{
    int bid = blockIdx.x;
    int h = bid & 15, c = (bid >> 4) & 15, b = bid >> 8;
    long rowbase = (long)b * L_ + c * CS_;
    int tid = threadIdx.x, lane = tid & 63, wave = tid >> 6;
    int r16 = lane & 15, q8 = (lane >> 4) * 8, rq = (lane >> 4) * 4;
    int wt = (wave >> 1) * 32, wmS = (wave & 1) * 32, wd = (wave & 1) * 64;

    __shared__ float cum_s[256];
    __shared__ __align__(16) bf16 Ss[64][72];

    cum_s[tid] = cum_g[(rowbase + tid) * H_ + h];
    __syncthreads();

    const bf16* Cb  = bc_b + rowbase * 4096 + 2048 + h * 128;
    const bf16* Bb  = bc_b + rowbase * 4096 + h * 128;
    const bf16* vTb = vT + ((long)b * 2048 + h * 128) * L_ + c * 256;
    const bf16* hp  = hst + (((long)c * B_ + b) * H_ + h) * 16384;

    floatx4 zero4 = {0.f, 0.f, 0.f, 0.f};

    for (int tt = 0; tt < 4; tt++) {
        int tbase = tt * 64;
        short8 caf[2][4];
#pragma unroll
        for (int i = 0; i < 2; i++)
#pragma unroll
            for (int ks = 0; ks < 4; ks++)
                caf[i][ks] = *(const short8*)(Cb + (long)(tbase + wt + i * 16 + r16) * 4096 + ks * 32 + q8);

        floatx4 yacc[2][4];
#pragma unroll
        for (int i = 0; i < 2; i++)
#pragma unroll
            for (int j = 0; j < 4; j++) yacc[i][j] = zero4;
#pragma unroll
        for (int ks = 0; ks < 4; ks++)
#pragma unroll
            for (int j = 0; j < 4; j++) {
                short8 hq = *(const short8*)(hp + (long)(wd + j * 16 + r16) * 128 + ks * 32 + q8);
#pragma unroll
                for (int i = 0; i < 2; i++)
                    yacc[i][j] = __builtin_amdgcn_mfma_f32_16x16x32_bf16(caf[i][ks], hq, yacc[i][j], 0, 0, 0);
            }
        float texp[2][4];
#pragma unroll
        for (int i = 0; i < 2; i++)
#pragma unroll
            for (int r = 0; r < 4; r++)
                texp[i][r] = __expf(cum_s[tbase + wt + i * 16 + rq + r]);
#pragma unroll
        for (int i = 0; i < 2; i++)
#pragma unroll
            for (int j = 0; j < 4; j++)
#pragma unroll
                for (int r = 0; r < 4; r++) yacc[i][j][r] *= texp[i][r];

        for (int mt = 0; mt <= tt; mt++) {
            int mbase = mt * 64;
            floatx4 sacc[2][2];
#pragma unroll
            for (int i = 0; i < 2; i++)
#pragma unroll
                for (int j = 0; j < 2; j++) sacc[i][j] = zero4;
#pragma unroll
            for (int ks = 0; ks < 4; ks++) {
                short8 bq[2];
#pragma unroll
                for (int j = 0; j < 2; j++)
                    bq[j] = *(const short8*)(Bb + (long)(mbase + wmS + j * 16 + r16) * 4096 + ks * 32 + q8);
#pragma unroll
                for (int i = 0; i < 2; i++)
#pragma unroll
                    for (int j = 0; j < 2; j++)
                        sacc[i][j] = __builtin_amdgcn_mfma_f32_16x16x32_bf16(caf[i][ks], bq[j], sacc[i][j], 0, 0, 0);
            }
            __syncthreads();
#pragma unroll
            for (int i = 0; i < 2; i++)
#pragma unroll
                for (int r = 0; r < 4; r++) {
                    int trow = wt + i * 16 + rq + r;
                    float ct = cum_s[tbase + trow];
#pragma unroll
                    for (int j = 0; j < 2; j++) {
                        int mcol = mbase + wmS + j * 16 + r16;
                        float val = (mcol <= tbase + trow) ? sacc[i][j][r] * __expf(ct - cum_s[mcol]) : 0.f;
                        Ss[trow][wmS + j * 16 + r16] = __float2bfloat16(val);
                    }
                }
            __syncthreads();
#pragma unroll
            for (int ks = 0; ks < 2; ks++) {
                short8 saf[2];
#pragma unroll
                for (int i = 0; i < 2; i++)
                    saf[i] = *(const short8*)&Ss[wt + i * 16 + r16][ks * 32 + q8];
#pragma unroll
                for (int j = 0; j < 4; j++) {
                    short8 vq = *(const short8*)(vTb + (long)(wd + j * 16 + r16) * L_ + mbase + ks * 32 + q8);
#pragma unroll
                    for (int i = 0; i < 2; i++)
                        yacc[i][j] = __builtin_amdgcn_mfma_f32_16x16x32_bf16(saf[i], vq, yacc[i][j], 0, 0, 0);
                }
            }
        }
#pragma unroll
        for (int i = 0; i < 2; i++)
#pragma unroll
            for (int r = 0; r < 4; r++) {
                int t = tbase + wt + i * 16 + rq + r;
                long grow = (rowbase + t) * 2048 + h * 128;
#pragma unroll
                for (int j = 0; j < 4; j++) {
                    int d = wd + j * 16 + r16;
                    float vv = __bfloat162float(vTb[(long)d * L_ + t]);
                    float y = yacc[i][j][r] + Dskip[h * 128 + d] * vv;
                    float g = __bfloat162float(gate_b[grow + d]);
                    float sg = g / (1.f + __expf(-g));
                    yg[grow + d] = __float2bfloat16(y * sg);
                }
            }
    }
}

__global__ void k_shift(const bf16* __restrict__ ob, bf16* __restrict__ wk)
{
    long idx = (long)blockIdx.x * 256 + threadIdx.x;
    if (idx >= (long)B_ * L_ * D_) return;
    int l = (int)((idx >> 10) & (L_ - 1));
    wk[idx] = (l == 0) ? __float2bfloat16(0.f) : ob[idx - D_];
}

// bf16 [b*L][D] -> bf16 [b*D][L]
__global__ void k_transpose_b(const bf16* __restrict__ srcg, bf16* __restrict__ dstg)
{
    __shared__ bf16 t[32][33];
    int b = blockIdx.z;
    const bf16* src = srcg + (long)b * L_ * D_;
    bf16* dst = dstg + (long)b * D_ * L_;
    int r0 = blockIdx.x * 32, c0 = blockIdx.y * 32;
    int tx = threadIdx.x & 31, ty = threadIdx.x >> 5;
    for (int i = 0; i < 32; i += 8)
        t[ty + i][tx] = src[(long)(r0 + ty + i) * D_ + c0 + tx];
    __syncthreads();
    for (int i = 0; i < 32; i += 8)
        dst[(long)(c0 + ty + i) * L_ + r0 + tx] = t[tx][ty + i];
}

// shifted+gw-weighted transpose from bf16 out: dst[d][l] = gw[l%256]*out[l-1][d]
__global__ void k_trans_wkg(const bf16* __restrict__ outg, const float* __restrict__ scr,
                            bf16* __restrict__ dstg)
{
    __shared__ float t[32][33];
    int b = blockIdx.z;
    const bf16* src = outg + (long)b * L_ * D_;
    bf16* dst = dstg + (long)b * D_ * L_;
    int r0 = blockIdx.x * 32, c0 = blockIdx.y * 32;
    int tx = threadIdx.x & 31, ty = threadIdx.x >> 5;
    for (int i = 0; i < 32; i += 8) {
        int rr = r0 + ty + i;
        float g = scr[272 + (rr & 255)];
        t[ty + i][tx] = (rr == 0) ? 0.f : __bfloat162float(src[(long)(rr - 1) * D_ + c0 + tx]) * g;
    }
    __syncthreads();
    for (int i = 0; i < 32; i += 8)
        dst[(long)(c0 + ty + i) * L_ + r0 + tx] = __float2bfloat16(t[tx][ty + i]);
}

// W recurrence, in place
__global__ void k_m2(bf16* __restrict__ UwW, const float* __restrict__ scr)
{
    long idx = (long)blockIdx.x * 256 + threadIdx.x;
    const long tot = (long)B_ * D_ * D_;
    if (idx >= tot) return;
    float gMC = scr[2];
    float w = 0.f;
    for (int c = 0; c < NC_; c++) {
        float tmp = __bfloat162float(UwW[c * tot + idx]);
        UwW[c * tot + idx] = __float2bfloat16(w);
        w = gMC * w + tmp;
    }
}

// ---------------------------------------------------------------------------
// Host side
// ---------------------------------------------------------------------------
static inline int cdiv_i(long a, long b) { return (int)((a + b - 1) / b); }

static void run_gemm(hipStream_t st, int epi, const bf16* A, const bf16* Bt,
                     float* C, bf16* CB, bf16* CB2, bf16* CB3,
                     const float* add0, const float* add1, const bf16* add0b,
                     const float* scr, int M, int N, int K,
                     long lda, long ldb, long ldc, int nbatch, int zinner,
                     long a_zo, long a_zi, long b_zo, long b_zi, long c_zo, long c_zi)
{
    GemmP p;
    p.A = A; p.Bt = Bt; p.C = C; p.CB = CB; p.CB2 = CB2; p.CB3 = CB3;
    p.add0 = add0; p.add1 = add1; p.add0b = add0b; p.scr = scr;
    p.lda = lda; p.ldb = ldb; p.ldc = ldc;
    p.M = M; p.N = N; p.K = K; p.zinner = zinner;
    p.a_zo = a_zo; p.a_zi = a_zi; p.b_zo = b_zo; p.b_zi = b_zi; p.c_zo = c_zo; p.c_zi = c_zi;
    dim3 g(cdiv_i(N, 128), cdiv_i(M, 128), nbatch);
    dim3 b(256);
    switch (epi) {
        case 0: gemm_bt<0><<<g, b, 0, st>>>(p); break;
        case 2: gemm_bt<2><<<g, b, 0, st>>>(p); break;
        case 3: gemm_bt<3><<<g, b, 0, st>>>(p); break;
        case 4: gemm_bt<4><<<g, b, 0, st>>>(p); break;
        case 6: gemm_bt<6><<<g, b, 0, st>>>(p); break;
        case 7: gemm_bt<7><<<g, b, 0, st>>>(p); break;
    }
}

extern "C" void kernel_launch(void* const* d_in, const int* in_sizes, int n_in,
                              void* d_out, int out_size, void* d_ws, size_t ws_size,
                              hipStream_t stream)
{
    const float* x       = (const float*)d_in[0];
    const float* norm_w  = (const float*)d_in[1];
    const float* w_in    = (const float*)d_in[2];
    const float* conv_w  = (const float*)d_in[3];
    const float* conv_b  = (const float*)d_in[4];
    const float* A_log   = (const float*)d_in[5];
    const float* dt_bias = (const float*)d_in[6];
    const float* D_skip  = (const float*)d_in[7];
    const float* w_out   = (const float*)d_in[8];
    const float* w_write = (const float*)d_in[9];
    const float* w_read  = (const float*)d_in[10];
    const float* decay   = (const float*)d_in[11];
    float* outp = (float*)d_out;

    // ---- workspace layout (same offsets as passing R5 run, ~244.9 MB) ----
    const size_t SZ_SCR  = 4096;
    const size_t SZ_DT   = (size_t)B_ * L_ * H_ * 4;
    const size_t SZ_CUML = 2048;
    const size_t SZ_WOUT = (size_t)D_ * DI_ * 2;
    const size_t SZ_WSML = (size_t)D_ * D_ * 2;
    const size_t SZ_R1   = (size_t)B_ * L_ * 2048 * 2;
    const size_t SZ_R2   = SZ_R1;
    const size_t SZ_R3   = (size_t)B_ * L_ * 4096 * 2;
    const size_t SZ_R4   = (size_t)B_ * L_ * D_ * 2 + (size_t)PROJ_ * D_ * 2;
    const size_t SZ_R5   = (size_t)B_ * L_ * 2048 * 4;

    size_t o = 0;
    auto take = [&](size_t sz) { size_t r = o; o += (sz + 255) & ~(size_t)255; return r; };
    const size_t O_SCR = take(SZ_SCR);
    const size_t O_DT  = take(SZ_DT);
    const size_t O_LD  = take(SZ_DT);   // unused (kept for layout stability)
    const size_t O_CUM = take(SZ_DT);
    const size_t O_CL  = take(SZ_CUML);
    const size_t O_WO  = take(SZ_WOUT);
    const size_t O_WW  = take(SZ_WSML);
    const size_t O_WR  = take(SZ_WSML);
    const size_t O_R1  = take(SZ_R1);
    const size_t O_R2  = take(SZ_R2);
    const size_t O_R3  = take(SZ_R3);
    const size_t O_R4  = take(SZ_R4);
    const size_t O_R5  = take(SZ_R5);
    const size_t NEED = o;
    if (ws_size < NEED) return;
    (void)O_LD;

    char* ws = (char*)d_ws;
    float* scr     = (float*)(ws + O_SCR);
    float* dt_raw  = (float*)(ws + O_DT);
    float* cum_g   = (float*)(ws + O_CUM);
    float* cumlast = (float*)(ws + O_CL);
    bf16*  w_out_b   = (bf16*)(ws + O_WO);
    bf16*  w_write_b = (bf16*)(ws + O_WW);
    bf16*  w_read_b  = (bf16*)(ws + O_WR);

    // R1: val_b -> (yg_b | hst_b) -> Sm_b + intra_b
    bf16*  val_b   = (bf16*)(ws + O_R1);
    bf16*  yg_b    = (bf16*)(ws + O_R1);
    bf16*  hst_b   = (bf16*)(ws + O_R1 + (size_t)B_ * L_ * D_ * 2);
    bf16*  Sm_b    = (bf16*)(ws + O_R1);
    bf16*  intra_b = (bf16*)(ws + O_R1 + (size_t)NC_ * B_ * MC_ * MC_ * 2);
    // R2: gate_b -> out_b + wk_b/reads_b
    bf16*  gate_b  = (bf16*)(ws + O_R2);
    bf16*  out_b   = (bf16*)(ws + O_R2);
    bf16*  wk_b    = (bf16*)(ws + O_R2 + (size_t)B_ * L_ * D_ * 2);
    bf16*  reads_b = wk_b;
    // R3: bc_b -> UwW
    bf16*  bc_b    = (bf16*)(ws + O_R3);
    bf16*  UwW     = (bf16*)(ws + O_R3);
    // R4: xn_b + w_in_b -> U_ssd
    bf16*  xn_b    = (bf16*)(ws + O_R4);
    bf16*  w_in_b  = (bf16*)(ws + O_R4 + (size_t)B_ * L_ * D_ * 2);
    float* U_ssd   = (float*)(ws + O_R4);
    // R5: vT_g + BT_g -> vbuf_b + vTm + wkgT
    bf16*  vT_g    = (bf16*)(ws + O_R5);
    bf16*  BT_g    = (bf16*)(ws + O_R5 + (size_t)B_ * L_ * 2048 * 2);
    bf16*  vbuf_b  = (bf16*)(ws + O_R5);
    bf16*  vTm     = (bf16*)(ws + O_R5 + (size_t)B_ * L_ * D_ * 4);
    bf16*  wkgT    = (bf16*)(ws + O_R5 + (size_t)B_ * L_ * D_ * 4 + (size_t)B_ * L_ * D_ * 2);

    const long BLD = (long)B_ * L_ * D_;

    k_gamma<<<1, 256, 0, stream>>>(decay, scr);
    {
        long n0 = (long)PROJ_ * D_ / 4, n1 = (long)D_ * DI_ / 4;
        long n2 = (long)D_ * D_ / 4,   n3 = n2;
        k_f2ball<<<cdiv_i(n0 + n1 + n2 + n3, 256), 256, 0, stream>>>(
            w_in, w_in_b, n0, w_out, w_out_b, n1, w_write, w_write_b, n2, w_read, w_read_b, n3);
    }
    k_rmsnorm<<<B_ * L_, 256, 0, stream>>>(x, norm_w, xn_b);
    // proj
    run_gemm(stream, 2, xn_b, w_in_b, dt_raw, val_b, gate_b, bc_b, nullptr, nullptr, nullptr, nullptr,
             B_ * L_, PROJ_, D_, D_, D_, 0, 1, 1, 0, 0, 0, 0, 0, 0);
    k_cum<<<B_ * NC_ * H_, 256, 0, stream>>>(dt_raw, dt_bias, A_log, cum_g, cumlast);
    // fused conv+silu+transpose, B transpose
    k_vtc<<<dim3(L_ / 32, DI_ / 32, B_), 256, 0, stream>>>(val_b, conv_w, conv_b, vT_g);
    k_bt<<<dim3(L_ / 32, DI_ / 32, B_), 256, 0, stream>>>(bc_b, BT_g);
    // SSD
    k_ssd_u2<<<B_ * NC_ * H_, 256, 0, stream>>>(vT_g, BT_g, cum_g, cumlast, U_ssd);
    k_ssd2<<<cdiv_i((long)B_ * H_ * HD_ * N_, 256), 256, 0, stream>>>(U_ssd, cumlast, hst_b);
    k_ssd_y<<<B_ * NC_ * H_, 256, 0, stream>>>(bc_b, vT_g, hst_b, cum_g, D_skip, gate_b, yg_b);
    // out projection (bf16 only)
    run_gemm(stream, 6, yg_b, w_out_b, nullptr, out_b, nullptr, nullptr, nullptr, nullptr, nullptr, nullptr,
             B_ * L_, D_, DI_, DI_, DI_, D_, 1, 1, 0, 0, 0, 0, 0, 0);
    // memory scan
    k_shift<<<cdiv_i(BLD, 256), 256, 0, stream>>>(out_b, wk_b);
    run_gemm(stream, 6, out_b, w_write_b, nullptr, vbuf_b, nullptr, nullptr, nullptr, nullptr, nullptr, nullptr,
             B_ * L_, D_, D_, D_, D_, D_, 1, 1, 0, 0, 0, 0, 0, 0);
    k_transpose_b<<<dim3(L_ / 32, D_ / 32, B_), 256, 0, stream>>>(vbuf_b, vTm);
    k_trans_wkg<<<dim3(L_ / 32, D_ / 32, B_), 256, 0, stream>>>(out_b, scr, wkgT);
    run_gemm(stream, 6, vTm, wkgT, nullptr, UwW, nullptr, nullptr, nullptr, nullptr, nullptr, nullptr,
             D_, D_, MC_, L_, L_, D_, B_ * NC_, NC_,
             (long)D_ * L_, MC_, (long)D_ * L_, MC_, (long)D_ * D_, (long)B_ * D_ * D_);
    k_m2<<<cdiv_i((long)B_ * D_ * D_, 256), 256, 0, stream>>>(UwW, scr);
    run_gemm(stream, 3, out_b, wk_b, nullptr, Sm_b, nullptr, nullptr, nullptr, nullptr, nullptr, scr,
             MC_, MC_, D_, D_, D_, MC_, B_ * NC_, NC_,
             (long)L_ * D_, (long)MC_ * D_, (long)L_ * D_, (long)MC_ * D_,
             (long)MC_ * MC_, (long)B_ * MC_ * MC_);
    run_gemm(stream, 6, Sm_b, vTm, nullptr, intra_b, nullptr, nullptr, nullptr, nullptr, nullptr, nullptr,
             MC_, D_, MC_, MC_, L_, D_, B_ * NC_, NC_,
             (long)MC_ * MC_, (long)B_ * MC_ * MC_, (long)D_ * L_, MC_,
             (long)L_ * D_, (long)MC_ * D_);
    run_gemm(stream, 4, out_b, UwW, nullptr, reads_b, nullptr, nullptr, nullptr, nullptr, intra_b, scr,
             MC_, D_, D_, D_, D_, D_, B_ * NC_, NC_,
             (long)L_ * D_, (long)MC_ * D_, (long)D_ * D_, (long)B_ * D_ * D_,
             (long)L_ * D_, (long)MC_ * D_);
    // final: d_out = x + out + 0.5 * reads @ w_read^T
    run_gemm(stream, 7, reads_b, w_read_b, outp, nullptr, nullptr, nullptr, x, nullptr, out_b, nullptr,
             B_ * L_, D_, D_, D_, D_, D_, 1, 1, 0, 0, 0, 0, 0, 0);
}

// Round 7
// 748.495 us; speedup vs baseline: 2.6621x; 1.0869x over previous
//
#include <hip/hip_runtime.h>
#include <hip/hip_bf16.h>

typedef __hip_bfloat16 bf16;
typedef __attribute__((ext_vector_type(8))) short short8;
typedef __attribute__((ext_vector_type(4))) float floatx4;
typedef __attribute__((ext_vector_type(16))) float floatx16;

#define B_ 2
#define L_ 4096
#define D_ 1024
#define DI_ 2048
#define H_ 16
#define HD_ 128
#define N_ 128
#define CS_ 256
#define MC_ 256
#define NC_ 16
#define PROJ_ 8208

__device__ __forceinline__ float bf2f(short s) {
    return __uint_as_float(((unsigned)(unsigned short)s) << 16);
}

__device__ __forceinline__ void gl_lds16(const void* g, void* s) {
    __builtin_amdgcn_global_load_lds(
        (const __attribute__((address_space(1))) void*)g,
        (__attribute__((address_space(3))) void*)s, 16, 0, 0);
}

// ---------------------------------------------------------------------------
// Generic bf16 MFMA GEMM: C[M,N] = A[M,K] @ Bt[N,K]^T  (both row-major, K contig)
// 128x128 tile, 4 waves, 32x32x16 MFMA, global_load_lds(16B) staging,
// XCD-aware supertile remap, XOR LDS bank swizzle.
// ---------------------------------------------------------------------------
struct GemmP {
    const bf16* A; const bf16* Bt;
    float* C; bf16* CB; bf16* CB2; bf16* CB3;
    const float* add0; const float* add1; const bf16* add0b; const float* scr;
    long lda, ldb, ldc;
    int M, N, K, zinner;
    long a_zo, a_zi, b_zo, b_zi, c_zo, c_zi;
};

template<int EPI>
__global__ __launch_bounds__(256, 2) void gemm_bt(GemmP p)
{
    // ---- XCD-aware tile remap (exact bijection grid -> tiles) ----
    int NT = gridDim.x, MT = gridDim.y;
    long T = (long)NT * MT * gridDim.z;
    long flat = ((long)blockIdx.z * MT + blockIdx.y) * NT + blockIdx.x;
    int xcd = (int)(flat & 7);
    long q = flat >> 3;
    long Tq = T >> 3; int Tr = (int)(T & 7);
    long tile = (long)xcd * Tq + (long)(xcd < Tr ? xcd : Tr) + q;
    long per_z = (long)NT * MT;
    int z = (int)(tile / per_z);
    int t2 = (int)(tile - (long)z * per_z);
    int FG = NT >> 3;
    int g, width, within;
    if (t2 < FG * MT * 8) { g = t2 / (MT * 8); width = 8; within = t2 - g * MT * 8; }
    else                  { g = FG; width = NT - FG * 8; within = t2 - FG * MT * 8; }
    int m_outer = within / (8 * width);
    int hb = MT - m_outer * 8; if (hb > 8) hb = 8;
    int inner = within - m_outer * 8 * width;
    int n_in = inner / hb, m_in = inner - n_in * hb;
    int m0 = (m_outer * 8 + m_in) * 128;
    int n0 = (g * 8 + n_in) * 128;

    int zo = z / p.zinner, zi = z % p.zinner;
    const bf16* A  = p.A  + (long)zo * p.a_zo + (long)zi * p.a_zi;
    const bf16* Bt = p.Bt + (long)zo * p.b_zo + (long)zi * p.b_zi;
    long coff = (long)zo * p.c_zo + (long)zi * p.c_zi;

    __shared__ __align__(16) bf16 As[128 * 64];
    __shared__ __align__(16) bf16 Bs[128 * 64];

    int tid = threadIdx.x;
    int lane = tid & 63, wave = tid >> 6;
    int wm = (wave >> 1) * 64, wn = (wave & 1) * 64;
    int ln31 = lane & 31, hi = lane >> 5;

    floatx16 acc[2][2];
#pragma unroll
    for (int i = 0; i < 2; i++)
#pragma unroll
        for (int j = 0; j < 2; j++)
#pragma unroll
            for (int r = 0; r < 16; r++) acc[i][j][r] = 0.f;

    int lrow = lane >> 3;
    int lc = ((lane & 7) ^ lrow) * 8;     // XOR-swizzled column (write side)
    int wrow = wave * 32;
    int rx = lane & 7;                    // read-side xor key (= row&7 of frag row)

    for (int k0 = 0; k0 < p.K; k0 += 64) {
#pragma unroll
        for (int t = 0; t < 4; t++) {
            int row = wrow + t * 8 + lrow;
            gl_lds16(A + (long)(m0 + row) * p.lda + k0 + lc, &As[(wrow + t * 8) * 64]);
            int bn = n0 + row; if (bn > p.N - 1) bn = p.N - 1;
            gl_lds16(Bt + (long)bn * p.ldb + k0 + lc, &Bs[(wrow + t * 8) * 64]);
        }
        __syncthreads();
#pragma unroll
        for (int ks = 0; ks < 64; ks += 16) {
            int lb = (ks >> 3) + hi;              // logical 8-elem k-block
            int po = ((lb ^ rx) << 3);            // swizzled phys offset
            short8 af[2], bq[2];
#pragma unroll
            for (int i = 0; i < 2; i++)
                af[i] = *(const short8*)&As[(wm + i * 32 + ln31) * 64 + po];
#pragma unroll
            for (int j = 0; j < 2; j++)
                bq[j] = *(const short8*)&Bs[(wn + j * 32 + ln31) * 64 + po];
#pragma unroll
            for (int i = 0; i < 2; i++)
#pragma unroll
                for (int j = 0; j < 2; j++)
                    acc[i][j] = __builtin_amdgcn_mfma_f32_32x32x16_bf16(af[i], bq[j], acc[i][j], 0, 0, 0);
        }
        __syncthreads();
    }

#pragma unroll
    for (int i = 0; i < 2; i++) {
#pragma unroll
        for (int j = 0; j < 2; j++) {
#pragma unroll
            for (int r = 0; r < 16; r++) {
                int gm = m0 + wm + i * 32 + (r & 3) + 8 * (r >> 2) + 4 * hi;
                int gn = n0 + wn + j * 32 + ln31;
                if (gm >= p.M || gn >= p.N) continue;
                float a = acc[i][j][r];
                if (EPI == 0) {
                    p.C[coff + (long)gm * p.ldc + gn] = a;
                } else if (EPI == 2) {                // proj 4-way split
                    if (gn < 2048)      p.CB [(long)gm * 2048 + gn]          = __float2bfloat16(a);
                    else if (gn < 4096) p.CB2[(long)gm * 2048 + (gn - 2048)] = __float2bfloat16(a);
                    else if (gn < 8192) p.CB3[(long)gm * 4096 + (gn - 4096)] = __float2bfloat16(a);
                    else                p.C  [(long)gm * 16   + (gn - 8192)] = a;
                } else if (EPI == 3) {                // Mmem causal decay mask -> bf16
                    float lg = p.scr[1];
                    float v = (gm > gn) ? a * __expf((float)(gm - 1 - gn) * lg) : 0.f;
                    p.CB[coff + (long)gm * p.ldc + gn] = __float2bfloat16(v);
                } else if (EPI == 4) {                // inter: acc*gp[m] + intra(bf16) -> bf16
                    long ix = coff + (long)gm * p.ldc + gn;
                    float t = a * p.scr[16 + gm] + __bfloat162float(p.add0b[ix]);
                    p.CB[ix] = __float2bfloat16(t);
                } else if (EPI == 6) {                // bf16 only
                    p.CB[coff + (long)gm * p.ldc + gn] = __float2bfloat16(a);
                } else if (EPI == 7) {                // final: x(f32) + out(bf16) + 0.5*acc
                    long ix = (long)gm * p.ldc + gn;
                    p.C[ix] = p.add0[ix] + __bfloat162float(p.add0b[ix]) + 0.5f * a;
                } else if (EPI == 8) {                // out_b + fused shift into wk
                    long ix = (long)gm * p.ldc + gn;
                    bf16 v = __float2bfloat16(a);
                    p.CB[ix] = v;
                    int l = gm & (L_ - 1);
                    if (l != L_ - 1) p.CB2[ix + p.ldc] = v;
                    if (l == 0) p.CB2[ix] = __float2bfloat16(0.f);
                }
            }
        }
    }
}

// ---------------------------------------------------------------------------
// Elementwise / helper kernels
// ---------------------------------------------------------------------------
__global__ void k_gamma(const float* decay, float* scr)
{
    int t = threadIdx.x;
    float g = 1.f / (1.f + expf(-decay[0]));
    float lg = logf(g);
    if (t == 0) { scr[0] = g; scr[1] = lg; scr[2] = expf(256.f * lg); }
    scr[16 + t]  = expf(lg * (float)t);          // gp
    scr[272 + t] = expf(lg * (float)(255 - t));  // gw
}

// one launch converting all four weight matrices fp32 -> bf16
__global__ void k_f2ball(const float* __restrict__ s0, bf16* __restrict__ d0, long n0,
                         const float* __restrict__ s1, bf16* __restrict__ d1, long n1,
                         const float* __restrict__ s2, bf16* __restrict__ d2, long n2,
                         const float* __restrict__ s3, bf16* __restrict__ d3, long n3)
{
    long i = (long)blockIdx.x * 256 + threadIdx.x;
    const float* s; bf16* d; long rel = i;
    if (rel < n0) { s = s0; d = d0; }
    else { rel -= n0;
        if (rel < n1) { s = s1; d = d1; }
        else { rel -= n1;
            if (rel < n2) { s = s2; d = d2; }
            else { rel -= n2; if (rel >= n3) return; s = s3; d = d3; }
        }
    }
    float4 v = ((const float4*)s)[rel];
    bf16* o = d + rel * 4;
    o[0] = __float2bfloat16(v.x); o[1] = __float2bfloat16(v.y);
    o[2] = __float2bfloat16(v.z); o[3] = __float2bfloat16(v.w);
}

__global__ __launch_bounds__(256) void k_rmsnorm(const float* __restrict__ x,
                                                 const float* __restrict__ w,
                                                 bf16* __restrict__ o)
{
    int row = blockIdx.x, t = threadIdx.x;
    float4 xv = ((const float4*)(x + (long)row * D_))[t];
    float s = xv.x*xv.x + xv.y*xv.y + xv.z*xv.z + xv.w*xv.w;
#pragma unroll
    for (int m = 32; m > 0; m >>= 1) s += __shfl_xor(s, m, 64);
    __shared__ float ps[4];
    if ((t & 63) == 0) ps[t >> 6] = s;
    __syncthreads();
    s = ps[0] + ps[1] + ps[2] + ps[3];
    float r = rsqrtf(s * (1.f / (float)D_) + 1e-6f);
    float4 wv = ((const float4*)w)[t];
    bf16* orow = o + (long)row * D_ + t * 4;
    orow[0] = __float2bfloat16(xv.x * r * wv.x);
    orow[1] = __float2bfloat16(xv.y * r * wv.y);
    orow[2] = __float2bfloat16(xv.z * r * wv.z);
    orow[3] = __float2bfloat16(xv.w * r * wv.w);
}

// fused softplus/ld + per-chunk inclusive cumsum
__global__ __launch_bounds__(256) void k_cum(const float* __restrict__ dtr,
                                             const float* __restrict__ dt_bias,
                                             const float* __restrict__ A_log,
                                             float* __restrict__ cum_g,
                                             float* __restrict__ cumlast)
{
    int bid = blockIdx.x;           // b*256 + c*16 + h
    int h = bid & 15, c = (bid >> 4) & 15, b = bid >> 8;
    long rowbase = (long)b * L_ + c * CS_;
    int tid = threadIdx.x;
    __shared__ float cum_s[256];
    float d = dtr[(rowbase + tid) * H_ + h] + dt_bias[h];
    float sp = (d > 20.f) ? d : log1pf(__expf(d));
    cum_s[tid] = -__expf(A_log[h]) * sp;
    __syncthreads();
    for (int off = 1; off < 256; off <<= 1) {
        float add = (tid >= off) ? cum_s[tid - off] : 0.f;
        __syncthreads();
        cum_s[tid] += add;
        __syncthreads();
    }
    cum_g[(rowbase + tid) * H_ + h] = cum_s[tid];
    if (tid == 255) cumlast[bid] = cum_s[255];
}

// fused causal-conv + silu + transpose: val_b [b*L][2048] -> vT [b*2048+d][L]
__global__ void k_vtc(const bf16* __restrict__ val_b, const float* __restrict__ cw,
                      const float* __restrict__ cb, bf16* __restrict__ vT)
{
    __shared__ bf16 tile[35][33];
    int b = blockIdx.z;
    int r0 = blockIdx.x * 32, c0 = blockIdx.y * 32;
    int tid = threadIdx.x;
    for (int idx = tid; idx < 35 * 32; idx += 256) {
        int row = idx >> 5, ch = idx & 31;
        int gl = r0 - 3 + row;
        bf16 v = __float2bfloat16(0.f);
        if (gl >= 0 && gl < L_) v = val_b[((long)b * L_ + gl) * 2048 + c0 + ch];
        tile[row][ch] = v;
    }
    __syncthreads();
    int tx = tid & 31, ty = tid >> 5;
    int l = r0 + tx;
    for (int i = 0; i < 32; i += 8) {
        int ch = c0 + ty + i;
        float4 cwv = ((const float4*)cw)[ch];
        float acc = cb[ch]
                  + cwv.x * __bfloat162float(tile[tx][ty + i])
                  + cwv.y * __bfloat162float(tile[tx + 1][ty + i])
                  + cwv.z * __bfloat162float(tile[tx + 2][ty + i])
                  + cwv.w * __bfloat162float(tile[tx + 3][ty + i]);
        float s = acc / (1.f + __expf(-acc));
        vT[((long)b * 2048 + ch) * L_ + l] = __float2bfloat16(s);
    }
}

// bc_b B-part [b*L][4096 cols 0..2047] -> BT [b*2048 + col][L]
__global__ void k_bt(const bf16* __restrict__ bc, bf16* __restrict__ BT)
{
    __shared__ bf16 tile[32][33];
    int b = blockIdx.z;
    int r0 = blockIdx.x * 32, c0 = blockIdx.y * 32;
    int tx = threadIdx.x & 31, ty = threadIdx.x >> 5;
    for (int i = 0; i < 32; i += 8)
        tile[ty + i][tx] = bc[((long)b * L_ + r0 + ty + i) * 4096 + c0 + tx];
    __syncthreads();
    int l = r0 + tx;
    for (int i = 0; i < 32; i += 8) {
        int col = c0 + ty + i;
        BT[((long)b * 2048 + col) * L_ + l] = tile[tx][ty + i];
    }
}

// U[c][b][h][d][n] = sum_t (v[t,d]*w_t) B[t,n] — MFMA; v scaled in-register
__global__ __launch_bounds__(256, 2) void k_ssd_u2(
    const bf16* __restrict__ vT, const bf16* __restrict__ BT,
    const float* __restrict__ cum_g, const float* __restrict__ cumlast,
    float* __restrict__ U)
{
    int bid = blockIdx.x;
    int h = bid & 15, c = (bid >> 4) & 15, b = bid >> 8;
    long rowbase = (long)b * L_ + c * CS_;
    int tid = threadIdx.x;
    __shared__ float w_s[256];
    w_s[tid] = __expf(cumlast[bid] - cum_g[(rowbase + tid) * H_ + h]);
    __syncthreads();
    int lane = tid & 63, wave = tid >> 6;
    int r16 = lane & 15, q8 = (lane >> 4) * 8, rq = (lane >> 4) * 4;
    int d0 = (wave >> 1) * 64, n0 = (wave & 1) * 64;
    const bf16* vb = vT + ((long)b * 2048 + h * 128) * L_ + c * 256;
    const bf16* bb = BT + ((long)b * 2048 + h * 128) * L_ + c * 256;
    floatx4 zero4 = {0.f, 0.f, 0.f, 0.f};
    floatx4 acc[4][4];
#pragma unroll
    for (int i = 0; i < 4; i++)
#pragma unroll
        for (int j = 0; j < 4; j++) acc[i][j] = zero4;
#pragma unroll 2
    for (int ks = 0; ks < 8; ks++) {
        float wv[8];
#pragma unroll
        for (int j = 0; j < 8; j++) wv[j] = w_s[ks * 32 + q8 + j];
        short8 af[4], bq[4];
#pragma unroll
        for (int i = 0; i < 4; i++) {
            short8 raw = *(const short8*)(vb + (long)(d0 + i * 16 + r16) * L_ + ks * 32 + q8);
#pragma unroll
            for (int j = 0; j < 8; j++) {
                float f = bf2f(raw[j]) * wv[j];
                raw[j] = (short)(__float_as_uint(f) >> 16);
            }
            af[i] = raw;
        }
#pragma unroll
        for (int j = 0; j < 4; j++)
            bq[j] = *(const short8*)(bb + (long)(n0 + j * 16 + r16) * L_ + ks * 32 + q8);
#pragma unroll
        for (int i = 0; i < 4; i++)
#pragma unroll
            for (int j = 0; j < 4; j++)
                acc[i][j] = __builtin_amdgcn_mfma_f32_16x16x32_bf16(af[i], bq[j], acc[i][j], 0, 0, 0);
    }
    float* up = U + (((long)c * B_ + b) * H_ + h) * 16384;
#pragma unroll
    for (int i = 0; i < 4; i++)
#pragma unroll
        for (int j = 0; j < 4; j++)
#pragma unroll
            for (int r = 0; r < 4; r++)
                up[(d0 + i * 16 + rq + r) * 128 + (n0 + j * 16 + r16)] = acc[i][j][r];
}

// h recurrence -> bf16 states entering each chunk
__global__ void k_ssd2(const float* __restrict__ U, const float* __restrict__ cumlast,
                       bf16* __restrict__ hst)
{
    long idx = (long)blockIdx.x * 256 + threadIdx.x;
    const long tot = (long)B_ * H_ * HD_ * N_;
    if (idx >= tot) return;
    int bh = (int)(idx >> 14);
    int b = bh >> 4, h = bh & 15;
    float hv = 0.f;
    for (int c = 0; c < NC_; c++) {
        hst[c * tot + idx] = __float2bfloat16(hv);
        float ef = __expf(cumlast[b * 256 + c * 16 + h]);
        hv = ef * hv + U[c * tot + idx];
    }
}

// Fused intra+inter SSD output, flash-style MFMA. Writes gated bf16 yg.
__global__ __launch_bounds__(256, 2) void k_ssd_y(
    const bf16* __restrict__ bc_b, const bf16* __restrict__ vT,
    const bf16* __restrict__ hst, const float* __restrict__ cum_g,
    const float* __restrict__ Dskip, const bf16* __restrict__ gate_b,
    bf16* __restrict__ yg)
{
    int bid = blockIdx.x;
    int h = bid & 15, c = (bid >> 4) & 15, b = bid >> 8;
    long rowbase = (long)b * L_ + c * CS_;
    int tid = threadIdx.x, lane = tid & 63, wave = tid >> 6;
    int r16 = lane & 15, q8 = (lane >> 4) * 8, rq = (lane >> 4) * 4;
    int wt = (wave >> 1) * 32, wmS = (wave & 1) * 32, wd = (wave & 1) * 64;

    __shared__ float cum_s[256];
    __shared__ __align__(16) bf16 Ss[64][72];

    cum_s[tid] = cum_g[(rowbase + tid) * H_ + h];
    __syncthreads();

    const bf16* Cb  = bc_b + rowbase * 4096 + 2048 + h * 128;
    const bf16* Bb  = bc_b + rowbase * 4096 + h * 128;
    const bf16* vTb = vT + ((long)b * 2048 + h * 128) * L_ + c * 256;
    const bf16* hp  = hst + (((long)c * B_ + b) * H_ + h) * 16384;

    floatx4 zero4 = {0.f, 0.f, 0.f, 0.f};

    for (int tt = 0; tt < 4; tt++) {
        int tbase = tt * 64;
        short8 caf[2][4];
#pragma unroll
        for (int i = 0; i < 2; i++)
#pragma unroll
            for (int ks = 0; ks < 4; ks++)
                caf[i][ks] = *(const short8*)(Cb + (long)(tbase + wt + i * 16 + r16) * 4096 + ks * 32 + q8);

        floatx4 yacc[2][4];
#pragma unroll
        for (int i = 0; i < 2; i++)
#pragma unroll
            for (int j = 0; j < 4; j++) yacc[i][j] = zero4;
#pragma unroll
        for (int ks = 0; ks < 4; ks++)
#pragma unroll
            for (int j = 0; j < 4; j++) {
                short8 hq = *(const short8*)(hp + (long)(wd + j * 16 + r16) * 128 + ks * 32 + q8);
#pragma unroll
                for (int i = 0; i < 2; i++)
                    yacc[i][j] = __builtin_amdgcn_mfma_f32_16x16x32_bf16(caf[i][ks], hq, yacc[i][j], 0, 0, 0);
            }
        float texp[2][4];
#pragma unroll
        for (int i = 0; i < 2; i++)
#pragma unroll
            for (int r = 0; r < 4; r++)
                texp[i][r] = __expf(cum_s[tbase + wt + i * 16 + rq + r]);
#pragma unroll
        for (int i = 0; i < 2; i++)
#pragma unroll
            for (int j = 0; j < 4; j++)
#pragma unroll
                for (int r = 0; r < 4; r++) yacc[i][j][r] *= texp[i][r];

        for (int mt = 0; mt <= tt; mt++) {
            int mbase = mt * 64;
            floatx4 sacc[2][2];
#pragma unroll
            for (int i = 0; i < 2; i++)
#pragma unroll
                for (int j = 0; j < 2; j++) sacc[i][j] = zero4;
#pragma unroll
            for (int ks = 0; ks < 4; ks++) {
                short8 bq[2];
#pragma unroll
                for (int j = 0; j < 2; j++)
                    bq[j] = *(const short8*)(Bb + (long)(mbase + wmS + j * 16 + r16) * 4096 + ks * 32 + q8);
#pragma unroll
                for (int i = 0; i < 2; i++)
#pragma unroll
                    for (int j = 0; j < 2; j++)
                        sacc[i][j] = __builtin_amdgcn_mfma_f32_16x16x32_bf16(caf[i][ks], bq[j], sacc[i][j], 0, 0, 0);
            }
            __syncthreads();
#pragma unroll
            for (int i = 0; i < 2; i++)
#pragma unroll
                for (int r = 0; r < 4; r++) {
                    int trow = wt + i * 16 + rq + r;
                    float ct = cum_s[tbase + trow];
#pragma unroll
                    for (int j = 0; j < 2; j++) {
                        int mcol = mbase + wmS + j * 16 + r16;
                        float val = (mcol <= tbase + trow) ? sacc[i][j][r] * __expf(ct - cum_s[mcol]) : 0.f;
                        Ss[trow][wmS + j * 16 + r16] = __float2bfloat16(val);
                    }
                }
            __syncthreads();
#pragma unroll
            for (int ks = 0; ks < 2; ks++) {
                short8 saf[2];
#pragma unroll
                for (int i = 0; i < 2; i++)
                    saf[i] = *(const short8*)&Ss[wt + i * 16 + r16][ks * 32 + q8];
#pragma unroll
                for (int j = 0; j < 4; j++) {
                    short8 vq = *(const short8*)(vTb + (long)(wd + j * 16 + r16) * L_ + mbase + ks * 32 + q8);
#pragma unroll
                    for (int i = 0; i < 2; i++)
                        yacc[i][j] = __builtin_amdgcn_mfma_f32_16x16x32_bf16(saf[i], vq, yacc[i][j], 0, 0, 0);
                }
            }
        }
#pragma unroll
        for (int i = 0; i < 2; i++)
#pragma unroll
            for (int r = 0; r < 4; r++) {
                int t = tbase + wt + i * 16 + rq + r;
                long grow = (rowbase + t) * 2048 + h * 128;
#pragma unroll
                for (int j = 0; j < 4; j++) {
                    int d = wd + j * 16 + r16;
                    float vv = __bfloat162float(vTb[(long)d * L_ + t]);
                    float y = yacc[i][j][r] + Dskip[h * 128 + d] * vv;
                    float g = __bfloat162float(gate_b[grow + d]);
                    float sg = g / (1.f + __expf(-g));
                    yg[grow + d] = __float2bfloat16(y * sg);
                }
            }
    }
}

// bf16 [b*L][D] -> bf16 [b*D][L]
__global__ void k_transpose_b(const bf16* __restrict__ srcg, bf16* __restrict__ dstg)
{
    __shared__ bf16 t[32][33];
    int b = blockIdx.z;
    const bf16* src = srcg + (long)b * L_ * D_;
    bf16* dst = dstg + (long)b * D_ * L_;
    int r0 = blockIdx.x * 32, c0 = blockIdx.y * 32;
    int tx = threadIdx.x & 31, ty = threadIdx.x >> 5;
    for (int i = 0; i < 32; i += 8)
        t[ty + i][tx] = src[(long)(r0 + ty + i) * D_ + c0 + tx];
    __syncthreads();
    for (int i = 0; i < 32; i += 8)
        dst[(long)(c0 + ty + i) * L_ + r0 + tx] = t[tx][ty + i];
}

// shifted+gw-weighted transpose from bf16 out: dst[d][l] = gw[l%256]*out[l-1][d]
__global__ void k_trans_wkg(const bf16* __restrict__ outg, const float* __restrict__ scr,
                            bf16* __restrict__ dstg)
{
    __shared__ float t[32][33];
    int b = blockIdx.z;
    const bf16* src = outg + (long)b * L_ * D_;
    bf16* dst = dstg + (long)b * D_ * L_;
    int r0 = blockIdx.x * 32, c0 = blockIdx.y * 32;
    int tx = threadIdx.x & 31, ty = threadIdx.x >> 5;
    for (int i = 0; i < 32; i += 8) {
        int rr = r0 + ty + i;
        float g = scr[272 + (rr & 255)];
        t[ty + i][tx] = (rr == 0) ? 0.f : __bfloat162float(src[(long)(rr - 1) * D_ + c0 + tx]) * g;
    }
    __syncthreads();
    for (int i = 0; i < 32; i += 8)
        dst[(long)(c0 + ty + i) * L_ + r0 + tx] = __float2bfloat16(t[tx][ty + i]);
}

// W recurrence, in place
__global__ void k_m2(bf16* __restrict__ UwW, const float* __restrict__ scr)
{
    long idx = (long)blockIdx.x * 256 + threadIdx.x;
    const long tot = (long)B_ * D_ * D_;
    if (idx >= tot) return;
    float gMC = scr[2];
    float w = 0.f;
    for (int c = 0; c < NC_; c++) {
        float tmp = __bfloat162float(UwW[c * tot + idx]);
        UwW[c * tot + idx] = __float2bfloat16(w);
        w = gMC * w + tmp;
    }
}

// ---------------------------------------------------------------------------
// Host side
// ---------------------------------------------------------------------------
static inline int cdiv_i(long a, long b) { return (int)((a + b - 1) / b); }

static void run_gemm(hipStream_t st, int epi, const bf16* A, const bf16* Bt,
                     float* C, bf16* CB, bf16* CB2, bf16* CB3,
                     const float* add0, const float* add1, const bf16* add0b,
                     const float* scr, int M, int N, int K,
                     long lda, long ldb, long ldc, int nbatch, int zinner,
                     long a_zo, long a_zi, long b_zo, long b_zi, long c_zo, long c_zi)
{
    GemmP p;
    p.A = A; p.Bt = Bt; p.C = C; p.CB = CB; p.CB2 = CB2; p.CB3 = CB3;
    p.add0 = add0; p.add1 = add1; p.add0b = add0b; p.scr = scr;
    p.lda = lda; p.ldb = ldb; p.ldc = ldc;
    p.M = M; p.N = N; p.K = K; p.zinner = zinner;
    p.a_zo = a_zo; p.a_zi = a_zi; p.b_zo = b_zo; p.b_zi = b_zi; p.c_zo = c_zo; p.c_zi = c_zi;
    dim3 g(cdiv_i(N, 128), cdiv_i(M, 128), nbatch);
    dim3 b(256);
    switch (epi) {
        case 0: gemm_bt<0><<<g, b, 0, st>>>(p); break;
        case 2: gemm_bt<2><<<g, b, 0, st>>>(p); break;
        case 3: gemm_bt<3><<<g, b, 0, st>>>(p); break;
        case 4: gemm_bt<4><<<g, b, 0, st>>>(p); break;
        case 6: gemm_bt<6><<<g, b, 0, st>>>(p); break;
        case 7: gemm_bt<7><<<g, b, 0, st>>>(p); break;
        case 8: gemm_bt<8><<<g, b, 0, st>>>(p); break;
    }
}

extern "C" void kernel_launch(void* const* d_in, const int* in_sizes, int n_in,
                              void* d_out, int out_size, void* d_ws, size_t ws_size,
                              hipStream_t stream)
{
    const float* x       = (const float*)d_in[0];
    const float* norm_w  = (const float*)d_in[1];
    const float* w_in    = (const float*)d_in[2];
    const float* conv_w  = (const float*)d_in[3];
    const float* conv_b  = (const float*)d_in[4];
    const float* A_log   = (const float*)d_in[5];
    const float* dt_bias = (const float*)d_in[6];
    const float* D_skip  = (const float*)d_in[7];
    const float* w_out   = (const float*)d_in[8];
    const float* w_write = (const float*)d_in[9];
    const float* w_read  = (const float*)d_in[10];
    const float* decay   = (const float*)d_in[11];
    float* outp = (float*)d_out;

    // ---- workspace layout (lifetime overlays, ~244.9 MB) ----
    const size_t SZ_SCR  = 4096;
    const size_t SZ_DT   = (size_t)B_ * L_ * H_ * 4;
    const size_t SZ_CUML = 2048;
    const size_t SZ_WOUT = (size_t)D_ * DI_ * 2;
    const size_t SZ_WSML = (size_t)D_ * D_ * 2;
    const size_t SZ_R1   = (size_t)B_ * L_ * 2048 * 2;
    const size_t SZ_R2   = SZ_R1;
    const size_t SZ_R3   = (size_t)B_ * L_ * 4096 * 2;
    const size_t SZ_R4   = (size_t)B_ * L_ * D_ * 2 + (size_t)PROJ_ * D_ * 2;
    const size_t SZ_R5   = (size_t)B_ * L_ * 2048 * 4;

    size_t o = 0;
    auto take = [&](size_t sz) { size_t r = o; o += (sz + 255) & ~(size_t)255; return r; };
    const size_t O_SCR = take(SZ_SCR);
    const size_t O_DT  = take(SZ_DT);
    const size_t O_LD  = take(SZ_DT);
    const size_t O_CUM = take(SZ_DT);
    const size_t O_CL  = take(SZ_CUML);
    const size_t O_WO  = take(SZ_WOUT);
    const size_t O_WW  = take(SZ_WSML);
    const size_t O_WR  = take(SZ_WSML);
    const size_t O_R1  = take(SZ_R1);
    const size_t O_R2  = take(SZ_R2);
    const size_t O_R3  = take(SZ_R3);
    const size_t O_R4  = take(SZ_R4);
    const size_t O_R5  = take(SZ_R5);
    const size_t NEED = o;
    if (ws_size < NEED) return;
    (void)O_LD;

    char* ws = (char*)d_ws;
    float* scr     = (float*)(ws + O_SCR);
    float* dt_raw  = (float*)(ws + O_DT);
    float* cum_g   = (float*)(ws + O_CUM);
    float* cumlast = (float*)(ws + O_CL);
    bf16*  w_out_b   = (bf16*)(ws + O_WO);
    bf16*  w_write_b = (bf16*)(ws + O_WW);
    bf16*  w_read_b  = (bf16*)(ws + O_WR);

    bf16*  val_b   = (bf16*)(ws + O_R1);
    bf16*  yg_b    = (bf16*)(ws + O_R1);
    bf16*  hst_b   = (bf16*)(ws + O_R1 + (size_t)B_ * L_ * D_ * 2);
    bf16*  Sm_b    = (bf16*)(ws + O_R1);
    bf16*  intra_b = (bf16*)(ws + O_R1 + (size_t)NC_ * B_ * MC_ * MC_ * 2);
    bf16*  gate_b  = (bf16*)(ws + O_R2);
    bf16*  out_b   = (bf16*)(ws + O_R2);
    bf16*  wk_b    = (bf16*)(ws + O_R2 + (size_t)B_ * L_ * D_ * 2);
    bf16*  reads_b = wk_b;
    bf16*  bc_b    = (bf16*)(ws + O_R3);
    bf16*  UwW     = (bf16*)(ws + O_R3);
    bf16*  xn_b    = (bf16*)(ws + O_R4);
    bf16*  w_in_b  = (bf16*)(ws + O_R4 + (size_t)B_ * L_ * D_ * 2);
    float* U_ssd   = (float*)(ws + O_R4);
    bf16*  vT_g    = (bf16*)(ws + O_R5);
    bf16*  BT_g    = (bf16*)(ws + O_R5 + (size_t)B_ * L_ * 2048 * 2);
    bf16*  vbuf_b  = (bf16*)(ws + O_R5);
    bf16*  vTm     = (bf16*)(ws + O_R5 + (size_t)B_ * L_ * D_ * 4);
    bf16*  wkgT    = (bf16*)(ws + O_R5 + (size_t)B_ * L_ * D_ * 4 + (size_t)B_ * L_ * D_ * 2);

    k_gamma<<<1, 256, 0, stream>>>(decay, scr);
    {
        long n0 = (long)PROJ_ * D_ / 4, n1 = (long)D_ * DI_ / 4;
        long n2 = (long)D_ * D_ / 4,   n3 = n2;
        k_f2ball<<<cdiv_i(n0 + n1 + n2 + n3, 256), 256, 0, stream>>>(
            w_in, w_in_b, n0, w_out, w_out_b, n1, w_write, w_write_b, n2, w_read, w_read_b, n3);
    }
    k_rmsnorm<<<B_ * L_, 256, 0, stream>>>(x, norm_w, xn_b);
    // proj
    run_gemm(stream, 2, xn_b, w_in_b, dt_raw, val_b, gate_b, bc_b, nullptr, nullptr, nullptr, nullptr,
             B_ * L_, PROJ_, D_, D_, D_, 0, 1, 1, 0, 0, 0, 0, 0, 0);
    k_cum<<<B_ * NC_ * H_, 256, 0, stream>>>(dt_raw, dt_bias, A_log, cum_g, cumlast);
    // fused conv+silu+transpose, B transpose
    k_vtc<<<dim3(L_ / 32, DI_ / 32, B_), 256, 0, stream>>>(val_b, conv_w, conv_b, vT_g);
    k_bt<<<dim3(L_ / 32, DI_ / 32, B_), 256, 0, stream>>>(bc_b, BT_g);
    // SSD
    k_ssd_u2<<<B_ * NC_ * H_, 256, 0, stream>>>(vT_g, BT_g, cum_g, cumlast, U_ssd);
    k_ssd2<<<cdiv_i((long)B_ * H_ * HD_ * N_, 256), 256, 0, stream>>>(U_ssd, cumlast, hst_b);
    k_ssd_y<<<B_ * NC_ * H_, 256, 0, stream>>>(bc_b, vT_g, hst_b, cum_g, D_skip, gate_b, yg_b);
    // out projection (bf16 + fused shift into wk)
    run_gemm(stream, 8, yg_b, w_out_b, nullptr, out_b, wk_b, nullptr, nullptr, nullptr, nullptr, nullptr,
             B_ * L_, D_, DI_, DI_, DI_, D_, 1, 1, 0, 0, 0, 0, 0, 0);
    // memory scan
    run_gemm(stream, 6, out_b, w_write_b, nullptr, vbuf_b, nullptr, nullptr, nullptr, nullptr, nullptr, nullptr,
             B_ * L_, D_, D_, D_, D_, D_, 1, 1, 0, 0, 0, 0, 0, 0);
    k_transpose_b<<<dim3(L_ / 32, D_ / 32, B_), 256, 0, stream>>>(vbuf_b, vTm);
    k_trans_wkg<<<dim3(L_ / 32, D_ / 32, B_), 256, 0, stream>>>(out_b, scr, wkgT);
    run_gemm(stream, 6, vTm, wkgT, nullptr, UwW, nullptr, nullptr, nullptr, nullptr, nullptr, nullptr,
             D_, D_, MC_, L_, L_, D_, B_ * NC_, NC_,
             (long)D_ * L_, MC_, (long)D_ * L_, MC_, (long)D_ * D_, (long)B_ * D_ * D_);
    k_m2<<<cdiv_i((long)B_ * D_ * D_, 256), 256, 0, stream>>>(UwW, scr);
    run_gemm(stream, 3, out_b, wk_b, nullptr, Sm_b, nullptr, nullptr, nullptr, nullptr, nullptr, scr,
             MC_, MC_, D_, D_, D_, MC_, B_ * NC_, NC_,
             (long)L_ * D_, (long)MC_ * D_, (long)L_ * D_, (long)MC_ * D_,
             (long)MC_ * MC_, (long)B_ * MC_ * MC_);
    run_gemm(stream, 6, Sm_b, vTm, nullptr, intra_b, nullptr, nullptr, nullptr, nullptr, nullptr, nullptr,
             MC_, D_, MC_, MC_, L_, D_, B_ * NC_, NC_,
             (long)MC_ * MC_, (long)B_ * MC_ * MC_, (long)D_ * L_, MC_,
             (long)L_ * D_, (long)MC_ * D_);
    run_gemm(stream, 4, out_b, UwW, nullptr, reads_b, nullptr, nullptr, nullptr, nullptr, intra_b, scr,
             MC_, D_, D_, D_, D_, D_, B_ * NC_, NC_,
             (long)L_ * D_, (long)MC_ * D_, (long)D_ * D_, (long)B_ * D_ * D_,
             (long)L_ * D_, (long)MC_ * D_);
    // final: d_out = x + out + 0.5 * reads @ w_read^T
    run_gemm(stream, 7, reads_b, w_read_b, outp, nullptr, nullptr, nullptr, x, nullptr, out_b, nullptr,
             B_ * L_, D_, D_, D_, D_, D_, 1, 1, 0, 0, 0, 0, 0, 0);
}